// Round 2
// baseline (9766.886 us; speedup 1.0000x reference)
//
#include <hip/hip_runtime.h>
#include <hip/hip_bf16.h>

// Problem constants (match reference)
#define NN 20000
#define EE 320000
#define DD 3072
#define HH 1536
#define LL 64

// ---------------------------------------------------------------------------
// Degree / norm kernels.  edge_index arrives as int32 (harness converts
// integer inputs to int32): layout [2, E] flattened -> src = ei[e], dst = ei[E+e].
// ---------------------------------------------------------------------------
__global__ void deg_init(float* deg, int n) {
    int i = blockIdx.x * blockDim.x + threadIdx.x;
    if (i < n) deg[i] = 1.0f;  // self-loop contributes 1
}

__global__ void deg_count(const int* __restrict__ ei, float* __restrict__ deg, int e) {
    int i = blockIdx.x * blockDim.x + threadIdx.x;
    if (i < e) {
        int d = ei[e + i];  // dst row of edge_index
        atomicAdd(&deg[d], 1.0f);
    }
}

__global__ void dinv_finalize(float* deg, int n) {
    int i = blockIdx.x * blockDim.x + threadIdx.x;
    if (i < n) deg[i] = rsqrtf(fmaxf(deg[i], 1e-12f));
}

// ---------------------------------------------------------------------------
// Generic tiled fp32 GEMM: C[M,N] = A[M,K] @ B[K,N] (+bias) (+relu)
// 64x64 tile, 256 threads, 4x4 per thread, BK=16.
// Requires K%16==0, N%64==0 (true for all 4 GEMMs here). M guarded.
// ---------------------------------------------------------------------------
#define BM 64
#define BN 64
#define BK 16
#define TM 4
#define TN 4

__global__ __launch_bounds__(256) void gemm_bias_act(
    const float* __restrict__ A, const float* __restrict__ B,
    const float* __restrict__ bias, float* __restrict__ C,
    int M, int N, int K, int has_bias, int relu)
{
    __shared__ float As[BK][BM + 1];
    __shared__ float Bs[BK][BN + 1];

    const int brow = blockIdx.y * BM;
    const int bcol = blockIdx.x * BN;
    const int tid  = threadIdx.x;
    const int tr   = tid >> 4;   // 0..15
    const int tc   = tid & 15;   // 0..15

    float acc[TM][TN];
#pragma unroll
    for (int m = 0; m < TM; ++m)
#pragma unroll
        for (int n = 0; n < TN; ++n) acc[m][n] = 0.0f;

    for (int k0 = 0; k0 < K; k0 += BK) {
        // load A tile (BM x BK)
#pragma unroll
        for (int i = tid; i < BM * BK; i += 256) {
            int r = i >> 4;        // /BK
            int c = i & (BK - 1);  // %BK
            int gr = brow + r;
            As[c][r] = (gr < M) ? A[(long long)gr * K + (k0 + c)] : 0.0f;
        }
        // load B tile (BK x BN)
#pragma unroll
        for (int i = tid; i < BK * BN; i += 256) {
            int r = i >> 6;        // /BN
            int c = i & (BN - 1);  // %BN
            Bs[r][c] = B[(long long)(k0 + r) * N + (bcol + c)];
        }
        __syncthreads();

#pragma unroll
        for (int kk = 0; kk < BK; ++kk) {
            float a[TM], b[TN];
#pragma unroll
            for (int m = 0; m < TM; ++m) a[m] = As[kk][tr * TM + m];
#pragma unroll
            for (int n = 0; n < TN; ++n) b[n] = Bs[kk][tc * TN + n];
#pragma unroll
            for (int m = 0; m < TM; ++m)
#pragma unroll
                for (int n = 0; n < TN; ++n) acc[m][n] += a[m] * b[n];
        }
        __syncthreads();
    }

#pragma unroll
    for (int m = 0; m < TM; ++m) {
        int gr = brow + tr * TM + m;
        if (gr >= M) continue;
#pragma unroll
        for (int n = 0; n < TN; ++n) {
            int gc = bcol + tc * TN + n;
            float v = acc[m][n];
            if (has_bias) v += bias[gc];
            if (relu) v = fmaxf(v, 0.0f);
            C[(long long)gr * N + gc] = v;
        }
    }
}

// ---------------------------------------------------------------------------
// Aggregation: out[i] = dinv[i]^2 * h[i]  (self-loop init)
// then scatter: out[dst] += h[src] * dinv[src]*dinv[dst] over edges
// ---------------------------------------------------------------------------
__global__ void agg_init(const float* __restrict__ h, const float* __restrict__ dinv,
                         float* __restrict__ out, int n, int F)
{
    long long total = (long long)n * F;
    for (long long idx = (long long)blockIdx.x * blockDim.x + threadIdx.x;
         idx < total; idx += (long long)gridDim.x * blockDim.x) {
        int i = (int)(idx / F);
        float d = dinv[i];
        out[idx] = h[idx] * d * d;
    }
}

__global__ void agg_scatter(const float* __restrict__ h, const float* __restrict__ dinv,
                            const int* __restrict__ ei,
                            float* __restrict__ out, int E, int F)
{
    for (int e = blockIdx.x; e < E; e += gridDim.x) {
        int s = ei[e];
        int d = ei[E + e];
        float norm = dinv[s] * dinv[d];
        const float* hs = h + (long long)s * F;
        float* od = out + (long long)d * F;
        for (int j = threadIdx.x; j < F; j += blockDim.x) {
            atomicAdd(&od[j], hs[j] * norm);
        }
    }
}

// ---------------------------------------------------------------------------
// y = LN(relu(in + bias)) * g + be   (one block per row)
// ---------------------------------------------------------------------------
__global__ void bias_relu_ln(const float* __restrict__ in, const float* __restrict__ bias,
                             const float* __restrict__ g, const float* __restrict__ be,
                             float* __restrict__ out, int F)
{
    const int row = blockIdx.x;
    const float* x = in + (long long)row * F;
    float* y = out + (long long)row * F;

    float lsum = 0.0f, lsq = 0.0f;
    for (int j = threadIdx.x; j < F; j += blockDim.x) {
        float v = fmaxf(x[j] + bias[j], 0.0f);
        lsum += v;
        lsq  += v * v;
    }
    // 64-lane wave reduce
#pragma unroll
    for (int off = 32; off > 0; off >>= 1) {
        lsum += __shfl_down(lsum, off);
        lsq  += __shfl_down(lsq,  off);
    }
    __shared__ float ssum[8], ssq[8];
    const int wave = threadIdx.x >> 6;
    const int lane = threadIdx.x & 63;
    const int nwaves = blockDim.x >> 6;
    if (lane == 0) { ssum[wave] = lsum; ssq[wave] = lsq; }
    __syncthreads();
    if (threadIdx.x == 0) {
        float s = 0.0f, q = 0.0f;
        for (int w = 0; w < nwaves; ++w) { s += ssum[w]; q += ssq[w]; }
        ssum[0] = s; ssq[0] = q;
    }
    __syncthreads();
    const float mean = ssum[0] / F;
    const float var  = ssq[0] / F - mean * mean;
    const float rstd = rsqrtf(var + 1e-5f);

    for (int j = threadIdx.x; j < F; j += blockDim.x) {
        float v = fmaxf(x[j] + bias[j], 0.0f);
        y[j] = (v - mean) * rstd * g[j] + be[j];
    }
}

// ---------------------------------------------------------------------------
// Launch.
// Buffer plan (liveness-checked):
//   out_recon region (N*D = 2*N*H floats of d_out) hosts h1 and agg1 early;
//   both are dead before step 9 writes the real reconstruction there.
//   ws layout: dinv (N) | wsH (N*H: hidden, then decode) | wsC (N*L) | wsD (N*L)
//   -> ws usage = (20000 + 30.72M + 2*1.28M) * 4 B ~= 133 MB.
// ---------------------------------------------------------------------------
extern "C" void kernel_launch(void* const* d_in, const int* in_sizes, int n_in,
                              void* d_out, int out_size, void* d_ws, size_t ws_size,
                              hipStream_t stream)
{
    const float* x     = (const float*)d_in[0];
    const int*   ei    = (const int*)d_in[1];
    const float* W_gc1 = (const float*)d_in[2];
    const float* b_gc1 = (const float*)d_in[3];
    const float* W_gc2 = (const float*)d_in[4];
    const float* b_gc2 = (const float*)d_in[5];
    const float* g1    = (const float*)d_in[6];
    const float* be1   = (const float*)d_in[7];
    const float* g2    = (const float*)d_in[8];
    const float* be2   = (const float*)d_in[9];
    const float* W_fc1 = (const float*)d_in[10];
    const float* b_fc1 = (const float*)d_in[11];
    const float* W_fc2 = (const float*)d_in[12];
    const float* b_fc2 = (const float*)d_in[13];

    float* out_latent = (float*)d_out;                       // [N, L]
    float* out_recon  = (float*)d_out + (long long)NN * LL;  // [N, D] = 2*N*H floats

    // Early-phase tenants of the recon region:
    float* h1   = out_recon;                         // N*H
    float* agg1 = out_recon + (long long)NN * HH;    // N*H

    float* wsf  = (float*)d_ws;
    float* dinv = wsf;                               // N
    float* wsH  = dinv + NN;                         // N*H (hidden, then decode)
    float* wsC  = wsH + (long long)NN * HH;          // N*L (h2)
    float* wsD  = wsC + (long long)NN * LL;          // N*L (agg2)

    // 1) degree + dinv
    deg_init<<<(NN + 255) / 256, 256, 0, stream>>>(dinv, NN);
    deg_count<<<(EE + 255) / 256, 256, 0, stream>>>(ei, dinv, EE);
    dinv_finalize<<<(NN + 255) / 256, 256, 0, stream>>>(dinv, NN);

    // 2) h1 = x @ W_gc1           [N, H]
    {
        dim3 grid(HH / BN, (NN + BM - 1) / BM);
        gemm_bias_act<<<grid, 256, 0, stream>>>(x, W_gc1, nullptr, h1, NN, HH, DD, 0, 0);
    }

    // 3) agg1 = self-loop init + edge scatter of h1   [N, H]
    agg_init<<<2048, 256, 0, stream>>>(h1, dinv, agg1, NN, HH);
    agg_scatter<<<EE, 256, 0, stream>>>(h1, dinv, ei, agg1, EE, HH);

    // 4) hidden = LN(relu(agg1 + b_gc1))  -> wsH
    bias_relu_ln<<<NN, 256, 0, stream>>>(agg1, b_gc1, g1, be1, wsH, HH);

    // 5) h2 = hidden @ W_gc2      [N, L] -> wsC
    {
        dim3 grid(LL / BN, (NN + BM - 1) / BM);
        gemm_bias_act<<<grid, 256, 0, stream>>>(wsH, W_gc2, nullptr, wsC, NN, LL, HH, 0, 0);
    }

    // 6) agg2 = self-loop init + edge scatter of h2   [N, L] -> wsD
    agg_init<<<1024, 256, 0, stream>>>(wsC, dinv, wsD, NN, LL);
    agg_scatter<<<EE, 64, 0, stream>>>(wsC, dinv, ei, wsD, EE, LL);

    // 7) latent = LN(relu(agg2 + b_gc2))  -> output 0
    bias_relu_ln<<<NN, 64, 0, stream>>>(wsD, b_gc2, g2, be2, out_latent, LL);

    // 8) decode = relu(latent @ W_fc1 + b_fc1)   [N, H] -> wsH (hidden is dead)
    {
        dim3 grid(HH / BN, (NN + BM - 1) / BM);
        gemm_bias_act<<<grid, 256, 0, stream>>>(out_latent, W_fc1, b_fc1, wsH, NN, HH, LL, 1, 1);
    }

    // 9) reconstructed = decode @ W_fc2 + b_fc2  [N, D]  -> output 1
    //    (h1/agg1 tenancy of out_recon is over; wsH is the A operand, no overlap)
    {
        dim3 grid(DD / BN, (NN + BM - 1) / BM);
        gemm_bias_act<<<grid, 256, 0, stream>>>(wsH, W_fc2, b_fc2, out_recon, NN, DD, HH, 1, 0);
    }
}

// Round 3
// 2744.447 us; speedup vs baseline: 3.5588x; 3.5588x over previous
//
#include <hip/hip_runtime.h>
#include <hip/hip_bf16.h>

// Problem constants (match reference)
#define NN 20000
#define EE 320000
#define DD 3072
#define HH 1536
#define LL 64

typedef unsigned short bf16_t;
typedef __attribute__((ext_vector_type(8))) __bf16 bf16x8;
typedef __attribute__((ext_vector_type(4))) float  f32x4;

__device__ __forceinline__ bf16_t f2bf(float f) {
    union { float f; unsigned u; } c; c.f = f;
    unsigned u = c.u;
    return (bf16_t)((u + 0x7fffu + ((u >> 16) & 1u)) >> 16);  // RNE (inputs finite)
}

// ---------------------------------------------------------------------------
// Degree / norm kernels. edge_index arrives as int32: src = ei[e], dst = ei[E+e].
// ---------------------------------------------------------------------------
__global__ void deg_init(float* deg, int n) {
    int i = blockIdx.x * blockDim.x + threadIdx.x;
    if (i < n) deg[i] = 1.0f;  // self-loop contributes 1
}

__global__ void deg_count(const int* __restrict__ ei, float* __restrict__ deg, int e) {
    int i = blockIdx.x * blockDim.x + threadIdx.x;
    if (i < e) atomicAdd(&deg[ei[e + i]], 1.0f);
}

__global__ void dinv_finalize(float* deg, int n) {
    int i = blockIdx.x * blockDim.x + threadIdx.x;
    if (i < n) deg[i] = rsqrtf(fmaxf(deg[i], 1e-12f));
}

// ---------------------------------------------------------------------------
// fp32 -> bf16 cast (vectorized), and fp32 [R][C] -> bf16 [C][R] transpose
// ---------------------------------------------------------------------------
__global__ void cvt_bf16(const float4* __restrict__ in, ushort4* __restrict__ out, long long n4) {
    for (long long i = (long long)blockIdx.x * blockDim.x + threadIdx.x;
         i < n4; i += (long long)gridDim.x * blockDim.x) {
        float4 v = in[i];
        ushort4 o;
        o.x = f2bf(v.x); o.y = f2bf(v.y); o.z = f2bf(v.z); o.w = f2bf(v.w);
        out[i] = o;
    }
}

__global__ __launch_bounds__(256) void cvt_transpose_bf16(
    const float* __restrict__ in, bf16_t* __restrict__ out, int R, int C)
{
    __shared__ float tile[32][33];
    const int bx = blockIdx.x, by = blockIdx.y;       // bx over C/32, by over R/32
    const int tx = threadIdx.x & 31;
    const int ty = (threadIdx.x >> 5) * 4;            // 8 groups of 4 rows
#pragma unroll
    for (int j = 0; j < 4; ++j)
        tile[ty + j][tx] = in[(long long)(by * 32 + ty + j) * C + bx * 32 + tx];
    __syncthreads();
#pragma unroll
    for (int j = 0; j < 4; ++j)
        out[(long long)(bx * 32 + ty + j) * R + by * 32 + tx] = f2bf(tile[tx][ty + j]);
}

// ---------------------------------------------------------------------------
// BF16 MFMA GEMM (m97 structure): C[M,N] = A[M,K] @ Bt[N,K]^T (+bias)
// 128x128 tile, BK=32, 256 threads (4 waves, each 64x64 = 4x4 frags of 16x16).
// A,Bt bf16 row-major; K%32==0, N%128==0; M guarded (staging rows clamped).
// ---------------------------------------------------------------------------
#define GLOAD_LDS16(g, l)                                                     \
    __builtin_amdgcn_global_load_lds(                                         \
        (const __attribute__((address_space(1))) unsigned int*)(g),          \
        (__attribute__((address_space(3))) unsigned int*)(l), 16, 0, 0)

template <int HAS_BIAS>
__global__ __launch_bounds__(256) void gemm_bf16_mfma(
    const bf16_t* __restrict__ A, const bf16_t* __restrict__ Bt,
    const float* __restrict__ bias, float* __restrict__ C,
    int M, int N, int K)
{
    __shared__ bf16_t As[128 * 32];
    __shared__ bf16_t Bs[128 * 32];

    const int tid = threadIdx.x;
    const int w   = tid >> 6;          // wave 0..3
    const int l   = tid & 63;
    const int wr  = w >> 1, wc = w & 1;

    const int brow = blockIdx.y * 128;
    const int bcol = blockIdx.x * 128;

    f32x4 acc[4][4] = {};

    const int srow   = tid >> 2;        // 0..63 (staging row within 64-row half)
    const int schunk = (tid & 3) * 8;   // bf16 offset within BK=32

    for (int k0 = 0; k0 < K; k0 += 32) {
        // stage A tile [128][32] (two 64-row halves; LDS dest wave-uniform base)
#pragma unroll
        for (int half = 0; half < 2; ++half) {
            int gr = brow + half * 64 + srow;
            if (gr > M - 1) gr = M - 1;                       // clamp (in-bounds dup read)
            const bf16_t* gsrc = A + (long long)gr * K + k0 + schunk;
            GLOAD_LDS16(gsrc, &As[(half * 64 + w * 16) * 32]);
        }
        // stage B tile [128][32]
#pragma unroll
        for (int half = 0; half < 2; ++half) {
            int r = half * 64 + srow;
            const bf16_t* gsrc = Bt + (long long)(bcol + r) * K + k0 + schunk;
            GLOAD_LDS16(gsrc, &Bs[(half * 64 + w * 16) * 32]);
        }
        __syncthreads();   // compiler drains vmcnt before s_barrier

        bf16x8 af[4], bfr[4];
#pragma unroll
        for (int m = 0; m < 4; ++m) {
            int row = wr * 64 + m * 16 + (l & 15);
            af[m] = *(const bf16x8*)&As[row * 32 + (l >> 4) * 8];
        }
#pragma unroll
        for (int n = 0; n < 4; ++n) {
            int row = wc * 64 + n * 16 + (l & 15);
            bfr[n] = *(const bf16x8*)&Bs[row * 32 + (l >> 4) * 8];
        }
#pragma unroll
        for (int m = 0; m < 4; ++m)
#pragma unroll
            for (int n = 0; n < 4; ++n)
                acc[m][n] = __builtin_amdgcn_mfma_f32_16x16x32_bf16(af[m], bfr[n], acc[m][n], 0, 0, 0);
        __syncthreads();   // protect LDS from next iteration's staging
    }

    // epilogue: C/D layout col=lane&15, row=(lane>>4)*4+j  [m89-verified]
#pragma unroll
    for (int m = 0; m < 4; ++m) {
#pragma unroll
        for (int n = 0; n < 4; ++n) {
            int col = bcol + wc * 64 + n * 16 + (l & 15);
            float b = HAS_BIAS ? bias[col] : 0.0f;
#pragma unroll
            for (int j = 0; j < 4; ++j) {
                int row = brow + wr * 64 + m * 16 + (l >> 4) * 4 + j;
                if (row < M) C[(long long)row * N + col] = acc[m][n][j] + b;
            }
        }
    }
}

// ---------------------------------------------------------------------------
// Generic tiled fp32 GEMM (for the two small GEMMs): C = A@B (+bias)(+relu),
// optional bf16 output. 64x64 tile, 256 threads, 4x4/thread, BK=16.
// ---------------------------------------------------------------------------
#define BM 64
#define BN 64
#define BK 16
#define TM 4
#define TN 4

template <int HAS_BIAS, int RELU, int OUT_BF16>
__global__ __launch_bounds__(256) void gemm_bias_act(
    const float* __restrict__ A, const float* __restrict__ B,
    const float* __restrict__ bias, void* __restrict__ Cout,
    int M, int N, int K)
{
    __shared__ float As[BK][BM + 1];
    __shared__ float Bs[BK][BN + 1];

    const int brow = blockIdx.y * BM;
    const int bcol = blockIdx.x * BN;
    const int tid  = threadIdx.x;
    const int tr   = tid >> 4;
    const int tc   = tid & 15;

    float acc[TM][TN];
#pragma unroll
    for (int m = 0; m < TM; ++m)
#pragma unroll
        for (int n = 0; n < TN; ++n) acc[m][n] = 0.0f;

    for (int k0 = 0; k0 < K; k0 += BK) {
#pragma unroll
        for (int i = tid; i < BM * BK; i += 256) {
            int r = i >> 4, c = i & (BK - 1);
            int gr = brow + r;
            As[c][r] = (gr < M) ? A[(long long)gr * K + (k0 + c)] : 0.0f;
        }
#pragma unroll
        for (int i = tid; i < BK * BN; i += 256) {
            int r = i >> 6, c = i & (BN - 1);
            Bs[r][c] = B[(long long)(k0 + r) * N + (bcol + c)];
        }
        __syncthreads();
#pragma unroll
        for (int kk = 0; kk < BK; ++kk) {
            float a[TM], b[TN];
#pragma unroll
            for (int m = 0; m < TM; ++m) a[m] = As[kk][tr * TM + m];
#pragma unroll
            for (int n = 0; n < TN; ++n) b[n] = Bs[kk][tc * TN + n];
#pragma unroll
            for (int m = 0; m < TM; ++m)
#pragma unroll
                for (int n = 0; n < TN; ++n) acc[m][n] += a[m] * b[n];
        }
        __syncthreads();
    }

#pragma unroll
    for (int m = 0; m < TM; ++m) {
        int gr = brow + tr * TM + m;
        if (gr >= M) continue;
#pragma unroll
        for (int n = 0; n < TN; ++n) {
            int gc = bcol + tc * TN + n;
            float v = acc[m][n];
            if (HAS_BIAS) v += bias[gc];
            if (RELU) v = fmaxf(v, 0.0f);
            if (OUT_BF16) ((bf16_t*)Cout)[(long long)gr * N + gc] = f2bf(v);
            else          ((float*)Cout)[(long long)gr * N + gc] = v;
        }
    }
}

// ---------------------------------------------------------------------------
// Aggregation: out[i] = dinv[i]^2 * h[i] (self-loop), then scatter-add edges
// ---------------------------------------------------------------------------
__global__ void agg_init(const float* __restrict__ h, const float* __restrict__ dinv,
                         float* __restrict__ out, int n, int F)
{
    long long total = (long long)n * F;
    for (long long idx = (long long)blockIdx.x * blockDim.x + threadIdx.x;
         idx < total; idx += (long long)gridDim.x * blockDim.x) {
        int i = (int)(idx / F);
        float d = dinv[i];
        out[idx] = h[idx] * d * d;
    }
}

__global__ void agg_scatter(const float* __restrict__ h, const float* __restrict__ dinv,
                            const int* __restrict__ ei,
                            float* __restrict__ out, int E, int F)
{
    for (int e = blockIdx.x; e < E; e += gridDim.x) {
        int s = ei[e];
        int d = ei[E + e];
        float norm = dinv[s] * dinv[d];
        const float* hs = h + (long long)s * F;
        float* od = out + (long long)d * F;
        for (int j = threadIdx.x; j < F; j += blockDim.x)
            atomicAdd(&od[j], hs[j] * norm);
    }
}

// ---------------------------------------------------------------------------
// y = LN(relu(in + bias)) * g + be   (one block per row)
// ---------------------------------------------------------------------------
__global__ void bias_relu_ln(const float* __restrict__ in, const float* __restrict__ bias,
                             const float* __restrict__ g, const float* __restrict__ be,
                             float* __restrict__ out, int F)
{
    const int row = blockIdx.x;
    const float* x = in + (long long)row * F;
    float* y = out + (long long)row * F;

    float lsum = 0.0f, lsq = 0.0f;
    for (int j = threadIdx.x; j < F; j += blockDim.x) {
        float v = fmaxf(x[j] + bias[j], 0.0f);
        lsum += v;
        lsq  += v * v;
    }
#pragma unroll
    for (int off = 32; off > 0; off >>= 1) {
        lsum += __shfl_down(lsum, off);
        lsq  += __shfl_down(lsq,  off);
    }
    __shared__ float ssum[8], ssq[8];
    const int wave = threadIdx.x >> 6;
    const int lane = threadIdx.x & 63;
    const int nwaves = blockDim.x >> 6;
    if (lane == 0) { ssum[wave] = lsum; ssq[wave] = lsq; }
    __syncthreads();
    if (threadIdx.x == 0) {
        float s = 0.0f, q = 0.0f;
        for (int w = 0; w < nwaves; ++w) { s += ssum[w]; q += ssq[w]; }
        ssum[0] = s; ssq[0] = q;
    }
    __syncthreads();
    const float mean = ssum[0] / F;
    const float var  = ssq[0] / F - mean * mean;
    const float rstd = rsqrtf(var + 1e-5f);

    for (int j = threadIdx.x; j < F; j += blockDim.x) {
        float v = fmaxf(x[j] + bias[j], 0.0f);
        y[j] = (v - mean) * rstd * g[j] + be[j];
    }
}

// ---------------------------------------------------------------------------
// Launch.
// d_out tenancy: out_recon (2*N*H f32) hosts h1 [0:NH) + agg1 [NH:2NH) early;
//   hidden overwrites h1 after h1 dies; all dead before step 9's final write.
// ws: dinv(N f32) | xb (N*D bf16; later decodeb N*H bf16) | W1t | W2t |
//     wsC (N*L f32) | wsD (N*L f32)   ~= 145 MB.
// ---------------------------------------------------------------------------
extern "C" void kernel_launch(void* const* d_in, const int* in_sizes, int n_in,
                              void* d_out, int out_size, void* d_ws, size_t ws_size,
                              hipStream_t stream)
{
    const float* x     = (const float*)d_in[0];
    const int*   ei    = (const int*)d_in[1];
    const float* W_gc1 = (const float*)d_in[2];
    const float* b_gc1 = (const float*)d_in[3];
    const float* W_gc2 = (const float*)d_in[4];
    const float* b_gc2 = (const float*)d_in[5];
    const float* g1    = (const float*)d_in[6];
    const float* be1   = (const float*)d_in[7];
    const float* g2    = (const float*)d_in[8];
    const float* be2   = (const float*)d_in[9];
    const float* W_fc1 = (const float*)d_in[10];
    const float* b_fc1 = (const float*)d_in[11];
    const float* W_fc2 = (const float*)d_in[12];
    const float* b_fc2 = (const float*)d_in[13];

    float* out_latent = (float*)d_out;                       // [N, L]
    float* out_recon  = (float*)d_out + (long long)NN * LL;  // [N, D]

    float* h1     = out_recon;                        // N*H (then hidden)
    float* agg1   = out_recon + (long long)NN * HH;   // N*H
    float* hidden = h1;                               // overwrites h1 after it dies

    float*  dinv = (float*)d_ws;                         // N
    bf16_t* xb   = (bf16_t*)(dinv + NN);                 // N*D bf16 (later decodeb N*H)
    bf16_t* W1t  = xb + (long long)NN * DD;              // H*D bf16  (W_gc1^T)
    bf16_t* W2t  = W1t + (long long)DD * HH;             // D*H bf16  (W_fc2^T)
    float*  wsC  = (float*)(W2t + (long long)DD * HH);   // N*L (h2)
    float*  wsD  = wsC + (long long)NN * LL;             // N*L (agg2)
    bf16_t* decodeb = xb;                                // N*H bf16, reuses xb region

    // 1) degree + dinv
    deg_init<<<(NN + 255) / 256, 256, 0, stream>>>(dinv, NN);
    deg_count<<<(EE + 255) / 256, 256, 0, stream>>>(ei, dinv, EE);
    dinv_finalize<<<(NN + 255) / 256, 256, 0, stream>>>(dinv, NN);

    // 2) bf16 conversions: xb = bf16(x); W1t = bf16(W_gc1^T); W2t = bf16(W_fc2^T)
    cvt_bf16<<<2048, 256, 0, stream>>>((const float4*)x, (ushort4*)xb, (long long)NN * DD / 4);
    {
        dim3 g1t(HH / 32, DD / 32);
        cvt_transpose_bf16<<<g1t, 256, 0, stream>>>(W_gc1, W1t, DD, HH);
        dim3 g2t(DD / 32, HH / 32);
        cvt_transpose_bf16<<<g2t, 256, 0, stream>>>(W_fc2, W2t, HH, DD);
    }

    // 3) h1 = xb @ W1t^T   [N, H]   (MFMA)
    {
        dim3 grid(HH / 128, (NN + 127) / 128);
        gemm_bf16_mfma<0><<<grid, 256, 0, stream>>>(xb, W1t, nullptr, h1, NN, HH, DD);
    }

    // 4) agg1 = self-loop init + edge scatter of h1   [N, H]
    agg_init<<<2048, 256, 0, stream>>>(h1, dinv, agg1, NN, HH);
    agg_scatter<<<EE, 256, 0, stream>>>(h1, dinv, ei, agg1, EE, HH);

    // 5) hidden = LN(relu(agg1 + b_gc1))  (h1 dead -> reuse its region)
    bias_relu_ln<<<NN, 256, 0, stream>>>(agg1, b_gc1, g1, be1, hidden, HH);

    // 6) h2 = hidden @ W_gc2      [N, L] -> wsC   (fp32)
    {
        dim3 grid(LL / BN, (NN + BM - 1) / BM);
        gemm_bias_act<0, 0, 0><<<grid, 256, 0, stream>>>(hidden, W_gc2, nullptr, wsC, NN, LL, HH);
    }

    // 7) agg2 + latent = LN(relu(agg2 + b_gc2)) -> output 0
    agg_init<<<1024, 256, 0, stream>>>(wsC, dinv, wsD, NN, LL);
    agg_scatter<<<EE, 64, 0, stream>>>(wsC, dinv, ei, wsD, EE, LL);
    bias_relu_ln<<<NN, 64, 0, stream>>>(wsD, b_gc2, g2, be2, out_latent, LL);

    // 8) decodeb = bf16(relu(latent @ W_fc1 + b_fc1))   [N, H]  (fp32 gemm, bf16 out)
    {
        dim3 grid(HH / BN, (NN + BM - 1) / BM);
        gemm_bias_act<1, 1, 1><<<grid, 256, 0, stream>>>(out_latent, W_fc1, b_fc1, decodeb, NN, HH, LL);
    }

    // 9) reconstructed = decodeb @ W2t^T + b_fc2  [N, D] -> output 1  (MFMA)
    {
        dim3 grid(DD / 128, (NN + 127) / 128);
        gemm_bf16_mfma<1><<<grid, 256, 0, stream>>>(decodeb, W2t, b_fc2, out_recon, NN, DD, HH);
    }
}

// Round 4
// 1557.025 us; speedup vs baseline: 6.2728x; 1.7626x over previous
//
#include <hip/hip_runtime.h>
#include <hip/hip_bf16.h>

// Problem constants (match reference)
#define NN 20000
#define EE 320000
#define DD 3072
#define HH 1536
#define LL 64

typedef unsigned short bf16_t;
typedef __attribute__((ext_vector_type(8))) __bf16 bf16x8;
typedef __attribute__((ext_vector_type(4))) float  f32x4;

__device__ __forceinline__ bf16_t f2bf(float f) {
    union { float f; unsigned u; } c; c.f = f;
    unsigned u = c.u;
    return (bf16_t)((u + 0x7fffu + ((u >> 16) & 1u)) >> 16);  // RNE (inputs finite)
}

// ---------------------------------------------------------------------------
// CSR build. edge_index is int32: src = ei[e], dst = ei[E+e].
// ---------------------------------------------------------------------------
__global__ void zero_int(int* __restrict__ p, int n) {
    int i = blockIdx.x * blockDim.x + threadIdx.x;
    if (i < n) p[i] = 0;
}

__global__ void cnt_count(const int* __restrict__ ei, int* __restrict__ cnt, int E) {
    int i = blockIdx.x * blockDim.x + threadIdx.x;
    if (i < E) atomicAdd(&cnt[ei[E + i]], 1);
}

// dinv[i] = rsqrt(deg) with deg = edge-indegree + 1 (self-loop)
__global__ void dinv_from_cnt(const int* __restrict__ cnt, float* __restrict__ dinv, int n) {
    int i = blockIdx.x * blockDim.x + threadIdx.x;
    if (i < n) dinv[i] = rsqrtf((float)(cnt[i] + 1));
}

// single-block exclusive scan (n = 20000, chunked Hillis-Steele)
__global__ __launch_bounds__(1024) void scan_rowptr(const int* __restrict__ cnt,
                                                    int* __restrict__ rowptr, int n)
{
    __shared__ int sdata[1024];
    __shared__ int scarry;
    const int tid = threadIdx.x;
    if (tid == 0) scarry = 0;
    __syncthreads();
    for (int base = 0; base < n; base += 1024) {
        int i = base + tid;
        int v = (i < n) ? cnt[i] : 0;
        int x = v;
        sdata[tid] = x;
        __syncthreads();
#pragma unroll
        for (int off = 1; off < 1024; off <<= 1) {
            int y = (tid >= off) ? sdata[tid - off] : 0;
            __syncthreads();
            x += y;
            sdata[tid] = x;
            __syncthreads();
        }
        if (i < n) rowptr[i] = scarry + x - v;  // exclusive
        int total = sdata[1023];
        __syncthreads();
        if (tid == 0) scarry += total;
        __syncthreads();
    }
    if (tid == 0) rowptr[n] = scarry;
}

__global__ void csr_fill(const int* __restrict__ ei, const int* __restrict__ rowptr,
                         int* __restrict__ cursor, int* __restrict__ csr_src, int E)
{
    int e = blockIdx.x * blockDim.x + threadIdx.x;
    if (e < E) {
        int d = ei[E + e];
        int pos = rowptr[d] + atomicAdd(&cursor[d], 1);
        csr_src[pos] = ei[e];
    }
}

// ---------------------------------------------------------------------------
// fp32 -> bf16 cast (vectorized), and fp32 [R][C] -> bf16 [C][R] transpose
// ---------------------------------------------------------------------------
__global__ void cvt_bf16(const float4* __restrict__ in, ushort4* __restrict__ out, long long n4) {
    for (long long i = (long long)blockIdx.x * blockDim.x + threadIdx.x;
         i < n4; i += (long long)gridDim.x * blockDim.x) {
        float4 v = in[i];
        ushort4 o;
        o.x = f2bf(v.x); o.y = f2bf(v.y); o.z = f2bf(v.z); o.w = f2bf(v.w);
        out[i] = o;
    }
}

__global__ __launch_bounds__(256) void cvt_transpose_bf16(
    const float* __restrict__ in, bf16_t* __restrict__ out, int R, int C)
{
    __shared__ float tile[32][33];
    const int bx = blockIdx.x, by = blockIdx.y;       // bx over C/32, by over R/32
    const int tx = threadIdx.x & 31;
    const int ty = (threadIdx.x >> 5) * 4;            // 8 groups of 4 rows
#pragma unroll
    for (int j = 0; j < 4; ++j)
        tile[ty + j][tx] = in[(long long)(by * 32 + ty + j) * C + bx * 32 + tx];
    __syncthreads();
#pragma unroll
    for (int j = 0; j < 4; ++j)
        out[(long long)(bx * 32 + ty + j) * R + by * 32 + tx] = f2bf(tile[tx][ty + j]);
}

// ---------------------------------------------------------------------------
// BF16 MFMA GEMM (m97 structure): C[M,N] = A[M,K] @ Bt[N,K]^T (+bias)
// 128x128 tile, BK=32, 256 threads (4 waves, each 64x64 = 4x4 frags of 16x16).
// ---------------------------------------------------------------------------
#define GLOAD_LDS16(g, l)                                                     \
    __builtin_amdgcn_global_load_lds(                                         \
        (const __attribute__((address_space(1))) unsigned int*)(g),          \
        (__attribute__((address_space(3))) unsigned int*)(l), 16, 0, 0)

template <int HAS_BIAS>
__global__ __launch_bounds__(256) void gemm_bf16_mfma(
    const bf16_t* __restrict__ A, const bf16_t* __restrict__ Bt,
    const float* __restrict__ bias, float* __restrict__ C,
    int M, int N, int K)
{
    __shared__ bf16_t As[128 * 32];
    __shared__ bf16_t Bs[128 * 32];

    const int tid = threadIdx.x;
    const int w   = tid >> 6;          // wave 0..3
    const int l   = tid & 63;
    const int wr  = w >> 1, wc = w & 1;

    const int brow = blockIdx.y * 128;
    const int bcol = blockIdx.x * 128;

    f32x4 acc[4][4] = {};

    const int srow   = tid >> 2;        // 0..63 (staging row within 64-row half)
    const int schunk = (tid & 3) * 8;   // bf16 offset within BK=32

    for (int k0 = 0; k0 < K; k0 += 32) {
#pragma unroll
        for (int half = 0; half < 2; ++half) {
            int gr = brow + half * 64 + srow;
            if (gr > M - 1) gr = M - 1;                       // clamp (in-bounds dup read)
            const bf16_t* gsrc = A + (long long)gr * K + k0 + schunk;
            GLOAD_LDS16(gsrc, &As[(half * 64 + w * 16) * 32]);
        }
#pragma unroll
        for (int half = 0; half < 2; ++half) {
            int r = half * 64 + srow;
            const bf16_t* gsrc = Bt + (long long)(bcol + r) * K + k0 + schunk;
            GLOAD_LDS16(gsrc, &Bs[(half * 64 + w * 16) * 32]);
        }
        __syncthreads();

        bf16x8 af[4], bfr[4];
#pragma unroll
        for (int m = 0; m < 4; ++m) {
            int row = wr * 64 + m * 16 + (l & 15);
            af[m] = *(const bf16x8*)&As[row * 32 + (l >> 4) * 8];
        }
#pragma unroll
        for (int n = 0; n < 4; ++n) {
            int row = wc * 64 + n * 16 + (l & 15);
            bfr[n] = *(const bf16x8*)&Bs[row * 32 + (l >> 4) * 8];
        }
#pragma unroll
        for (int m = 0; m < 4; ++m)
#pragma unroll
            for (int n = 0; n < 4; ++n)
                acc[m][n] = __builtin_amdgcn_mfma_f32_16x16x32_bf16(af[m], bfr[n], acc[m][n], 0, 0, 0);
        __syncthreads();
    }

#pragma unroll
    for (int m = 0; m < 4; ++m) {
#pragma unroll
        for (int n = 0; n < 4; ++n) {
            int col = bcol + wc * 64 + n * 16 + (l & 15);
            float b = HAS_BIAS ? bias[col] : 0.0f;
#pragma unroll
            for (int j = 0; j < 4; ++j) {
                int row = brow + wr * 64 + m * 16 + (l >> 4) * 4 + j;
                if (row < M) C[(long long)row * N + col] = acc[m][n][j] + b;
            }
        }
    }
}

// ---------------------------------------------------------------------------
// Generic tiled fp32 GEMM (small GEMMs): C = A@B (+bias)(+relu), opt bf16 out.
// ---------------------------------------------------------------------------
#define BM 64
#define BN 64
#define BK 16
#define TM 4
#define TN 4

template <int HAS_BIAS, int RELU, int OUT_BF16>
__global__ __launch_bounds__(256) void gemm_bias_act(
    const float* __restrict__ A, const float* __restrict__ B,
    const float* __restrict__ bias, void* __restrict__ Cout,
    int M, int N, int K)
{
    __shared__ float As[BK][BM + 1];
    __shared__ float Bs[BK][BN + 1];

    const int brow = blockIdx.y * BM;
    const int bcol = blockIdx.x * BN;
    const int tid  = threadIdx.x;
    const int tr   = tid >> 4;
    const int tc   = tid & 15;

    float acc[TM][TN];
#pragma unroll
    for (int m = 0; m < TM; ++m)
#pragma unroll
        for (int n = 0; n < TN; ++n) acc[m][n] = 0.0f;

    for (int k0 = 0; k0 < K; k0 += BK) {
#pragma unroll
        for (int i = tid; i < BM * BK; i += 256) {
            int r = i >> 4, c = i & (BK - 1);
            int gr = brow + r;
            As[c][r] = (gr < M) ? A[(long long)gr * K + (k0 + c)] : 0.0f;
        }
#pragma unroll
        for (int i = tid; i < BK * BN; i += 256) {
            int r = i >> 6, c = i & (BN - 1);
            Bs[r][c] = B[(long long)(k0 + r) * N + (bcol + c)];
        }
        __syncthreads();
#pragma unroll
        for (int kk = 0; kk < BK; ++kk) {
            float a[TM], b[TN];
#pragma unroll
            for (int m = 0; m < TM; ++m) a[m] = As[kk][tr * TM + m];
#pragma unroll
            for (int n = 0; n < TN; ++n) b[n] = Bs[kk][tc * TN + n];
#pragma unroll
            for (int m = 0; m < TM; ++m)
#pragma unroll
                for (int n = 0; n < TN; ++n) acc[m][n] += a[m] * b[n];
        }
        __syncthreads();
    }

#pragma unroll
    for (int m = 0; m < TM; ++m) {
        int gr = brow + tr * TM + m;
        if (gr >= M) continue;
#pragma unroll
        for (int n = 0; n < TN; ++n) {
            int gc = bcol + tc * TN + n;
            float v = acc[m][n];
            if (HAS_BIAS) v += bias[gc];
            if (RELU) v = fmaxf(v, 0.0f);
            if (OUT_BF16) ((bf16_t*)Cout)[(long long)gr * N + gc] = f2bf(v);
            else          ((float*)Cout)[(long long)gr * N + gc] = v;
        }
    }
}

// ---------------------------------------------------------------------------
// Fused GCN aggregation (CSR gather) + bias + ReLU + LayerNorm, F = 1536.
// out[d] = LN(relu(dinv[d]*(sum_s dinv[s]*h[s] + dinv[d]*h[d]) + bias))
// One block (256 thr) per dst row; thread t owns features t+256c, c=0..5.
// ---------------------------------------------------------------------------
__global__ __launch_bounds__(256) void gcn_agg_ln_h(
    const float* __restrict__ h, const float* __restrict__ dinv,
    const int* __restrict__ rowptr, const int* __restrict__ csr_src,
    const float* __restrict__ bias, const float* __restrict__ g,
    const float* __restrict__ be, float* __restrict__ out)
{
    const int row = blockIdx.x;
    const int tid = threadIdx.x;
    const float dd = dinv[row];

    float acc[6];
    {
        const float* hr = h + (long long)row * HH;
#pragma unroll
        for (int c = 0; c < 6; ++c) acc[c] = dd * hr[c * 256 + tid];
    }
    const int s0 = rowptr[row], s1 = rowptr[row + 1];
    for (int k = s0; k < s1; ++k) {
        const int s = csr_src[k];
        const float w = dinv[s];
        const float* hs = h + (long long)s * HH;
#pragma unroll
        for (int c = 0; c < 6; ++c) acc[c] += w * hs[c * 256 + tid];
    }

    float v[6];
    float lsum = 0.0f, lsq = 0.0f;
#pragma unroll
    for (int c = 0; c < 6; ++c) {
        v[c] = fmaxf(acc[c] * dd + bias[c * 256 + tid], 0.0f);
        lsum += v[c];
        lsq  += v[c] * v[c];
    }
#pragma unroll
    for (int off = 32; off > 0; off >>= 1) {
        lsum += __shfl_down(lsum, off);
        lsq  += __shfl_down(lsq,  off);
    }
    __shared__ float ssum[4], ssq[4];
    const int wave = tid >> 6, lane = tid & 63;
    if (lane == 0) { ssum[wave] = lsum; ssq[wave] = lsq; }
    __syncthreads();
    if (tid == 0) {
        float s = 0.0f, q = 0.0f;
#pragma unroll
        for (int w2 = 0; w2 < 4; ++w2) { s += ssum[w2]; q += ssq[w2]; }
        ssum[0] = s; ssq[0] = q;
    }
    __syncthreads();
    const float mean = ssum[0] / HH;
    const float var  = ssq[0] / HH - mean * mean;
    const float rstd = rsqrtf(var + 1e-5f);

    float* y = out + (long long)row * HH;
#pragma unroll
    for (int c = 0; c < 6; ++c)
        y[c * 256 + tid] = (v[c] - mean) * rstd * g[c * 256 + tid] + be[c * 256 + tid];
}

// Same, F = 64: one wave per row (4 rows per block), full-wave shfl_xor LN.
__global__ __launch_bounds__(256) void gcn_agg_ln_l(
    const float* __restrict__ h, const float* __restrict__ dinv,
    const int* __restrict__ rowptr, const int* __restrict__ csr_src,
    const float* __restrict__ bias, const float* __restrict__ g,
    const float* __restrict__ be, float* __restrict__ out, int n)
{
    const int row  = blockIdx.x * 4 + (threadIdx.x >> 6);
    const int lane = threadIdx.x & 63;
    if (row >= n) return;
    const float dd = dinv[row];

    float acc = dd * h[(long long)row * LL + lane];
    const int s0 = rowptr[row], s1 = rowptr[row + 1];
    for (int k = s0; k < s1; ++k) {
        const int s = csr_src[k];
        acc += dinv[s] * h[(long long)s * LL + lane];
    }
    float v = fmaxf(acc * dd + bias[lane], 0.0f);
    float lsum = v, lsq = v * v;
#pragma unroll
    for (int off = 32; off > 0; off >>= 1) {
        lsum += __shfl_xor(lsum, off);
        lsq  += __shfl_xor(lsq,  off);
    }
    const float mean = lsum / LL;
    const float var  = lsq / LL - mean * mean;
    const float rstd = rsqrtf(var + 1e-5f);
    out[(long long)row * LL + lane] = (v - mean) * rstd * g[lane] + be[lane];
}

// ---------------------------------------------------------------------------
// Launch.
// d_out tenancy: out_recon (2*N*H f32) hosts h1 [0:NH) and hidden [NH:2NH)
//   early; both dead before step 9's final write (gather reads h1 while
//   writing hidden -> MUST be disjoint).
// ws: dinv | cnt | cursor | rowptr | csr_src | xb (N*D bf16, later decodeb) |
//     W1t | W2t | wsC (N*L h2)   ~= 145 MB.
// ---------------------------------------------------------------------------
extern "C" void kernel_launch(void* const* d_in, const int* in_sizes, int n_in,
                              void* d_out, int out_size, void* d_ws, size_t ws_size,
                              hipStream_t stream)
{
    const float* x     = (const float*)d_in[0];
    const int*   ei    = (const int*)d_in[1];
    const float* W_gc1 = (const float*)d_in[2];
    const float* b_gc1 = (const float*)d_in[3];
    const float* W_gc2 = (const float*)d_in[4];
    const float* b_gc2 = (const float*)d_in[5];
    const float* g1    = (const float*)d_in[6];
    const float* be1   = (const float*)d_in[7];
    const float* g2    = (const float*)d_in[8];
    const float* be2   = (const float*)d_in[9];
    const float* W_fc1 = (const float*)d_in[10];
    const float* b_fc1 = (const float*)d_in[11];
    const float* W_fc2 = (const float*)d_in[12];
    const float* b_fc2 = (const float*)d_in[13];

    float* out_latent = (float*)d_out;                       // [N, L]
    float* out_recon  = (float*)d_out + (long long)NN * LL;  // [N, D]

    float* h1     = out_recon;                        // N*H
    float* hidden = out_recon + (long long)NN * HH;   // N*H (disjoint from h1!)

    float*  dinv    = (float*)d_ws;                          // N
    int*    cnt     = (int*)(dinv + NN);                     // N
    int*    cursor  = cnt + NN;                              // N
    int*    rowptr  = cursor + NN;                           // N+1
    int*    csr_src = rowptr + NN + 1;                       // E
    bf16_t* xb      = (bf16_t*)(csr_src + EE);               // N*D bf16 (later decodeb)
    bf16_t* W1t     = xb + (long long)NN * DD;               // H*D bf16 (W_gc1^T)
    bf16_t* W2t     = W1t + (long long)DD * HH;              // D*H bf16 (W_fc2^T)
    float*  wsC     = (float*)(W2t + (long long)DD * HH);    // N*L (h2)
    bf16_t* decodeb = xb;                                    // N*H bf16, reuses xb

    // 1) CSR build + dinv
    zero_int<<<(2 * NN + 255) / 256, 256, 0, stream>>>(cnt, 2 * NN);  // cnt + cursor
    cnt_count<<<(EE + 255) / 256, 256, 0, stream>>>(ei, cnt, EE);
    dinv_from_cnt<<<(NN + 255) / 256, 256, 0, stream>>>(cnt, dinv, NN);
    scan_rowptr<<<1, 1024, 0, stream>>>(cnt, rowptr, NN);
    csr_fill<<<(EE + 255) / 256, 256, 0, stream>>>(ei, rowptr, cursor, csr_src, EE);

    // 2) bf16 conversions
    cvt_bf16<<<2048, 256, 0, stream>>>((const float4*)x, (ushort4*)xb, (long long)NN * DD / 4);
    {
        dim3 g1t(HH / 32, DD / 32);
        cvt_transpose_bf16<<<g1t, 256, 0, stream>>>(W_gc1, W1t, DD, HH);
        dim3 g2t(DD / 32, HH / 32);
        cvt_transpose_bf16<<<g2t, 256, 0, stream>>>(W_fc2, W2t, HH, DD);
    }

    // 3) h1 = xb @ W1t^T   [N, H]   (MFMA)
    {
        dim3 grid(HH / 128, (NN + 127) / 128);
        gemm_bf16_mfma<0><<<grid, 256, 0, stream>>>(xb, W1t, nullptr, h1, NN, HH, DD);
    }

    // 4) hidden = LN(relu(agg(h1) + b_gc1))   (fused CSR gather + LN)
    gcn_agg_ln_h<<<NN, 256, 0, stream>>>(h1, dinv, rowptr, csr_src, b_gc1, g1, be1, hidden);

    // 5) h2 = hidden @ W_gc2      [N, L] -> wsC   (fp32)
    {
        dim3 grid(LL / BN, (NN + BM - 1) / BM);
        gemm_bias_act<0, 0, 0><<<grid, 256, 0, stream>>>(hidden, W_gc2, nullptr, wsC, NN, LL, HH);
    }

    // 6) latent = LN(relu(agg(h2) + b_gc2)) -> output 0  (fused)
    gcn_agg_ln_l<<<(NN + 3) / 4, 256, 0, stream>>>(wsC, dinv, rowptr, csr_src, b_gc2, g2, be2, out_latent, NN);

    // 7) decodeb = bf16(relu(latent @ W_fc1 + b_fc1))   [N, H]
    {
        dim3 grid(HH / BN, (NN + BM - 1) / BM);
        gemm_bias_act<1, 1, 1><<<grid, 256, 0, stream>>>(out_latent, W_fc1, b_fc1, decodeb, NN, HH, LL);
    }

    // 8) reconstructed = decodeb @ W2t^T + b_fc2  [N, D] -> output 1  (MFMA)
    {
        dim3 grid(DD / 128, (NN + 127) / 128);
        gemm_bf16_mfma<1><<<grid, 256, 0, stream>>>(decodeb, W2t, b_fc2, out_recon, NN, DD, HH);
    }
}

// Round 5
// 1409.792 us; speedup vs baseline: 6.9279x; 1.1044x over previous
//
#include <hip/hip_runtime.h>
#include <hip/hip_bf16.h>

// Problem constants (match reference)
#define NN 20000
#define EE 320000
#define DD 3072
#define HH 1536
#define LL 64

typedef unsigned short bf16_t;
typedef __attribute__((ext_vector_type(8))) __bf16 bf16x8;
typedef __attribute__((ext_vector_type(4))) float  f32x4;

__device__ __forceinline__ bf16_t f2bf(float f) {
    union { float f; unsigned u; } c; c.f = f;
    unsigned u = c.u;
    return (bf16_t)((u + 0x7fffu + ((u >> 16) & 1u)) >> 16);  // RNE (inputs finite)
}

// ---------------------------------------------------------------------------
// CSR build. edge_index is int32: src = ei[e], dst = ei[E+e].
// ---------------------------------------------------------------------------
__global__ void zero_int(int* __restrict__ p, int n) {
    int i = blockIdx.x * blockDim.x + threadIdx.x;
    if (i < n) p[i] = 0;
}

__global__ void cnt_count(const int* __restrict__ ei, int* __restrict__ cnt, int E) {
    int i = blockIdx.x * blockDim.x + threadIdx.x;
    if (i < E) atomicAdd(&cnt[ei[E + i]], 1);
}

__global__ void dinv_from_cnt(const int* __restrict__ cnt, float* __restrict__ dinv, int n) {
    int i = blockIdx.x * blockDim.x + threadIdx.x;
    if (i < n) dinv[i] = rsqrtf((float)(cnt[i] + 1));
}

// single-block exclusive scan (n = 20000, chunked Hillis-Steele)
__global__ __launch_bounds__(1024) void scan_rowptr(const int* __restrict__ cnt,
                                                    int* __restrict__ rowptr, int n)
{
    __shared__ int sdata[1024];
    __shared__ int scarry;
    const int tid = threadIdx.x;
    if (tid == 0) scarry = 0;
    __syncthreads();
    for (int base = 0; base < n; base += 1024) {
        int i = base + tid;
        int v = (i < n) ? cnt[i] : 0;
        int x = v;
        sdata[tid] = x;
        __syncthreads();
#pragma unroll
        for (int off = 1; off < 1024; off <<= 1) {
            int y = (tid >= off) ? sdata[tid - off] : 0;
            __syncthreads();
            x += y;
            sdata[tid] = x;
            __syncthreads();
        }
        if (i < n) rowptr[i] = scarry + x - v;  // exclusive
        int total = sdata[1023];
        __syncthreads();
        if (tid == 0) scarry += total;
        __syncthreads();
    }
    if (tid == 0) rowptr[n] = scarry;
}

__global__ void csr_fill(const int* __restrict__ ei, const int* __restrict__ rowptr,
                         int* __restrict__ cursor, int* __restrict__ csr_src, int E)
{
    int e = blockIdx.x * blockDim.x + threadIdx.x;
    if (e < E) {
        int d = ei[E + e];
        int pos = rowptr[d] + atomicAdd(&cursor[d], 1);
        csr_src[pos] = ei[e];
    }
}

// ---------------------------------------------------------------------------
// fp32 -> bf16 cast (vectorized), and fp32 [R][C] -> bf16 [C][R] transpose
// ---------------------------------------------------------------------------
__global__ void cvt_bf16(const float4* __restrict__ in, ushort4* __restrict__ out, long long n4) {
    for (long long i = (long long)blockIdx.x * blockDim.x + threadIdx.x;
         i < n4; i += (long long)gridDim.x * blockDim.x) {
        float4 v = in[i];
        ushort4 o;
        o.x = f2bf(v.x); o.y = f2bf(v.y); o.z = f2bf(v.z); o.w = f2bf(v.w);
        out[i] = o;
    }
}

__global__ __launch_bounds__(256) void cvt_transpose_bf16(
    const float* __restrict__ in, bf16_t* __restrict__ out, int R, int C)
{
    __shared__ float tile[32][33];
    const int bx = blockIdx.x, by = blockIdx.y;
    const int tx = threadIdx.x & 31;
    const int ty = (threadIdx.x >> 5) * 4;
#pragma unroll
    for (int j = 0; j < 4; ++j)
        tile[ty + j][tx] = in[(long long)(by * 32 + ty + j) * C + bx * 32 + tx];
    __syncthreads();
#pragma unroll
    for (int j = 0; j < 4; ++j)
        out[(long long)(bx * 32 + ty + j) * R + by * 32 + tx] = f2bf(tile[tx][ty + j]);
}

// ---------------------------------------------------------------------------
// BF16 MFMA GEMM (m97 structure + T1 bijective XCD swizzle, m204):
// C[M,N] = A[M,K] @ Bt[N,K]^T (+bias), optional bf16 output.
// 1D grid (gx*gy blocks); within an XCD chunk wgid is consecutive with
// col-fastest order -> A row-panel (128*K*2B) stays in that XCD's L2.
// ---------------------------------------------------------------------------
#define GLOAD_LDS16(g, l)                                                     \
    __builtin_amdgcn_global_load_lds(                                         \
        (const __attribute__((address_space(1))) unsigned int*)(g),          \
        (__attribute__((address_space(3))) unsigned int*)(l), 16, 0, 0)

template <int HAS_BIAS, int OUT_BF16>
__global__ __launch_bounds__(256) void gemm_bf16_mfma(
    const bf16_t* __restrict__ A, const bf16_t* __restrict__ Bt,
    const float* __restrict__ bias, void* __restrict__ Cout,
    int M, int N, int K, int gx)
{
    __shared__ bf16_t As[128 * 32];
    __shared__ bf16_t Bs[128 * 32];

    // bijective XCD chunk swizzle (nwg need not be %8)
    const int nwg = gridDim.x;
    const int q = nwg >> 3, r = nwg & 7;
    const int xcd = blockIdx.x & 7, lo = blockIdx.x >> 3;
    const int wgid = (xcd < r ? xcd * (q + 1) : r * (q + 1) + (xcd - r) * q) + lo;
    const int brow = (wgid / gx) * 128;
    const int bcol = (wgid % gx) * 128;

    const int tid = threadIdx.x;
    const int w   = tid >> 6;          // wave 0..3
    const int l   = tid & 63;
    const int wr  = w >> 1, wc = w & 1;

    f32x4 acc[4][4] = {};

    const int srow   = tid >> 2;        // 0..63
    const int schunk = (tid & 3) * 8;   // bf16 offset within BK=32

    for (int k0 = 0; k0 < K; k0 += 32) {
#pragma unroll
        for (int half = 0; half < 2; ++half) {
            int gr = brow + half * 64 + srow;
            if (gr > M - 1) gr = M - 1;                       // clamp (in-bounds dup read)
            const bf16_t* gsrc = A + (long long)gr * K + k0 + schunk;
            GLOAD_LDS16(gsrc, &As[(half * 64 + w * 16) * 32]);
        }
#pragma unroll
        for (int half = 0; half < 2; ++half) {
            int rr = half * 64 + srow;
            const bf16_t* gsrc = Bt + (long long)(bcol + rr) * K + k0 + schunk;
            GLOAD_LDS16(gsrc, &Bs[(half * 64 + w * 16) * 32]);
        }
        __syncthreads();

        bf16x8 af[4], bfr[4];
#pragma unroll
        for (int m = 0; m < 4; ++m) {
            int row = wr * 64 + m * 16 + (l & 15);
            af[m] = *(const bf16x8*)&As[row * 32 + (l >> 4) * 8];
        }
#pragma unroll
        for (int n = 0; n < 4; ++n) {
            int row = wc * 64 + n * 16 + (l & 15);
            bfr[n] = *(const bf16x8*)&Bs[row * 32 + (l >> 4) * 8];
        }
#pragma unroll
        for (int m = 0; m < 4; ++m)
#pragma unroll
            for (int n = 0; n < 4; ++n)
                acc[m][n] = __builtin_amdgcn_mfma_f32_16x16x32_bf16(af[m], bfr[n], acc[m][n], 0, 0, 0);
        __syncthreads();
    }

#pragma unroll
    for (int m = 0; m < 4; ++m) {
#pragma unroll
        for (int n = 0; n < 4; ++n) {
            int col = bcol + wc * 64 + n * 16 + (l & 15);
            float b = HAS_BIAS ? bias[col] : 0.0f;
#pragma unroll
            for (int j = 0; j < 4; ++j) {
                int row = brow + wr * 64 + m * 16 + (l >> 4) * 4 + j;
                if (row < M) {
                    float v = acc[m][n][j] + b;
                    if (OUT_BF16) ((bf16_t*)Cout)[(long long)row * N + col] = f2bf(v);
                    else          ((float*)Cout)[(long long)row * N + col] = v;
                }
            }
        }
    }
}

// ---------------------------------------------------------------------------
// Generic tiled fp32 GEMM (small GEMMs): C = A@B (+bias)(+relu), opt bf16 out.
// ---------------------------------------------------------------------------
#define BM 64
#define BN 64
#define BK 16
#define TM 4
#define TN 4

template <int HAS_BIAS, int RELU, int OUT_BF16>
__global__ __launch_bounds__(256) void gemm_bias_act(
    const float* __restrict__ A, const float* __restrict__ B,
    const float* __restrict__ bias, void* __restrict__ Cout,
    int M, int N, int K)
{
    __shared__ float As[BK][BM + 1];
    __shared__ float Bs[BK][BN + 1];

    const int brow = blockIdx.y * BM;
    const int bcol = blockIdx.x * BN;
    const int tid  = threadIdx.x;
    const int tr   = tid >> 4;
    const int tc   = tid & 15;

    float acc[TM][TN];
#pragma unroll
    for (int m = 0; m < TM; ++m)
#pragma unroll
        for (int n = 0; n < TN; ++n) acc[m][n] = 0.0f;

    for (int k0 = 0; k0 < K; k0 += BK) {
#pragma unroll
        for (int i = tid; i < BM * BK; i += 256) {
            int r = i >> 4, c = i & (BK - 1);
            int gr = brow + r;
            As[c][r] = (gr < M) ? A[(long long)gr * K + (k0 + c)] : 0.0f;
        }
#pragma unroll
        for (int i = tid; i < BK * BN; i += 256) {
            int r = i >> 6, c = i & (BN - 1);
            Bs[r][c] = B[(long long)(k0 + r) * N + (bcol + c)];
        }
        __syncthreads();
#pragma unroll
        for (int kk = 0; kk < BK; ++kk) {
            float a[TM], b[TN];
#pragma unroll
            for (int m = 0; m < TM; ++m) a[m] = As[kk][tr * TM + m];
#pragma unroll
            for (int n = 0; n < TN; ++n) b[n] = Bs[kk][tc * TN + n];
#pragma unroll
            for (int m = 0; m < TM; ++m)
#pragma unroll
                for (int n = 0; n < TN; ++n) acc[m][n] += a[m] * b[n];
        }
        __syncthreads();
    }

#pragma unroll
    for (int m = 0; m < TM; ++m) {
        int gr = brow + tr * TM + m;
        if (gr >= M) continue;
#pragma unroll
        for (int n = 0; n < TN; ++n) {
            int gc = bcol + tc * TN + n;
            float v = acc[m][n];
            if (HAS_BIAS) v += bias[gc];
            if (RELU) v = fmaxf(v, 0.0f);
            if (OUT_BF16) ((bf16_t*)Cout)[(long long)gr * N + gc] = f2bf(v);
            else          ((float*)Cout)[(long long)gr * N + gc] = v;
        }
    }
}

// ---------------------------------------------------------------------------
// Fused GCN aggregation (CSR gather, bf16 h) + bias + ReLU + LN, F = 1536.
// One WAVE per dst row (4 rows/block); lane owns 3 bf16x8 chunks (24 feats).
// out[d] = LN(relu(dinv[d]*(sum_s dinv[s]*h[s] + dinv[d]*h[d]) + bias))
// ---------------------------------------------------------------------------
__global__ __launch_bounds__(256) void gcn_agg_ln_h(
    const bf16_t* __restrict__ h, const float* __restrict__ dinv,
    const int* __restrict__ rowptr, const int* __restrict__ csr_src,
    const float* __restrict__ bias, const float* __restrict__ g,
    const float* __restrict__ be, float* __restrict__ out, int n)
{
    const int row  = blockIdx.x * 4 + (threadIdx.x >> 6);
    const int lane = threadIdx.x & 63;
    if (row >= n) return;
    const float dd = dinv[row];

    float acc[24];
    {
        const bf16x8* hr = (const bf16x8*)(h + (long long)row * HH);
#pragma unroll
        for (int c = 0; c < 3; ++c) {
            bf16x8 v = hr[c * 64 + lane];
#pragma unroll
            for (int j = 0; j < 8; ++j) acc[c * 8 + j] = dd * (float)v[j];
        }
    }
    const int s0 = rowptr[row], s1 = rowptr[row + 1];
    for (int k = s0; k < s1; ++k) {
        const int s = csr_src[k];
        const float w = dinv[s];
        const bf16x8* hs = (const bf16x8*)(h + (long long)s * HH);
#pragma unroll
        for (int c = 0; c < 3; ++c) {
            bf16x8 v = hs[c * 64 + lane];
#pragma unroll
            for (int j = 0; j < 8; ++j) acc[c * 8 + j] += w * (float)v[j];
        }
    }

    float lsum = 0.0f, lsq = 0.0f;
#pragma unroll
    for (int c = 0; c < 3; ++c)
#pragma unroll
        for (int j = 0; j < 8; ++j) {
            int idx = c * 512 + lane * 8 + j;
            float v = fmaxf(acc[c * 8 + j] * dd + bias[idx], 0.0f);
            acc[c * 8 + j] = v;
            lsum += v;
            lsq  += v * v;
        }
#pragma unroll
    for (int off = 32; off > 0; off >>= 1) {
        lsum += __shfl_xor(lsum, off);
        lsq  += __shfl_xor(lsq,  off);
    }
    const float mean = lsum / HH;
    const float var  = lsq / HH - mean * mean;
    const float rstd = rsqrtf(var + 1e-5f);

    float* y = out + (long long)row * HH;
#pragma unroll
    for (int c = 0; c < 3; ++c)
#pragma unroll
        for (int j = 0; j < 8; ++j) {
            int idx = c * 512 + lane * 8 + j;
            y[idx] = (acc[c * 8 + j] - mean) * rstd * g[idx] + be[idx];
        }
}

// Same, F = 64 (fp32 h): one wave per row (4 rows per block).
__global__ __launch_bounds__(256) void gcn_agg_ln_l(
    const float* __restrict__ h, const float* __restrict__ dinv,
    const int* __restrict__ rowptr, const int* __restrict__ csr_src,
    const float* __restrict__ bias, const float* __restrict__ g,
    const float* __restrict__ be, float* __restrict__ out, int n)
{
    const int row  = blockIdx.x * 4 + (threadIdx.x >> 6);
    const int lane = threadIdx.x & 63;
    if (row >= n) return;
    const float dd = dinv[row];

    float acc = dd * h[(long long)row * LL + lane];
    const int s0 = rowptr[row], s1 = rowptr[row + 1];
    for (int k = s0; k < s1; ++k) {
        const int s = csr_src[k];
        acc += dinv[s] * h[(long long)s * LL + lane];
    }
    float v = fmaxf(acc * dd + bias[lane], 0.0f);
    float lsum = v, lsq = v * v;
#pragma unroll
    for (int off = 32; off > 0; off >>= 1) {
        lsum += __shfl_xor(lsum, off);
        lsq  += __shfl_xor(lsq,  off);
    }
    const float mean = lsum / LL;
    const float var  = lsq / LL - mean * mean;
    const float rstd = rsqrtf(var + 1e-5f);
    out[(long long)row * LL + lane] = (v - mean) * rstd * g[lane] + be[lane];
}

// ---------------------------------------------------------------------------
// Launch.
// d_out tenancy: out_recon (2*N*H f32) hosts h1b (bf16, first N*H*2 bytes)
//   and hidden (f32, second N*H floats); disjoint; both dead before step 8.
// ws: dinv | cnt | cursor | rowptr | csr_src | xb (N*D bf16, later decodeb) |
//     W1t | W2t | wsC (N*L h2)   ~= 145 MB.
// ---------------------------------------------------------------------------
extern "C" void kernel_launch(void* const* d_in, const int* in_sizes, int n_in,
                              void* d_out, int out_size, void* d_ws, size_t ws_size,
                              hipStream_t stream)
{
    const float* x     = (const float*)d_in[0];
    const int*   ei    = (const int*)d_in[1];
    const float* W_gc1 = (const float*)d_in[2];
    const float* b_gc1 = (const float*)d_in[3];
    const float* W_gc2 = (const float*)d_in[4];
    const float* b_gc2 = (const float*)d_in[5];
    const float* g1    = (const float*)d_in[6];
    const float* be1   = (const float*)d_in[7];
    const float* g2    = (const float*)d_in[8];
    const float* be2   = (const float*)d_in[9];
    const float* W_fc1 = (const float*)d_in[10];
    const float* b_fc1 = (const float*)d_in[11];
    const float* W_fc2 = (const float*)d_in[12];
    const float* b_fc2 = (const float*)d_in[13];

    float* out_latent = (float*)d_out;                       // [N, L]
    float* out_recon  = (float*)d_out + (long long)NN * LL;  // [N, D]

    bf16_t* h1b   = (bf16_t*)out_recon;               // N*H bf16 (first half)
    float*  hidden = out_recon + (long long)NN * HH;  // N*H f32 (second half)

    float*  dinv    = (float*)d_ws;                          // N
    int*    cnt     = (int*)(dinv + NN);                     // N
    int*    cursor  = cnt + NN;                              // N
    int*    rowptr  = cursor + NN;                           // N+1
    int*    csr_src = rowptr + NN + 1;                       // E
    bf16_t* xb      = (bf16_t*)(csr_src + EE);               // N*D bf16 (later decodeb)
    bf16_t* W1t     = xb + (long long)NN * DD;               // H*D bf16 (W_gc1^T)
    bf16_t* W2t     = W1t + (long long)DD * HH;              // D*H bf16 (W_fc2^T)
    float*  wsC     = (float*)(W2t + (long long)DD * HH);    // N*L (h2)
    bf16_t* decodeb = xb;                                    // N*H bf16, reuses xb

    // 1) CSR build + dinv
    zero_int<<<(2 * NN + 255) / 256, 256, 0, stream>>>(cnt, 2 * NN);  // cnt + cursor
    cnt_count<<<(EE + 255) / 256, 256, 0, stream>>>(ei, cnt, EE);
    dinv_from_cnt<<<(NN + 255) / 256, 256, 0, stream>>>(cnt, dinv, NN);
    scan_rowptr<<<1, 1024, 0, stream>>>(cnt, rowptr, NN);
    csr_fill<<<(EE + 255) / 256, 256, 0, stream>>>(ei, rowptr, cursor, csr_src, EE);

    // 2) bf16 conversions
    cvt_bf16<<<2048, 256, 0, stream>>>((const float4*)x, (ushort4*)xb, (long long)NN * DD / 4);
    {
        dim3 g1t(HH / 32, DD / 32);
        cvt_transpose_bf16<<<g1t, 256, 0, stream>>>(W_gc1, W1t, DD, HH);
        dim3 g2t(DD / 32, HH / 32);
        cvt_transpose_bf16<<<g2t, 256, 0, stream>>>(W_fc2, W2t, HH, DD);
    }

    // 3) h1b = bf16(xb @ W1t^T)   [N, H]   (MFMA, swizzled, bf16 out)
    {
        int gx = HH / 128, gy = (NN + 127) / 128;
        gemm_bf16_mfma<0, 1><<<gx * gy, 256, 0, stream>>>(xb, W1t, nullptr, h1b, NN, HH, DD, gx);
    }

    // 4) hidden = LN(relu(agg(h1b) + b_gc1))   (fused CSR gather + LN, wave/row)
    gcn_agg_ln_h<<<(NN + 3) / 4, 256, 0, stream>>>(h1b, dinv, rowptr, csr_src, b_gc1, g1, be1, hidden, NN);

    // 5) h2 = hidden @ W_gc2      [N, L] -> wsC   (fp32)
    {
        dim3 grid(LL / BN, (NN + BM - 1) / BM);
        gemm_bias_act<0, 0, 0><<<grid, 256, 0, stream>>>(hidden, W_gc2, nullptr, wsC, NN, LL, HH);
    }

    // 6) latent = LN(relu(agg(h2) + b_gc2)) -> output 0  (fused)
    gcn_agg_ln_l<<<(NN + 3) / 4, 256, 0, stream>>>(wsC, dinv, rowptr, csr_src, b_gc2, g2, be2, out_latent, NN);

    // 7) decodeb = bf16(relu(latent @ W_fc1 + b_fc1))   [N, H]
    {
        dim3 grid(HH / BN, (NN + BM - 1) / BM);
        gemm_bias_act<1, 1, 1><<<grid, 256, 0, stream>>>(out_latent, W_fc1, b_fc1, decodeb, NN, HH, LL);
    }

    // 8) reconstructed = decodeb @ W2t^T + b_fc2  [N, D] -> output 1  (MFMA, swizzled)
    {
        int gx = DD / 128, gy = (NN + 127) / 128;
        gemm_bf16_mfma<1, 0><<<gx * gy, 256, 0, stream>>>(decodeb, W2t, b_fc2, out_recon, NN, DD, HH, gx);
    }
}

// Round 7
// 954.624 us; speedup vs baseline: 10.2311x; 1.4768x over previous
//
#include <hip/hip_runtime.h>
#include <hip/hip_bf16.h>

// Problem constants (match reference)
#define NN 20000
#define EE 320000
#define DD 3072
#define HH 1536
#define LL 64

typedef unsigned short bf16_t;
typedef __attribute__((ext_vector_type(8))) __bf16 bf16x8;
typedef __attribute__((ext_vector_type(4))) float  f32x4;

__device__ __forceinline__ bf16_t f2bf(float f) {
    union { float f; unsigned u; } c; c.f = f;
    unsigned u = c.u;
    return (bf16_t)((u + 0x7fffu + ((u >> 16) & 1u)) >> 16);  // RNE (inputs finite)
}

// ---------------------------------------------------------------------------
// CSR build. edge_index is int32: src = ei[e], dst = ei[E+e].
// ---------------------------------------------------------------------------
__global__ void zero_int(int* __restrict__ p, int n) {
    int i = blockIdx.x * blockDim.x + threadIdx.x;
    if (i < n) p[i] = 0;
}

__global__ void cnt_count(const int* __restrict__ ei, int* __restrict__ cnt, int E) {
    int i = blockIdx.x * blockDim.x + threadIdx.x;
    if (i < E) atomicAdd(&cnt[ei[E + i]], 1);
}

__global__ void dinv_from_cnt(const int* __restrict__ cnt, float* __restrict__ dinv, int n) {
    int i = blockIdx.x * blockDim.x + threadIdx.x;
    if (i < n) dinv[i] = rsqrtf((float)(cnt[i] + 1));
}

// single-block exclusive scan (n = 20000, chunked Hillis-Steele)
__global__ __launch_bounds__(1024) void scan_rowptr(const int* __restrict__ cnt,
                                                    int* __restrict__ rowptr, int n)
{
    __shared__ int sdata[1024];
    __shared__ int scarry;
    const int tid = threadIdx.x;
    if (tid == 0) scarry = 0;
    __syncthreads();
    for (int base = 0; base < n; base += 1024) {
        int i = base + tid;
        int v = (i < n) ? cnt[i] : 0;
        int x = v;
        sdata[tid] = x;
        __syncthreads();
#pragma unroll
        for (int off = 1; off < 1024; off <<= 1) {
            int y = (tid >= off) ? sdata[tid - off] : 0;
            __syncthreads();
            x += y;
            sdata[tid] = x;
            __syncthreads();
        }
        if (i < n) rowptr[i] = scarry + x - v;  // exclusive
        int total = sdata[1023];
        __syncthreads();
        if (tid == 0) scarry += total;
        __syncthreads();
    }
    if (tid == 0) rowptr[n] = scarry;
}

__global__ void csr_fill(const int* __restrict__ ei, const int* __restrict__ rowptr,
                         int* __restrict__ cursor, int* __restrict__ csr_src, int E)
{
    int e = blockIdx.x * blockDim.x + threadIdx.x;
    if (e < E) {
        int d = ei[E + e];
        int pos = rowptr[d] + atomicAdd(&cursor[d], 1);
        csr_src[pos] = ei[e];
    }
}

// ---------------------------------------------------------------------------
// fp32 -> bf16 cast (vectorized), and fp32 [R][C] -> bf16 [C][R] transpose
// ---------------------------------------------------------------------------
__global__ void cvt_bf16(const float4* __restrict__ in, ushort4* __restrict__ out, long long n4) {
    for (long long i = (long long)blockIdx.x * blockDim.x + threadIdx.x;
         i < n4; i += (long long)gridDim.x * blockDim.x) {
        float4 v = in[i];
        ushort4 o;
        o.x = f2bf(v.x); o.y = f2bf(v.y); o.z = f2bf(v.z); o.w = f2bf(v.w);
        out[i] = o;
    }
}

__global__ __launch_bounds__(256) void cvt_transpose_bf16(
    const float* __restrict__ in, bf16_t* __restrict__ out, int R, int C)
{
    __shared__ float tile[32][33];
    const int bx = blockIdx.x, by = blockIdx.y;   // bx over C/32, by over R/32
    const int tx = threadIdx.x & 31;
    const int ty = (threadIdx.x >> 5) * 4;
#pragma unroll
    for (int j = 0; j < 4; ++j)
        tile[ty + j][tx] = in[(long long)(by * 32 + ty + j) * C + bx * 32 + tx];
    __syncthreads();
#pragma unroll
    for (int j = 0; j < 4; ++j)
        out[(long long)(bx * 32 + ty + j) * R + by * 32 + tx] = f2bf(tile[tx][ty + j]);
}

// ---------------------------------------------------------------------------
// BF16 MFMA GEMM (m97 structure + bijective XCD swizzle):
// C[M,N] = A[M,K] @ Bt[N,K]^T (+bias)(+relu), fp32 or bf16 out.
// BNT = 128: 128x128 tile, 4 waves as 2x2, wave-tile 64x64 (4x4 frags).
// BNT =  64: 128x64  tile, 4 waves as 2x2, wave-tile 64x32 (4x2 frags).
// BK=32. K%32==0, N%BNT==0; M guarded via clamp (duplicate in-bounds read).
// Wave-column offset = wc * (BNT/2)  [ROUND-6 BUG was BNT/4].
// ---------------------------------------------------------------------------
#define GLOAD_LDS16(g, l)                                                     \
    __builtin_amdgcn_global_load_lds(                                         \
        (const __attribute__((address_space(1))) unsigned int*)(g),          \
        (__attribute__((address_space(3))) unsigned int*)(l), 16, 0, 0)

template <int HAS_BIAS, int RELU, int OUT_BF16, int BNT>
__global__ __launch_bounds__(256) void gemm_bf16_mfma(
    const bf16_t* __restrict__ A, const bf16_t* __restrict__ Bt,
    const float* __restrict__ bias, void* __restrict__ Cout,
    int M, int N, int K, int gx)
{
    constexpr int NFRAG = BNT / 32;      // B frags per wave (4 or 2)
    constexpr int BHALF = BNT / 64;      // B staging passes (2 or 1)
    constexpr int WCOFF = BNT / 2;       // wave-column offset

    __shared__ bf16_t As[128 * 32];
    __shared__ bf16_t Bs[BNT * 32];

    // bijective XCD chunk swizzle (works for any nwg)
    const int nwg = gridDim.x;
    const int q = nwg >> 3, r = nwg & 7;
    const int xcd = blockIdx.x & 7, lo = blockIdx.x >> 3;
    const int wgid = (xcd < r ? xcd * (q + 1) : r * (q + 1) + (xcd - r) * q) + lo;
    const int brow = (wgid / gx) * 128;
    const int bcol = (wgid % gx) * BNT;

    const int tid = threadIdx.x;
    const int w   = tid >> 6;          // wave 0..3
    const int l   = tid & 63;
    const int wr  = w >> 1, wc = w & 1;

    f32x4 acc[4][NFRAG] = {};

    const int srow   = tid >> 2;        // 0..63
    const int schunk = (tid & 3) * 8;   // bf16 offset within BK=32

    for (int k0 = 0; k0 < K; k0 += 32) {
#pragma unroll
        for (int half = 0; half < 2; ++half) {
            int gr = brow + half * 64 + srow;
            if (gr > M - 1) gr = M - 1;                       // clamp (in-bounds dup read)
            const bf16_t* gsrc = A + (long long)gr * K + k0 + schunk;
            GLOAD_LDS16(gsrc, &As[(half * 64 + w * 16) * 32]);
        }
#pragma unroll
        for (int half = 0; half < BHALF; ++half) {
            int rr = half * 64 + srow;
            const bf16_t* gsrc = Bt + (long long)(bcol + rr) * K + k0 + schunk;
            GLOAD_LDS16(gsrc, &Bs[(half * 64 + w * 16) * 32]);
        }
        __syncthreads();

        bf16x8 af[4], bfr[NFRAG];
#pragma unroll
        for (int m = 0; m < 4; ++m) {
            int row = wr * 64 + m * 16 + (l & 15);
            af[m] = *(const bf16x8*)&As[row * 32 + (l >> 4) * 8];
        }
#pragma unroll
        for (int n = 0; n < NFRAG; ++n) {
            int row = wc * WCOFF + n * 16 + (l & 15);
            bfr[n] = *(const bf16x8*)&Bs[row * 32 + (l >> 4) * 8];
        }
#pragma unroll
        for (int m = 0; m < 4; ++m)
#pragma unroll
            for (int n = 0; n < NFRAG; ++n)
                acc[m][n] = __builtin_amdgcn_mfma_f32_16x16x32_bf16(af[m], bfr[n], acc[m][n], 0, 0, 0);
        __syncthreads();
    }

#pragma unroll
    for (int m = 0; m < 4; ++m) {
#pragma unroll
        for (int n = 0; n < NFRAG; ++n) {
            int col = bcol + wc * WCOFF + n * 16 + (l & 15);
            float b = HAS_BIAS ? bias[col] : 0.0f;
#pragma unroll
            for (int j = 0; j < 4; ++j) {
                int row = brow + wr * 64 + m * 16 + (l >> 4) * 4 + j;
                if (row < M) {
                    float v = acc[m][n][j] + b;
                    if (RELU) v = fmaxf(v, 0.0f);
                    if (OUT_BF16) ((bf16_t*)Cout)[(long long)row * N + col] = f2bf(v);
                    else          ((float*)Cout)[(long long)row * N + col] = v;
                }
            }
        }
    }
}

// ---------------------------------------------------------------------------
// Fused GCN aggregation (CSR gather, bf16 h) + bias + ReLU + LN, F = 1536.
// One WAVE per dst row (4 rows/block); lane owns 3 bf16x8 chunks (24 feats).
// Output bf16 (feeds MFMA GEMM only).
// ---------------------------------------------------------------------------
__global__ __launch_bounds__(256) void gcn_agg_ln_h(
    const bf16_t* __restrict__ h, const float* __restrict__ dinv,
    const int* __restrict__ rowptr, const int* __restrict__ csr_src,
    const float* __restrict__ bias, const float* __restrict__ g,
    const float* __restrict__ be, bf16_t* __restrict__ out, int n)
{
    const int row  = blockIdx.x * 4 + (threadIdx.x >> 6);
    const int lane = threadIdx.x & 63;
    if (row >= n) return;
    const float dd = dinv[row];

    float acc[24];
    {
        const bf16x8* hr = (const bf16x8*)(h + (long long)row * HH);
#pragma unroll
        for (int c = 0; c < 3; ++c) {
            bf16x8 v = hr[c * 64 + lane];
#pragma unroll
            for (int j = 0; j < 8; ++j) acc[c * 8 + j] = dd * (float)v[j];
        }
    }
    const int s0 = rowptr[row], s1 = rowptr[row + 1];
    for (int k = s0; k < s1; ++k) {
        const int s = csr_src[k];
        const float w = dinv[s];
        const bf16x8* hs = (const bf16x8*)(h + (long long)s * HH);
#pragma unroll
        for (int c = 0; c < 3; ++c) {
            bf16x8 v = hs[c * 64 + lane];
#pragma unroll
            for (int j = 0; j < 8; ++j) acc[c * 8 + j] += w * (float)v[j];
        }
    }

    float lsum = 0.0f, lsq = 0.0f;
#pragma unroll
    for (int c = 0; c < 3; ++c)
#pragma unroll
        for (int j = 0; j < 8; ++j) {
            int idx = c * 512 + lane * 8 + j;
            float v = fmaxf(acc[c * 8 + j] * dd + bias[idx], 0.0f);
            acc[c * 8 + j] = v;
            lsum += v;
            lsq  += v * v;
        }
#pragma unroll
    for (int off = 32; off > 0; off >>= 1) {
        lsum += __shfl_xor(lsum, off);
        lsq  += __shfl_xor(lsq,  off);
    }
    const float mean = lsum / HH;
    const float var  = lsq / HH - mean * mean;
    const float rstd = rsqrtf(var + 1e-5f);

    bf16_t* y = out + (long long)row * HH;
#pragma unroll
    for (int c = 0; c < 3; ++c)
#pragma unroll
        for (int j = 0; j < 8; ++j) {
            int idx = c * 512 + lane * 8 + j;
            y[idx] = f2bf((acc[c * 8 + j] - mean) * rstd * g[idx] + be[idx]);
        }
}

// Same, F = 64 (fp32 h): one wave per row. Writes fp32 latent (output 0)
// AND bf16 copy (feeds FC1 MFMA).
__global__ __launch_bounds__(256) void gcn_agg_ln_l(
    const float* __restrict__ h, const float* __restrict__ dinv,
    const int* __restrict__ rowptr, const int* __restrict__ csr_src,
    const float* __restrict__ bias, const float* __restrict__ g,
    const float* __restrict__ be, float* __restrict__ out,
    bf16_t* __restrict__ outb, int n)
{
    const int row  = blockIdx.x * 4 + (threadIdx.x >> 6);
    const int lane = threadIdx.x & 63;
    if (row >= n) return;
    const float dd = dinv[row];

    float acc = dd * h[(long long)row * LL + lane];
    const int s0 = rowptr[row], s1 = rowptr[row + 1];
    for (int k = s0; k < s1; ++k) {
        const int s = csr_src[k];
        acc += dinv[s] * h[(long long)s * LL + lane];
    }
    float v = fmaxf(acc * dd + bias[lane], 0.0f);
    float lsum = v, lsq = v * v;
#pragma unroll
    for (int off = 32; off > 0; off >>= 1) {
        lsum += __shfl_xor(lsum, off);
        lsq  += __shfl_xor(lsq,  off);
    }
    const float mean = lsum / LL;
    const float var  = lsq / LL - mean * mean;
    const float rstd = rsqrtf(var + 1e-5f);
    float o = (v - mean) * rstd * g[lane] + be[lane];
    out[(long long)row * LL + lane]  = o;
    outb[(long long)row * LL + lane] = f2bf(o);
}

// ---------------------------------------------------------------------------
// Launch.
// d_out tenancy: out_recon (N*D f32 = 245 MB) hosts h1b (bf16) in its first
//   quarter and hiddenb (bf16) in its second half; both dead before the
//   final recon write.
// ws: dinv|cnt|cursor|rowptr|csr_src | [align 256] | xb (N*D bf16, later
//     decodeb) | W1t | W2t | Wg2t | Wf1t | latentb | wsC (N*L f32) ~= 172 MB.
// ---------------------------------------------------------------------------
extern "C" void kernel_launch(void* const* d_in, const int* in_sizes, int n_in,
                              void* d_out, int out_size, void* d_ws, size_t ws_size,
                              hipStream_t stream)
{
    const float* x     = (const float*)d_in[0];
    const int*   ei    = (const int*)d_in[1];
    const float* W_gc1 = (const float*)d_in[2];
    const float* b_gc1 = (const float*)d_in[3];
    const float* W_gc2 = (const float*)d_in[4];
    const float* b_gc2 = (const float*)d_in[5];
    const float* g1    = (const float*)d_in[6];
    const float* be1   = (const float*)d_in[7];
    const float* g2    = (const float*)d_in[8];
    const float* be2   = (const float*)d_in[9];
    const float* W_fc1 = (const float*)d_in[10];
    const float* b_fc1 = (const float*)d_in[11];
    const float* W_fc2 = (const float*)d_in[12];
    const float* b_fc2 = (const float*)d_in[13];

    float* out_latent = (float*)d_out;                       // [N, L]
    float* out_recon  = (float*)d_out + (long long)NN * LL;  // [N, D]

    bf16_t* h1b     = (bf16_t*)out_recon;                         // N*H bf16
    bf16_t* hiddenb = (bf16_t*)(out_recon + (long long)NN * HH);  // N*H bf16 (2nd half)

    float*  dinv    = (float*)d_ws;                          // N
    int*    cnt     = (int*)(dinv + NN);                     // N
    int*    cursor  = cnt + NN;                              // N
    int*    rowptr  = cursor + NN;                           // N+1
    int*    csr_src = rowptr + NN + 1;                       // E
    // align the bf16 region to 256 B
    char*   pbase   = (char*)(csr_src + EE);
    pbase = (char*)(((size_t)pbase + 255) & ~(size_t)255);
    bf16_t* xb      = (bf16_t*)pbase;                        // N*D bf16 (later decodeb)
    bf16_t* W1t     = xb + (long long)NN * DD;               // H*D bf16 (W_gc1^T)
    bf16_t* W2t     = W1t + (long long)DD * HH;              // D*H bf16 (W_fc2^T)
    bf16_t* Wg2t    = W2t + (long long)DD * HH;              // L*H bf16 (W_gc2^T)
    bf16_t* Wf1t    = Wg2t + (long long)HH * LL;             // H*L bf16 (W_fc1^T)
    bf16_t* latentb = Wf1t + (long long)LL * HH;             // N*L bf16
    float*  wsC     = (float*)(latentb + (long long)NN * LL); // N*L f32 (h2)
    bf16_t* decodeb = xb;                                    // N*H bf16, reuses xb

    // 1) CSR build + dinv
    zero_int<<<(2 * NN + 255) / 256, 256, 0, stream>>>(cnt, 2 * NN);  // cnt + cursor
    cnt_count<<<(EE + 255) / 256, 256, 0, stream>>>(ei, cnt, EE);
    dinv_from_cnt<<<(NN + 255) / 256, 256, 0, stream>>>(cnt, dinv, NN);
    scan_rowptr<<<1, 1024, 0, stream>>>(cnt, rowptr, NN);
    csr_fill<<<(EE + 255) / 256, 256, 0, stream>>>(ei, rowptr, cursor, csr_src, EE);

    // 2) bf16 conversions (x + all four weight transposes)
    cvt_bf16<<<2048, 256, 0, stream>>>((const float4*)x, (ushort4*)xb, (long long)NN * DD / 4);
    {
        dim3 ga(HH / 32, DD / 32);
        cvt_transpose_bf16<<<ga, 256, 0, stream>>>(W_gc1, W1t, DD, HH);
        dim3 gb(DD / 32, HH / 32);
        cvt_transpose_bf16<<<gb, 256, 0, stream>>>(W_fc2, W2t, HH, DD);
        dim3 gc(LL / 32, HH / 32);
        cvt_transpose_bf16<<<gc, 256, 0, stream>>>(W_gc2, Wg2t, HH, LL);
        dim3 gd(HH / 32, LL / 32);
        cvt_transpose_bf16<<<gd, 256, 0, stream>>>(W_fc1, Wf1t, LL, HH);
    }

    const int MB = (NN + 127) / 128;   // 157 row blocks

    // 3) h1b = bf16(xb @ W1t^T)   [N, H]   (MFMA 128x128)
    {
        int gx = HH / 128;
        gemm_bf16_mfma<0, 0, 1, 128><<<gx * MB, 256, 0, stream>>>(xb, W1t, nullptr, h1b, NN, HH, DD, gx);
    }

    // 4) hiddenb = bf16(LN(relu(agg(h1b) + b_gc1)))   (fused gather + LN)
    gcn_agg_ln_h<<<(NN + 3) / 4, 256, 0, stream>>>(h1b, dinv, rowptr, csr_src, b_gc1, g1, be1, hiddenb, NN);

    // 5) h2 = hiddenb @ Wg2t^T    [N, L] f32 -> wsC   (MFMA 128x64)
    gemm_bf16_mfma<0, 0, 0, 64><<<MB, 256, 0, stream>>>(hiddenb, Wg2t, nullptr, wsC, NN, LL, HH, 1);

    // 6) latent = LN(relu(agg(h2) + b_gc2)) -> output 0 (+ bf16 copy)
    gcn_agg_ln_l<<<(NN + 3) / 4, 256, 0, stream>>>(wsC, dinv, rowptr, csr_src, b_gc2, g2, be2, out_latent, latentb, NN);

    // 7) decodeb = bf16(relu(latentb @ Wf1t^T + b_fc1))  [N, H] (MFMA 128x128, K=64)
    {
        int gx = HH / 128;
        gemm_bf16_mfma<1, 1, 1, 128><<<gx * MB, 256, 0, stream>>>(latentb, Wf1t, b_fc1, decodeb, NN, HH, LL, gx);
    }

    // 8) reconstructed = decodeb @ W2t^T + b_fc2  [N, D] -> output 1 (MFMA)
    //    (h1b dead after step 4; hiddenb dead after step 5)
    {
        int gx = DD / 128;
        gemm_bf16_mfma<1, 0, 0, 128><<<gx * MB, 256, 0, stream>>>(decodeb, W2t, b_fc2, out_recon, NN, DD, HH, gx);
    }
}

// Round 8
// 845.655 us; speedup vs baseline: 11.5495x; 1.1289x over previous
//
#include <hip/hip_runtime.h>
#include <hip/hip_bf16.h>

// Problem constants (match reference)
#define NN 20000
#define EE 320000
#define DD 3072
#define HH 1536
#define LL 64

typedef unsigned short bf16_t;
typedef __attribute__((ext_vector_type(8))) __bf16 bf16x8;
typedef __attribute__((ext_vector_type(4))) float  f32x4;

__device__ __forceinline__ bf16_t f2bf(float f) {
    union { float f; unsigned u; } c; c.f = f;
    unsigned u = c.u;
    return (bf16_t)((u + 0x7fffu + ((u >> 16) & 1u)) >> 16);  // RNE (inputs finite)
}

// ---------------------------------------------------------------------------
// CSR build. edge_index is int32: src = ei[e], dst = ei[E+e].
// ---------------------------------------------------------------------------
__global__ void zero_int(int* __restrict__ p, int n) {
    int i = blockIdx.x * blockDim.x + threadIdx.x;
    if (i < n) p[i] = 0;
}

__global__ void cnt_count(const int* __restrict__ ei, int* __restrict__ cnt, int E) {
    int i = blockIdx.x * blockDim.x + threadIdx.x;
    if (i < E) atomicAdd(&cnt[ei[E + i]], 1);
}

__global__ void dinv_from_cnt(const int* __restrict__ cnt, float* __restrict__ dinv, int n) {
    int i = blockIdx.x * blockDim.x + threadIdx.x;
    if (i < n) dinv[i] = rsqrtf((float)(cnt[i] + 1));
}

// single-block exclusive scan (n = 20000, chunked Hillis-Steele)
__global__ __launch_bounds__(1024) void scan_rowptr(const int* __restrict__ cnt,
                                                    int* __restrict__ rowptr, int n)
{
    __shared__ int sdata[1024];
    __shared__ int scarry;
    const int tid = threadIdx.x;
    if (tid == 0) scarry = 0;
    __syncthreads();
    for (int base = 0; base < n; base += 1024) {
        int i = base + tid;
        int v = (i < n) ? cnt[i] : 0;
        int x = v;
        sdata[tid] = x;
        __syncthreads();
#pragma unroll
        for (int off = 1; off < 1024; off <<= 1) {
            int y = (tid >= off) ? sdata[tid - off] : 0;
            __syncthreads();
            x += y;
            sdata[tid] = x;
            __syncthreads();
        }
        if (i < n) rowptr[i] = scarry + x - v;  // exclusive
        int total = sdata[1023];
        __syncthreads();
        if (tid == 0) scarry += total;
        __syncthreads();
    }
    if (tid == 0) rowptr[n] = scarry;
}

__global__ void csr_fill(const int* __restrict__ ei, const int* __restrict__ rowptr,
                         int* __restrict__ cursor, int* __restrict__ csr_src, int E)
{
    int e = blockIdx.x * blockDim.x + threadIdx.x;
    if (e < E) {
        int d = ei[E + e];
        int pos = rowptr[d] + atomicAdd(&cursor[d], 1);
        csr_src[pos] = ei[e];
    }
}

// ---------------------------------------------------------------------------
// fp32 -> bf16 cast (vectorized), and fp32 [R][C] -> bf16 [C][R] transpose
// ---------------------------------------------------------------------------
__global__ void cvt_bf16(const float4* __restrict__ in, ushort4* __restrict__ out, long long n4) {
    for (long long i = (long long)blockIdx.x * blockDim.x + threadIdx.x;
         i < n4; i += (long long)gridDim.x * blockDim.x) {
        float4 v = in[i];
        ushort4 o;
        o.x = f2bf(v.x); o.y = f2bf(v.y); o.z = f2bf(v.z); o.w = f2bf(v.w);
        out[i] = o;
    }
}

__global__ __launch_bounds__(256) void cvt_transpose_bf16(
    const float* __restrict__ in, bf16_t* __restrict__ out, int R, int C)
{
    __shared__ float tile[32][33];
    const int bx = blockIdx.x, by = blockIdx.y;   // bx over C/32, by over R/32
    const int tx = threadIdx.x & 31;
    const int ty = (threadIdx.x >> 5) * 4;
#pragma unroll
    for (int j = 0; j < 4; ++j)
        tile[ty + j][tx] = in[(long long)(by * 32 + ty + j) * C + bx * 32 + tx];
    __syncthreads();
#pragma unroll
    for (int j = 0; j < 4; ++j)
        out[(long long)(bx * 32 + ty + j) * R + by * 32 + tx] = f2bf(tile[tx][ty + j]);
}

#define GLOAD_LDS16(g, l)                                                     \
    __builtin_amdgcn_global_load_lds(                                         \
        (const __attribute__((address_space(1))) unsigned int*)(g),          \
        (__attribute__((address_space(3))) unsigned int*)(l), 16, 0, 0)

// ---------------------------------------------------------------------------
// 8-phase 256x256 BF16 MFMA GEMM (m201-style): C = A[M,K] @ Bt[N,K]^T.
// 512 thr = 8 waves (2 row x 4 col). BK=64, double-buffered LDS (128 KiB),
// st-swizzled (slot ^= row&7 on global src + on ds_read). Per tile: 4 phases
// = 4 C-quadrants (mh,nh); each phase stages one half-tile; single counted
// vmcnt(4) per tile (never 0). Stage schedule (tile t): [t+1.A1, t+1.B1,
// t+2.A0, t+2.B0] -- each region staged only after its last reader's barrier.
// Requires K%64==0, N%256==0; M guarded (clamped reads, guarded writes).
// ---------------------------------------------------------------------------
#define MFMA16(a, b, c) __builtin_amdgcn_mfma_f32_16x16x32_bf16((a), (b), (c), 0, 0, 0)

#define LDA_F(CUR, MH, MF, KS)                                                \
    (*(const bf16x8*)((const char*)(&lds[(CUR)][0][(MH)][0]) +                \
        (arow + (MF) * 16) * 128 + ((KS) ? offk1 : offk0)))
#define LDB_F(CUR, NH, NF, KS)                                                \
    (*(const bf16x8*)((const char*)(&lds[(CUR)][1][(NH)][0]) +                \
        (brw + (NF) * 16) * 128 + ((KS) ? offk1 : offk0)))

#define PHASE(CUR, MH, NH, STAGE_STMT, DOVM)                                   \
    do {                                                                       \
        bf16x8 pa[4][2], pb[2][2];                                             \
        _Pragma("unroll")                                                      \
        for (int mf = 0; mf < 4; ++mf) {                                       \
            pa[mf][0] = LDA_F(CUR, MH, mf, 0);                                 \
            pa[mf][1] = LDA_F(CUR, MH, mf, 1);                                 \
        }                                                                      \
        _Pragma("unroll")                                                      \
        for (int nf = 0; nf < 2; ++nf) {                                       \
            pb[nf][0] = LDB_F(CUR, NH, nf, 0);                                 \
            pb[nf][1] = LDB_F(CUR, NH, nf, 1);                                 \
        }                                                                      \
        STAGE_STMT;                                                            \
        __builtin_amdgcn_sched_barrier(0);                                     \
        __builtin_amdgcn_s_barrier();                                          \
        asm volatile("s_waitcnt lgkmcnt(0)" ::: "memory");                     \
        __builtin_amdgcn_sched_barrier(0);                                     \
        __builtin_amdgcn_s_setprio(1);                                         \
        _Pragma("unroll")                                                      \
        for (int mf = 0; mf < 4; ++mf) {                                       \
            _Pragma("unroll")                                                  \
            for (int nf = 0; nf < 2; ++nf) {                                   \
                acc[MH][NH][mf][nf] = MFMA16(pa[mf][0], pb[nf][0], acc[MH][NH][mf][nf]); \
                acc[MH][NH][mf][nf] = MFMA16(pa[mf][1], pb[nf][1], acc[MH][NH][mf][nf]); \
            }                                                                  \
        }                                                                      \
        __builtin_amdgcn_s_setprio(0);                                         \
        if (DOVM) { asm volatile("s_waitcnt vmcnt(4)" ::: "memory"); }         \
        __builtin_amdgcn_sched_barrier(0);                                     \
        __builtin_amdgcn_s_barrier();                                          \
    } while (0)

template <int HAS_BIAS, int RELU, int OUT_BF16>
__global__ __launch_bounds__(512, 2) void gemm_bf16_8ph(
    const bf16_t* __restrict__ A, const bf16_t* __restrict__ Bt,
    const float* __restrict__ bias, void* __restrict__ Cout,
    int M, int N, int K, int gx)
{
    __shared__ bf16_t lds[2][2][2][8192];   // [buf][A/B][half][128 rows x 64 k] = 128 KiB

    // bijective XCD chunk swizzle
    const int nwg = gridDim.x;
    const int q = nwg >> 3, r = nwg & 7;
    const int xcd = blockIdx.x & 7, lo = blockIdx.x >> 3;
    const int wgid = (xcd < r ? xcd * (q + 1) : r * (q + 1) + (xcd - r) * q) + lo;
    const int brow = (wgid / gx) * 256;
    const int bcol = (wgid % gx) * 256;

    const int tid = threadIdx.x;
    const int w = tid >> 6, l = tid & 63;
    const int wr = w >> 2, wc = w & 3;     // 2 x 4 wave grid
    const int nt = K >> 6;                 // BK=64 tiles

    f32x4 acc[2][2][4][2] = {};

    // staging lane constants: chunk c = w*2+i covers rows c*8..c*8+7 (1 KiB)
    const int srow8 = l >> 3;                         // row within chunk
    const int swz8  = (((l & 7) ^ (l >> 3)) << 3);    // swizzled k-slot (bf16 units)

    auto stage_a = [&](int buf, int h, int s) {
#pragma unroll
        for (int i = 0; i < 2; ++i) {
            const int c = (w << 1) + i;
            int grow = brow + h * 128 + c * 8 + srow8;
            if (grow > M - 1) grow = M - 1;           // clamp (in-bounds dup read)
            const bf16_t* g = A + (long long)grow * K + (s << 6) + swz8;
            GLOAD_LDS16(g, &lds[buf][0][h][c * 512]);
        }
    };
    auto stage_b = [&](int buf, int h, int s) {
#pragma unroll
        for (int i = 0; i < 2; ++i) {
            const int c = (w << 1) + i;
            const int grow = bcol + h * 128 + c * 8 + srow8;   // N%256==0, no clamp
            const bf16_t* g = Bt + (long long)grow * K + (s << 6) + swz8;
            GLOAD_LDS16(g, &lds[buf][1][h][c * 512]);
        }
    };

    // ds_read address constants (read-side swizzle: same involution)
    const int arow  = wr * 64 + (l & 15);
    const int brw   = wc * 32 + (l & 15);
    const int xm    = (l & 7) << 4;
    const int offk0 = ((l >> 4) << 4) ^ xm;
    const int offk1 = (((l >> 4) << 4) + 64) ^ xm;

    // prologue: tile0 complete + tile1 A0,B0  (12 loads; vmcnt(4) -> tile0 landed)
    stage_a(0, 0, 0); stage_b(0, 0, 0);
    stage_a(0, 1, 0); stage_b(0, 1, 0);
    stage_a(1, 0, 1); stage_b(1, 0, 1);
    __builtin_amdgcn_sched_barrier(0);
    asm volatile("s_waitcnt vmcnt(4)" ::: "memory");
    __builtin_amdgcn_sched_barrier(0);
    __builtin_amdgcn_s_barrier();

    int cur = 0;
    for (int t = 0; t < nt; ++t) {
        const int t1 = (t + 1 < nt) ? t + 1 : nt - 1;
        const int t2 = (t + 2 < nt) ? t + 2 : nt - 1;
        PHASE(cur, 0, 0, stage_a(cur ^ 1, 1, t1), 0);  // reads A0,B0; stage t+1.A1
        PHASE(cur, 0, 1, stage_b(cur ^ 1, 1, t1), 0);  // reads A0,B1; stage t+1.B1
        PHASE(cur, 1, 0, stage_a(cur,     0, t2), 0);  // reads A1,B0; stage t+2.A0
        PHASE(cur, 1, 1, stage_b(cur,     0, t2), 1);  // reads A1,B1; stage t+2.B0 + vmcnt(4)
        cur ^= 1;
    }

    // epilogue: C/D layout col=lane&15, row=(lane>>4)*4+j per 16x16 frag
#pragma unroll
    for (int mh = 0; mh < 2; ++mh) {
#pragma unroll
        for (int nh = 0; nh < 2; ++nh) {
#pragma unroll
            for (int nf = 0; nf < 2; ++nf) {
                const int col = bcol + nh * 128 + wc * 32 + nf * 16 + (l & 15);
                const float bv = HAS_BIAS ? bias[col] : 0.0f;
#pragma unroll
                for (int mf = 0; mf < 4; ++mf) {
#pragma unroll
                    for (int j = 0; j < 4; ++j) {
                        const int row = brow + mh * 128 + wr * 64 + mf * 16 + (l >> 4) * 4 + j;
                        if (row < M) {
                            float v = acc[mh][nh][mf][nf][j] + bv;
                            if (RELU) v = fmaxf(v, 0.0f);
                            if (OUT_BF16) ((bf16_t*)Cout)[(long long)row * N + col] = f2bf(v);
                            else          ((float*)Cout)[(long long)row * N + col] = v;
                        }
                    }
                }
            }
        }
    }
}

// ---------------------------------------------------------------------------
// m97-structure BF16 MFMA GEMM (kept for the two small GEMMs):
// C[M,N] = A[M,K] @ Bt[N,K]^T (+bias)(+relu), fp32 or bf16 out.
// ---------------------------------------------------------------------------
template <int HAS_BIAS, int RELU, int OUT_BF16, int BNT>
__global__ __launch_bounds__(256) void gemm_bf16_mfma(
    const bf16_t* __restrict__ A, const bf16_t* __restrict__ Bt,
    const float* __restrict__ bias, void* __restrict__ Cout,
    int M, int N, int K, int gx)
{
    constexpr int NFRAG = BNT / 32;
    constexpr int BHALF = BNT / 64;
    constexpr int WCOFF = BNT / 2;

    __shared__ bf16_t As[128 * 32];
    __shared__ bf16_t Bs[BNT * 32];

    const int nwg = gridDim.x;
    const int q = nwg >> 3, r = nwg & 7;
    const int xcd = blockIdx.x & 7, lo = blockIdx.x >> 3;
    const int wgid = (xcd < r ? xcd * (q + 1) : r * (q + 1) + (xcd - r) * q) + lo;
    const int brow = (wgid / gx) * 128;
    const int bcol = (wgid % gx) * BNT;

    const int tid = threadIdx.x;
    const int w   = tid >> 6;
    const int l   = tid & 63;
    const int wr  = w >> 1, wc = w & 1;

    f32x4 acc[4][NFRAG] = {};

    const int srow   = tid >> 2;
    const int schunk = (tid & 3) * 8;

    for (int k0 = 0; k0 < K; k0 += 32) {
#pragma unroll
        for (int half = 0; half < 2; ++half) {
            int gr = brow + half * 64 + srow;
            if (gr > M - 1) gr = M - 1;
            const bf16_t* gsrc = A + (long long)gr * K + k0 + schunk;
            GLOAD_LDS16(gsrc, &As[(half * 64 + w * 16) * 32]);
        }
#pragma unroll
        for (int half = 0; half < BHALF; ++half) {
            int rr = half * 64 + srow;
            const bf16_t* gsrc = Bt + (long long)(bcol + rr) * K + k0 + schunk;
            GLOAD_LDS16(gsrc, &Bs[(half * 64 + w * 16) * 32]);
        }
        __syncthreads();

        bf16x8 af[4], bfr[NFRAG];
#pragma unroll
        for (int m = 0; m < 4; ++m) {
            int row = wr * 64 + m * 16 + (l & 15);
            af[m] = *(const bf16x8*)&As[row * 32 + (l >> 4) * 8];
        }
#pragma unroll
        for (int n = 0; n < NFRAG; ++n) {
            int row = wc * WCOFF + n * 16 + (l & 15);
            bfr[n] = *(const bf16x8*)&Bs[row * 32 + (l >> 4) * 8];
        }
#pragma unroll
        for (int m = 0; m < 4; ++m)
#pragma unroll
            for (int n = 0; n < NFRAG; ++n)
                acc[m][n] = MFMA16(af[m], bfr[n], acc[m][n]);
        __syncthreads();
    }

#pragma unroll
    for (int m = 0; m < 4; ++m) {
#pragma unroll
        for (int n = 0; n < NFRAG; ++n) {
            int col = bcol + wc * WCOFF + n * 16 + (l & 15);
            float b = HAS_BIAS ? bias[col] : 0.0f;
#pragma unroll
            for (int j = 0; j < 4; ++j) {
                int row = brow + wr * 64 + m * 16 + (l >> 4) * 4 + j;
                if (row < M) {
                    float v = acc[m][n][j] + b;
                    if (RELU) v = fmaxf(v, 0.0f);
                    if (OUT_BF16) ((bf16_t*)Cout)[(long long)row * N + col] = f2bf(v);
                    else          ((float*)Cout)[(long long)row * N + col] = v;
                }
            }
        }
    }
}

// ---------------------------------------------------------------------------
// Fused GCN aggregation (CSR gather, bf16 h) + bias + ReLU + LN, F = 1536.
// One WAVE per dst row (4 rows/block); lane owns 3 bf16x8 chunks (24 feats).
// ---------------------------------------------------------------------------
__global__ __launch_bounds__(256) void gcn_agg_ln_h(
    const bf16_t* __restrict__ h, const float* __restrict__ dinv,
    const int* __restrict__ rowptr, const int* __restrict__ csr_src,
    const float* __restrict__ bias, const float* __restrict__ g,
    const float* __restrict__ be, bf16_t* __restrict__ out, int n)
{
    const int row  = blockIdx.x * 4 + (threadIdx.x >> 6);
    const int lane = threadIdx.x & 63;
    if (row >= n) return;
    const float dd = dinv[row];

    float acc[24];
    {
        const bf16x8* hr = (const bf16x8*)(h + (long long)row * HH);
#pragma unroll
        for (int c = 0; c < 3; ++c) {
            bf16x8 v = hr[c * 64 + lane];
#pragma unroll
            for (int j = 0; j < 8; ++j) acc[c * 8 + j] = dd * (float)v[j];
        }
    }
    const int s0 = rowptr[row], s1 = rowptr[row + 1];
    for (int k = s0; k < s1; ++k) {
        const int s = csr_src[k];
        const float w = dinv[s];
        const bf16x8* hs = (const bf16x8*)(h + (long long)s * HH);
#pragma unroll
        for (int c = 0; c < 3; ++c) {
            bf16x8 v = hs[c * 64 + lane];
#pragma unroll
            for (int j = 0; j < 8; ++j) acc[c * 8 + j] += w * (float)v[j];
        }
    }

    float lsum = 0.0f, lsq = 0.0f;
#pragma unroll
    for (int c = 0; c < 3; ++c)
#pragma unroll
        for (int j = 0; j < 8; ++j) {
            int idx = c * 512 + lane * 8 + j;
            float v = fmaxf(acc[c * 8 + j] * dd + bias[idx], 0.0f);
            acc[c * 8 + j] = v;
            lsum += v;
            lsq  += v * v;
        }
#pragma unroll
    for (int off = 32; off > 0; off >>= 1) {
        lsum += __shfl_xor(lsum, off);
        lsq  += __shfl_xor(lsq,  off);
    }
    const float mean = lsum / HH;
    const float var  = lsq / HH - mean * mean;
    const float rstd = rsqrtf(var + 1e-5f);

    bf16_t* y = out + (long long)row * HH;
#pragma unroll
    for (int c = 0; c < 3; ++c)
#pragma unroll
        for (int j = 0; j < 8; ++j) {
            int idx = c * 512 + lane * 8 + j;
            y[idx] = f2bf((acc[c * 8 + j] - mean) * rstd * g[idx] + be[idx]);
        }
}

// Same, F = 64 (fp32 h): writes fp32 latent (output 0) AND bf16 copy.
__global__ __launch_bounds__(256) void gcn_agg_ln_l(
    const float* __restrict__ h, const float* __restrict__ dinv,
    const int* __restrict__ rowptr, const int* __restrict__ csr_src,
    const float* __restrict__ bias, const float* __restrict__ g,
    const float* __restrict__ be, float* __restrict__ out,
    bf16_t* __restrict__ outb, int n)
{
    const int row  = blockIdx.x * 4 + (threadIdx.x >> 6);
    const int lane = threadIdx.x & 63;
    if (row >= n) return;
    const float dd = dinv[row];

    float acc = dd * h[(long long)row * LL + lane];
    const int s0 = rowptr[row], s1 = rowptr[row + 1];
    for (int k = s0; k < s1; ++k) {
        const int s = csr_src[k];
        acc += dinv[s] * h[(long long)s * LL + lane];
    }
    float v = fmaxf(acc * dd + bias[lane], 0.0f);
    float lsum = v, lsq = v * v;
#pragma unroll
    for (int off = 32; off > 0; off >>= 1) {
        lsum += __shfl_xor(lsum, off);
        lsq  += __shfl_xor(lsq,  off);
    }
    const float mean = lsum / LL;
    const float var  = lsq / LL - mean * mean;
    const float rstd = rsqrtf(var + 1e-5f);
    float o = (v - mean) * rstd * g[lane] + be[lane];
    out[(long long)row * LL + lane]  = o;
    outb[(long long)row * LL + lane] = f2bf(o);
}

// ---------------------------------------------------------------------------
// Launch.
// ---------------------------------------------------------------------------
extern "C" void kernel_launch(void* const* d_in, const int* in_sizes, int n_in,
                              void* d_out, int out_size, void* d_ws, size_t ws_size,
                              hipStream_t stream)
{
    const float* x     = (const float*)d_in[0];
    const int*   ei    = (const int*)d_in[1];
    const float* W_gc1 = (const float*)d_in[2];
    const float* b_gc1 = (const float*)d_in[3];
    const float* W_gc2 = (const float*)d_in[4];
    const float* b_gc2 = (const float*)d_in[5];
    const float* g1    = (const float*)d_in[6];
    const float* be1   = (const float*)d_in[7];
    const float* g2    = (const float*)d_in[8];
    const float* be2   = (const float*)d_in[9];
    const float* W_fc1 = (const float*)d_in[10];
    const float* b_fc1 = (const float*)d_in[11];
    const float* W_fc2 = (const float*)d_in[12];
    const float* b_fc2 = (const float*)d_in[13];

    float* out_latent = (float*)d_out;                       // [N, L]
    float* out_recon  = (float*)d_out + (long long)NN * LL;  // [N, D]

    bf16_t* h1b     = (bf16_t*)out_recon;                         // N*H bf16
    bf16_t* hiddenb = (bf16_t*)(out_recon + (long long)NN * HH);  // N*H bf16 (2nd half)

    float*  dinv    = (float*)d_ws;                          // N
    int*    cnt     = (int*)(dinv + NN);                     // N
    int*    cursor  = cnt + NN;                              // N
    int*    rowptr  = cursor + NN;                           // N+1
    int*    csr_src = rowptr + NN + 1;                       // E
    char*   pbase   = (char*)(csr_src + EE);
    pbase = (char*)(((size_t)pbase + 255) & ~(size_t)255);
    bf16_t* xb      = (bf16_t*)pbase;                        // N*D bf16 (later decodeb)
    bf16_t* W1t     = xb + (long long)NN * DD;               // H*D bf16 (W_gc1^T)
    bf16_t* W2t     = W1t + (long long)DD * HH;              // D*H bf16 (W_fc2^T)
    bf16_t* Wg2t    = W2t + (long long)DD * HH;              // L*H bf16 (W_gc2^T)
    bf16_t* Wf1t    = Wg2t + (long long)HH * LL;             // H*L bf16 (W_fc1^T)
    bf16_t* latentb = Wf1t + (long long)LL * HH;             // N*L bf16
    float*  wsC     = (float*)(latentb + (long long)NN * LL); // N*L f32 (h2)
    bf16_t* decodeb = xb;                                    // N*H bf16, reuses xb

    // 1) CSR build + dinv
    zero_int<<<(2 * NN + 255) / 256, 256, 0, stream>>>(cnt, 2 * NN);
    cnt_count<<<(EE + 255) / 256, 256, 0, stream>>>(ei, cnt, EE);
    dinv_from_cnt<<<(NN + 255) / 256, 256, 0, stream>>>(cnt, dinv, NN);
    scan_rowptr<<<1, 1024, 0, stream>>>(cnt, rowptr, NN);
    csr_fill<<<(EE + 255) / 256, 256, 0, stream>>>(ei, rowptr, cursor, csr_src, EE);

    // 2) bf16 conversions
    cvt_bf16<<<2048, 256, 0, stream>>>((const float4*)x, (ushort4*)xb, (long long)NN * DD / 4);
    {
        dim3 ga(HH / 32, DD / 32);
        cvt_transpose_bf16<<<ga, 256, 0, stream>>>(W_gc1, W1t, DD, HH);
        dim3 gb(DD / 32, HH / 32);
        cvt_transpose_bf16<<<gb, 256, 0, stream>>>(W_fc2, W2t, HH, DD);
        dim3 gc(LL / 32, HH / 32);
        cvt_transpose_bf16<<<gc, 256, 0, stream>>>(W_gc2, Wg2t, HH, LL);
        dim3 gd(HH / 32, LL / 32);
        cvt_transpose_bf16<<<gd, 256, 0, stream>>>(W_fc1, Wf1t, LL, HH);
    }

    const int MB128 = (NN + 127) / 128;   // 157
    const int MB256 = (NN + 255) / 256;   // 79

    // 3) h1b = bf16(xb @ W1t^T)   [N, H]   (8-phase 256x256)
    {
        int gx = HH / 256;   // 6
        gemm_bf16_8ph<0, 0, 1><<<gx * MB256, 512, 0, stream>>>(xb, W1t, nullptr, h1b, NN, HH, DD, gx);
    }

    // 4) hiddenb = bf16(LN(relu(agg(h1b) + b_gc1)))
    gcn_agg_ln_h<<<(NN + 3) / 4, 256, 0, stream>>>(h1b, dinv, rowptr, csr_src, b_gc1, g1, be1, hiddenb, NN);

    // 5) h2 = hiddenb @ Wg2t^T    [N, L] f32 -> wsC   (MFMA 128x64)
    gemm_bf16_mfma<0, 0, 0, 64><<<MB128, 256, 0, stream>>>(hiddenb, Wg2t, nullptr, wsC, NN, LL, HH, 1);

    // 6) latent = LN(relu(agg(h2) + b_gc2)) -> output 0 (+ bf16 copy)
    gcn_agg_ln_l<<<(NN + 3) / 4, 256, 0, stream>>>(wsC, dinv, rowptr, csr_src, b_gc2, g2, be2, out_latent, latentb, NN);

    // 7) decodeb = bf16(relu(latentb @ Wf1t^T + b_fc1))  [N, H] (MFMA 128x128, K=64)
    {
        int gx = HH / 128;
        gemm_bf16_mfma<1, 1, 1, 128><<<gx * MB128, 256, 0, stream>>>(latentb, Wf1t, b_fc1, decodeb, NN, HH, LL, gx);
    }

    // 8) reconstructed = decodeb @ W2t^T + b_fc2  [N, D] -> output 1 (8-phase)
    {
        int gx = DD / 256;   // 12
        gemm_bf16_8ph<1, 0, 0><<<gx * MB256, 512, 0, stream>>>(decodeb, W2t, b_fc2, out_recon, NN, DD, HH, gx);
    }
}

// Round 9
// 804.053 us; speedup vs baseline: 12.1471x; 1.0517x over previous
//
#include <hip/hip_runtime.h>
#include <hip/hip_bf16.h>

// Problem constants (match reference)
#define NN 20000
#define EE 320000
#define DD 3072
#define HH 1536
#define LL 64

typedef unsigned short bf16_t;
typedef __attribute__((ext_vector_type(8))) __bf16 bf16x8;
typedef __attribute__((ext_vector_type(4))) float  f32x4;

__device__ __forceinline__ bf16_t f2bf(float f) {
    union { float f; unsigned u; } c; c.f = f;
    unsigned u = c.u;
    return (bf16_t)((u + 0x7fffu + ((u >> 16) & 1u)) >> 16);  // RNE (inputs finite)
}

// ---------------------------------------------------------------------------
// CSR build. edge_index is int32: src = ei[e], dst = ei[E+e].
// ---------------------------------------------------------------------------
__global__ void zero_int(int* __restrict__ p, int n) {
    int i = blockIdx.x * blockDim.x + threadIdx.x;
    if (i < n) p[i] = 0;
}

__global__ void cnt_count(const int* __restrict__ ei, int* __restrict__ cnt, int E) {
    int i = blockIdx.x * blockDim.x + threadIdx.x;
    if (i < E) atomicAdd(&cnt[ei[E + i]], 1);
}

__global__ void dinv_from_cnt(const int* __restrict__ cnt, float* __restrict__ dinv, int n) {
    int i = blockIdx.x * blockDim.x + threadIdx.x;
    if (i < n) dinv[i] = rsqrtf((float)(cnt[i] + 1));
}

// single-block exclusive scan (n = 20000, chunked Hillis-Steele)
__global__ __launch_bounds__(1024) void scan_rowptr(const int* __restrict__ cnt,
                                                    int* __restrict__ rowptr, int n)
{
    __shared__ int sdata[1024];
    __shared__ int scarry;
    const int tid = threadIdx.x;
    if (tid == 0) scarry = 0;
    __syncthreads();
    for (int base = 0; base < n; base += 1024) {
        int i = base + tid;
        int v = (i < n) ? cnt[i] : 0;
        int x = v;
        sdata[tid] = x;
        __syncthreads();
#pragma unroll
        for (int off = 1; off < 1024; off <<= 1) {
            int y = (tid >= off) ? sdata[tid - off] : 0;
            __syncthreads();
            x += y;
            sdata[tid] = x;
            __syncthreads();
        }
        if (i < n) rowptr[i] = scarry + x - v;  // exclusive
        int total = sdata[1023];
        __syncthreads();
        if (tid == 0) scarry += total;
        __syncthreads();
    }
    if (tid == 0) rowptr[n] = scarry;
}

__global__ void csr_fill(const int* __restrict__ ei, const int* __restrict__ rowptr,
                         int* __restrict__ cursor, int* __restrict__ csr_src, int E)
{
    int e = blockIdx.x * blockDim.x + threadIdx.x;
    if (e < E) {
        int d = ei[E + e];
        int pos = rowptr[d] + atomicAdd(&cursor[d], 1);
        csr_src[pos] = ei[e];
    }
}

// ---------------------------------------------------------------------------
// fp32 -> bf16 cast (vectorized), and fp32 [R][C] -> bf16 [C][R] transpose
// ---------------------------------------------------------------------------
__global__ void cvt_bf16(const float4* __restrict__ in, ushort4* __restrict__ out, long long n4) {
    for (long long i = (long long)blockIdx.x * blockDim.x + threadIdx.x;
         i < n4; i += (long long)gridDim.x * blockDim.x) {
        float4 v = in[i];
        ushort4 o;
        o.x = f2bf(v.x); o.y = f2bf(v.y); o.z = f2bf(v.z); o.w = f2bf(v.w);
        out[i] = o;
    }
}

__global__ __launch_bounds__(256) void cvt_transpose_bf16(
    const float* __restrict__ in, bf16_t* __restrict__ out, int R, int C)
{
    __shared__ float tile[32][33];
    const int bx = blockIdx.x, by = blockIdx.y;   // bx over C/32, by over R/32
    const int tx = threadIdx.x & 31;
    const int ty = (threadIdx.x >> 5) * 4;
#pragma unroll
    for (int j = 0; j < 4; ++j)
        tile[ty + j][tx] = in[(long long)(by * 32 + ty + j) * C + bx * 32 + tx];
    __syncthreads();
#pragma unroll
    for (int j = 0; j < 4; ++j)
        out[(long long)(bx * 32 + ty + j) * R + by * 32 + tx] = f2bf(tile[tx][ty + j]);
}

#define GLOAD_LDS16(g, l)                                                     \
    __builtin_amdgcn_global_load_lds(                                         \
        (const __attribute__((address_space(1))) unsigned int*)(g),          \
        (__attribute__((address_space(3))) unsigned int*)(l), 16, 0, 0)

// ---------------------------------------------------------------------------
// 8-phase 256x256 BF16 MFMA GEMM, snake quadrant order with operand holding:
// per tile: P1(0,0) reads A0+B0 (12); P2(0,1) reads B1 only (A0 held, 4);
// P3(1,1) reads A1 only (B1 held, 8); P4(1,0) reads B0 (A1 held, 4).
// 28 ds_read_b128/tile/wave vs 48 in the naive quadrant scheme -> LDS pipe
// no longer 1.9x oversubscribed vs MFMA. Staging/vmcnt identical to r8.
// ---------------------------------------------------------------------------
#define MFMA16(a, b, c) __builtin_amdgcn_mfma_f32_16x16x32_bf16((a), (b), (c), 0, 0, 0)

#define LDA_F(CUR, MH, MF, KS)                                                \
    (*(const bf16x8*)((const char*)(&lds[(CUR)][0][(MH)][0]) +                \
        (arow + (MF) * 16) * 128 + ((KS) ? offk1 : offk0)))
#define LDB_F(CUR, NH, NF, KS)                                                \
    (*(const bf16x8*)((const char*)(&lds[(CUR)][1][(NH)][0]) +                \
        (brw + (NF) * 16) * 128 + ((KS) ? offk1 : offk0)))

#define READ_A(CUR, MH)                                                        \
    _Pragma("unroll")                                                          \
    for (int mf = 0; mf < 4; ++mf) {                                           \
        pa[mf][0] = LDA_F(CUR, MH, mf, 0);                                     \
        pa[mf][1] = LDA_F(CUR, MH, mf, 1);                                     \
    }

#define READ_B(CUR, NH)                                                        \
    _Pragma("unroll")                                                          \
    for (int nf = 0; nf < 2; ++nf) {                                           \
        pb[nf][0] = LDB_F(CUR, NH, nf, 0);                                     \
        pb[nf][1] = LDB_F(CUR, NH, nf, 1);                                     \
    }

#define PHASE_TAIL(MH, NH, STAGE_STMT, DOVM)                                   \
    do {                                                                       \
        STAGE_STMT;                                                            \
        __builtin_amdgcn_sched_barrier(0);                                     \
        __builtin_amdgcn_s_barrier();                                          \
        asm volatile("s_waitcnt lgkmcnt(0)" ::: "memory");                     \
        __builtin_amdgcn_sched_barrier(0);                                     \
        __builtin_amdgcn_s_setprio(1);                                         \
        _Pragma("unroll")                                                      \
        for (int mf = 0; mf < 4; ++mf) {                                       \
            _Pragma("unroll")                                                  \
            for (int nf = 0; nf < 2; ++nf) {                                   \
                acc[MH][NH][mf][nf] = MFMA16(pa[mf][0], pb[nf][0], acc[MH][NH][mf][nf]); \
                acc[MH][NH][mf][nf] = MFMA16(pa[mf][1], pb[nf][1], acc[MH][NH][mf][nf]); \
            }                                                                  \
        }                                                                      \
        __builtin_amdgcn_s_setprio(0);                                         \
        if (DOVM) { asm volatile("s_waitcnt vmcnt(4)" ::: "memory"); }         \
        __builtin_amdgcn_sched_barrier(0);                                     \
        __builtin_amdgcn_s_barrier();                                          \
    } while (0)

template <int HAS_BIAS, int RELU, int OUT_BF16>
__global__ __launch_bounds__(512, 2) void gemm_bf16_8ph(
    const bf16_t* __restrict__ A, const bf16_t* __restrict__ Bt,
    const float* __restrict__ bias, void* __restrict__ Cout,
    int M, int N, int K, int gx)
{
    __shared__ bf16_t lds[2][2][2][8192];   // [buf][A/B][half][128 rows x 64 k] = 128 KiB

    // bijective XCD chunk swizzle
    const int nwg = gridDim.x;
    const int q = nwg >> 3, r = nwg & 7;
    const int xcd = blockIdx.x & 7, lo = blockIdx.x >> 3;
    const int wgid = (xcd < r ? xcd * (q + 1) : r * (q + 1) + (xcd - r) * q) + lo;
    const int brow = (wgid / gx) * 256;
    const int bcol = (wgid % gx) * 256;

    const int tid = threadIdx.x;
    const int w = tid >> 6, l = tid & 63;
    const int wr = w >> 2, wc = w & 3;     // 2 x 4 wave grid
    const int nt = K >> 6;                 // BK=64 tiles

    f32x4 acc[2][2][4][2] = {};

    // staging lane constants: chunk c = w*2+i covers rows c*8..c*8+7 (1 KiB)
    const int srow8 = l >> 3;                         // row within chunk
    const int swz8  = (((l & 7) ^ (l >> 3)) << 3);    // swizzled k-slot (bf16 units)

    auto stage_a = [&](int buf, int h, int s) {
#pragma unroll
        for (int i = 0; i < 2; ++i) {
            const int c = (w << 1) + i;
            int grow = brow + h * 128 + c * 8 + srow8;
            if (grow > M - 1) grow = M - 1;           // clamp (in-bounds dup read)
            const bf16_t* g = A + (long long)grow * K + (s << 6) + swz8;
            GLOAD_LDS16(g, &lds[buf][0][h][c * 512]);
        }
    };
    auto stage_b = [&](int buf, int h, int s) {
#pragma unroll
        for (int i = 0; i < 2; ++i) {
            const int c = (w << 1) + i;
            const int grow = bcol + h * 128 + c * 8 + srow8;   // N%256==0, no clamp
            const bf16_t* g = Bt + (long long)grow * K + (s << 6) + swz8;
            GLOAD_LDS16(g, &lds[buf][1][h][c * 512]);
        }
    };

    // ds_read address constants (read-side swizzle: same involution)
    const int arow  = wr * 64 + (l & 15);
    const int brw   = wc * 32 + (l & 15);
    const int xm    = (l & 7) << 4;
    const int offk0 = ((l >> 4) << 4) ^ xm;
    const int offk1 = (((l >> 4) << 4) + 64) ^ xm;

    // prologue: tile0 complete + tile1 A0,B0  (12 loads; vmcnt(4) -> tile0 landed)
    stage_a(0, 0, 0); stage_b(0, 0, 0);
    stage_a(0, 1, 0); stage_b(0, 1, 0);
    stage_a(1, 0, 1); stage_b(1, 0, 1);
    __builtin_amdgcn_sched_barrier(0);
    asm volatile("s_waitcnt vmcnt(4)" ::: "memory");
    __builtin_amdgcn_sched_barrier(0);
    __builtin_amdgcn_s_barrier();

    int cur = 0;
    for (int t = 0; t < nt; ++t) {
        const int t1 = (t + 1 < nt) ? t + 1 : nt - 1;
        const int t2 = (t + 2 < nt) ? t + 2 : nt - 1;
        bf16x8 pa[4][2], pb[2][2];
        // P1 (0,0): read A0+B0; stage t+1.A1
        READ_A(cur, 0); READ_B(cur, 0);
        PHASE_TAIL(0, 0, stage_a(cur ^ 1, 1, t1), 0);
        // P2 (0,1): read B1 (A0 held); stage t+1.B1
        READ_B(cur, 1);
        PHASE_TAIL(0, 1, stage_b(cur ^ 1, 1, t1), 0);
        // P3 (1,1): read A1 (B1 held); stage t+2.A0
        READ_A(cur, 1);
        PHASE_TAIL(1, 1, stage_a(cur, 0, t2), 0);
        // P4 (1,0): read B0 (A1 held); stage t+2.B0 + vmcnt(4)
        READ_B(cur, 0);
        PHASE_TAIL(1, 0, stage_b(cur, 0, t2), 1);
        cur ^= 1;
    }

    // epilogue: C/D layout col=lane&15, row=(lane>>4)*4+j per 16x16 frag
#pragma unroll
    for (int mh = 0; mh < 2; ++mh) {
#pragma unroll
        for (int nh = 0; nh < 2; ++nh) {
#pragma unroll
            for (int nf = 0; nf < 2; ++nf) {
                const int col = bcol + nh * 128 + wc * 32 + nf * 16 + (l & 15);
                const float bv = HAS_BIAS ? bias[col] : 0.0f;
#pragma unroll
                for (int mf = 0; mf < 4; ++mf) {
#pragma unroll
                    for (int j = 0; j < 4; ++j) {
                        const int row = brow + mh * 128 + wr * 64 + mf * 16 + (l >> 4) * 4 + j;
                        if (row < M) {
                            float v = acc[mh][nh][mf][nf][j] + bv;
                            if (RELU) v = fmaxf(v, 0.0f);
                            if (OUT_BF16) ((bf16_t*)Cout)[(long long)row * N + col] = f2bf(v);
                            else          ((float*)Cout)[(long long)row * N + col] = v;
                        }
                    }
                }
            }
        }
    }
}

// ---------------------------------------------------------------------------
// m97-structure BF16 MFMA GEMM (kept for the two small GEMMs):
// C[M,N] = A[M,K] @ Bt[N,K]^T (+bias)(+relu), fp32 or bf16 out.
// ---------------------------------------------------------------------------
template <int HAS_BIAS, int RELU, int OUT_BF16, int BNT>
__global__ __launch_bounds__(256) void gemm_bf16_mfma(
    const bf16_t* __restrict__ A, const bf16_t* __restrict__ Bt,
    const float* __restrict__ bias, void* __restrict__ Cout,
    int M, int N, int K, int gx)
{
    constexpr int NFRAG = BNT / 32;
    constexpr int BHALF = BNT / 64;
    constexpr int WCOFF = BNT / 2;

    __shared__ bf16_t As[128 * 32];
    __shared__ bf16_t Bs[BNT * 32];

    const int nwg = gridDim.x;
    const int q = nwg >> 3, r = nwg & 7;
    const int xcd = blockIdx.x & 7, lo = blockIdx.x >> 3;
    const int wgid = (xcd < r ? xcd * (q + 1) : r * (q + 1) + (xcd - r) * q) + lo;
    const int brow = (wgid / gx) * 128;
    const int bcol = (wgid % gx) * BNT;

    const int tid = threadIdx.x;
    const int w   = tid >> 6;
    const int l   = tid & 63;
    const int wr  = w >> 1, wc = w & 1;

    f32x4 acc[4][NFRAG] = {};

    const int srow   = tid >> 2;
    const int schunk = (tid & 3) * 8;

    for (int k0 = 0; k0 < K; k0 += 32) {
#pragma unroll
        for (int half = 0; half < 2; ++half) {
            int gr = brow + half * 64 + srow;
            if (gr > M - 1) gr = M - 1;
            const bf16_t* gsrc = A + (long long)gr * K + k0 + schunk;
            GLOAD_LDS16(gsrc, &As[(half * 64 + w * 16) * 32]);
        }
#pragma unroll
        for (int half = 0; half < BHALF; ++half) {
            int rr = half * 64 + srow;
            const bf16_t* gsrc = Bt + (long long)(bcol + rr) * K + k0 + schunk;
            GLOAD_LDS16(gsrc, &Bs[(half * 64 + w * 16) * 32]);
        }
        __syncthreads();

        bf16x8 af[4], bfr[NFRAG];
#pragma unroll
        for (int m = 0; m < 4; ++m) {
            int row = wr * 64 + m * 16 + (l & 15);
            af[m] = *(const bf16x8*)&As[row * 32 + (l >> 4) * 8];
        }
#pragma unroll
        for (int n = 0; n < NFRAG; ++n) {
            int row = wc * WCOFF + n * 16 + (l & 15);
            bfr[n] = *(const bf16x8*)&Bs[row * 32 + (l >> 4) * 8];
        }
#pragma unroll
        for (int m = 0; m < 4; ++m)
#pragma unroll
            for (int n = 0; n < NFRAG; ++n)
                acc[m][n] = MFMA16(af[m], bfr[n], acc[m][n]);
        __syncthreads();
    }

#pragma unroll
    for (int m = 0; m < 4; ++m) {
#pragma unroll
        for (int n = 0; n < NFRAG; ++n) {
            int col = bcol + wc * WCOFF + n * 16 + (l & 15);
            float b = HAS_BIAS ? bias[col] : 0.0f;
#pragma unroll
            for (int j = 0; j < 4; ++j) {
                int row = brow + wr * 64 + m * 16 + (l >> 4) * 4 + j;
                if (row < M) {
                    float v = acc[m][n][j] + b;
                    if (RELU) v = fmaxf(v, 0.0f);
                    if (OUT_BF16) ((bf16_t*)Cout)[(long long)row * N + col] = f2bf(v);
                    else          ((float*)Cout)[(long long)row * N + col] = v;
                }
            }
        }
    }
}

// ---------------------------------------------------------------------------
// Fused GCN aggregation (CSR gather, bf16 h) + bias + ReLU + LN, F = 1536.
// One WAVE per dst row (4 rows/block); lane owns 3 bf16x8 chunks (24 feats).
// ---------------------------------------------------------------------------
__global__ __launch_bounds__(256) void gcn_agg_ln_h(
    const bf16_t* __restrict__ h, const float* __restrict__ dinv,
    const int* __restrict__ rowptr, const int* __restrict__ csr_src,
    const float* __restrict__ bias, const float* __restrict__ g,
    const float* __restrict__ be, bf16_t* __restrict__ out, int n)
{
    const int row  = blockIdx.x * 4 + (threadIdx.x >> 6);
    const int lane = threadIdx.x & 63;
    if (row >= n) return;
    const float dd = dinv[row];

    float acc[24];
    {
        const bf16x8* hr = (const bf16x8*)(h + (long long)row * HH);
#pragma unroll
        for (int c = 0; c < 3; ++c) {
            bf16x8 v = hr[c * 64 + lane];
#pragma unroll
            for (int j = 0; j < 8; ++j) acc[c * 8 + j] = dd * (float)v[j];
        }
    }
    const int s0 = rowptr[row], s1 = rowptr[row + 1];
    for (int k = s0; k < s1; ++k) {
        const int s = csr_src[k];
        const float w = dinv[s];
        const bf16x8* hs = (const bf16x8*)(h + (long long)s * HH);
#pragma unroll
        for (int c = 0; c < 3; ++c) {
            bf16x8 v = hs[c * 64 + lane];
#pragma unroll
            for (int j = 0; j < 8; ++j) acc[c * 8 + j] += w * (float)v[j];
        }
    }

    float lsum = 0.0f, lsq = 0.0f;
#pragma unroll
    for (int c = 0; c < 3; ++c)
#pragma unroll
        for (int j = 0; j < 8; ++j) {
            int idx = c * 512 + lane * 8 + j;
            float v = fmaxf(acc[c * 8 + j] * dd + bias[idx], 0.0f);
            acc[c * 8 + j] = v;
            lsum += v;
            lsq  += v * v;
        }
#pragma unroll
    for (int off = 32; off > 0; off >>= 1) {
        lsum += __shfl_xor(lsum, off);
        lsq  += __shfl_xor(lsq,  off);
    }
    const float mean = lsum / HH;
    const float var  = lsq / HH - mean * mean;
    const float rstd = rsqrtf(var + 1e-5f);

    bf16_t* y = out + (long long)row * HH;
#pragma unroll
    for (int c = 0; c < 3; ++c)
#pragma unroll
        for (int j = 0; j < 8; ++j) {
            int idx = c * 512 + lane * 8 + j;
            y[idx] = f2bf((acc[c * 8 + j] - mean) * rstd * g[idx] + be[idx]);
        }
}

// Same, F = 64 (fp32 h): writes fp32 latent (output 0) AND bf16 copy.
__global__ __launch_bounds__(256) void gcn_agg_ln_l(
    const float* __restrict__ h, const float* __restrict__ dinv,
    const int* __restrict__ rowptr, const int* __restrict__ csr_src,
    const float* __restrict__ bias, const float* __restrict__ g,
    const float* __restrict__ be, float* __restrict__ out,
    bf16_t* __restrict__ outb, int n)
{
    const int row  = blockIdx.x * 4 + (threadIdx.x >> 6);
    const int lane = threadIdx.x & 63;
    if (row >= n) return;
    const float dd = dinv[row];

    float acc = dd * h[(long long)row * LL + lane];
    const int s0 = rowptr[row], s1 = rowptr[row + 1];
    for (int k = s0; k < s1; ++k) {
        const int s = csr_src[k];
        acc += dinv[s] * h[(long long)s * LL + lane];
    }
    float v = fmaxf(acc * dd + bias[lane], 0.0f);
    float lsum = v, lsq = v * v;
#pragma unroll
    for (int off = 32; off > 0; off >>= 1) {
        lsum += __shfl_xor(lsum, off);
        lsq  += __shfl_xor(lsq,  off);
    }
    const float mean = lsum / LL;
    const float var  = lsq / LL - mean * mean;
    const float rstd = rsqrtf(var + 1e-5f);
    float o = (v - mean) * rstd * g[lane] + be[lane];
    out[(long long)row * LL + lane]  = o;
    outb[(long long)row * LL + lane] = f2bf(o);
}

// ---------------------------------------------------------------------------
// Launch.
// ---------------------------------------------------------------------------
extern "C" void kernel_launch(void* const* d_in, const int* in_sizes, int n_in,
                              void* d_out, int out_size, void* d_ws, size_t ws_size,
                              hipStream_t stream)
{
    const float* x     = (const float*)d_in[0];
    const int*   ei    = (const int*)d_in[1];
    const float* W_gc1 = (const float*)d_in[2];
    const float* b_gc1 = (const float*)d_in[3];
    const float* W_gc2 = (const float*)d_in[4];
    const float* b_gc2 = (const float*)d_in[5];
    const float* g1    = (const float*)d_in[6];
    const float* be1   = (const float*)d_in[7];
    const float* g2    = (const float*)d_in[8];
    const float* be2   = (const float*)d_in[9];
    const float* W_fc1 = (const float*)d_in[10];
    const float* b_fc1 = (const float*)d_in[11];
    const float* W_fc2 = (const float*)d_in[12];
    const float* b_fc2 = (const float*)d_in[13];

    float* out_latent = (float*)d_out;                       // [N, L]
    float* out_recon  = (float*)d_out + (long long)NN * LL;  // [N, D]

    bf16_t* h1b     = (bf16_t*)out_recon;                         // N*H bf16
    bf16_t* hiddenb = (bf16_t*)(out_recon + (long long)NN * HH);  // N*H bf16 (2nd half)

    float*  dinv    = (float*)d_ws;                          // N
    int*    cnt     = (int*)(dinv + NN);                     // N
    int*    cursor  = cnt + NN;                              // N
    int*    rowptr  = cursor + NN;                           // N+1
    int*    csr_src = rowptr + NN + 1;                       // E
    char*   pbase   = (char*)(csr_src + EE);
    pbase = (char*)(((size_t)pbase + 255) & ~(size_t)255);
    bf16_t* xb      = (bf16_t*)pbase;                        // N*D bf16 (later decodeb)
    bf16_t* W1t     = xb + (long long)NN * DD;               // H*D bf16 (W_gc1^T)
    bf16_t* W2t     = W1t + (long long)DD * HH;              // D*H bf16 (W_fc2^T)
    bf16_t* Wg2t    = W2t + (long long)DD * HH;              // L*H bf16 (W_gc2^T)
    bf16_t* Wf1t    = Wg2t + (long long)HH * LL;             // H*L bf16 (W_fc1^T)
    bf16_t* latentb = Wf1t + (long long)LL * HH;             // N*L bf16
    float*  wsC     = (float*)(latentb + (long long)NN * LL); // N*L f32 (h2)
    bf16_t* decodeb = xb;                                    // N*H bf16, reuses xb

    // 1) CSR build + dinv
    zero_int<<<(2 * NN + 255) / 256, 256, 0, stream>>>(cnt, 2 * NN);
    cnt_count<<<(EE + 255) / 256, 256, 0, stream>>>(ei, cnt, EE);
    dinv_from_cnt<<<(NN + 255) / 256, 256, 0, stream>>>(cnt, dinv, NN);
    scan_rowptr<<<1, 1024, 0, stream>>>(cnt, rowptr, NN);
    csr_fill<<<(EE + 255) / 256, 256, 0, stream>>>(ei, rowptr, cursor, csr_src, EE);

    // 2) bf16 conversions
    cvt_bf16<<<2048, 256, 0, stream>>>((const float4*)x, (ushort4*)xb, (long long)NN * DD / 4);
    {
        dim3 ga(HH / 32, DD / 32);
        cvt_transpose_bf16<<<ga, 256, 0, stream>>>(W_gc1, W1t, DD, HH);
        dim3 gb(DD / 32, HH / 32);
        cvt_transpose_bf16<<<gb, 256, 0, stream>>>(W_fc2, W2t, HH, DD);
        dim3 gc(LL / 32, HH / 32);
        cvt_transpose_bf16<<<gc, 256, 0, stream>>>(W_gc2, Wg2t, HH, LL);
        dim3 gd(HH / 32, LL / 32);
        cvt_transpose_bf16<<<gd, 256, 0, stream>>>(W_fc1, Wf1t, LL, HH);
    }

    const int MB128 = (NN + 127) / 128;   // 157
    const int MB256 = (NN + 255) / 256;   // 79

    // 3) h1b = bf16(xb @ W1t^T)   [N, H]   (8-phase 256x256)
    {
        int gx = HH / 256;   // 6
        gemm_bf16_8ph<0, 0, 1><<<gx * MB256, 512, 0, stream>>>(xb, W1t, nullptr, h1b, NN, HH, DD, gx);
    }

    // 4) hiddenb = bf16(LN(relu(agg(h1b) + b_gc1)))
    gcn_agg_ln_h<<<(NN + 3) / 4, 256, 0, stream>>>(h1b, dinv, rowptr, csr_src, b_gc1, g1, be1, hiddenb, NN);

    // 5) h2 = hiddenb @ Wg2t^T    [N, L] f32 -> wsC   (MFMA 128x64)
    gemm_bf16_mfma<0, 0, 0, 64><<<MB128, 256, 0, stream>>>(hiddenb, Wg2t, nullptr, wsC, NN, LL, HH, 1);

    // 6) latent = LN(relu(agg(h2) + b_gc2)) -> output 0 (+ bf16 copy)
    gcn_agg_ln_l<<<(NN + 3) / 4, 256, 0, stream>>>(wsC, dinv, rowptr, csr_src, b_gc2, g2, be2, out_latent, latentb, NN);

    // 7) decodeb = bf16(relu(latentb @ Wf1t^T + b_fc1))  [N, H] (MFMA 128x128, K=64)
    {
        int gx = HH / 128;
        gemm_bf16_mfma<1, 1, 1, 128><<<gx * MB128, 256, 0, stream>>>(latentb, Wf1t, b_fc1, decodeb, NN, HH, LL, gx);
    }

    // 8) reconstructed = decodeb @ W2t^T + b_fc2  [N, D] -> output 1 (8-phase)
    {
        int gx = DD / 256;   // 12
        gemm_bf16_8ph<1, 0, 0><<<gx * MB256, 512, 0, stream>>>(decodeb, W2t, b_fc2, out_recon, NN, DD, HH, gx);
    }
}

// Round 10
// 781.564 us; speedup vs baseline: 12.4966x; 1.0288x over previous
//
#include <hip/hip_runtime.h>
#include <hip/hip_bf16.h>

// Problem constants (match reference)
#define NN 20000
#define EE 320000
#define DD 3072
#define HH 1536
#define LL 64

typedef unsigned short bf16_t;
typedef __attribute__((ext_vector_type(8))) __bf16 bf16x8;
typedef __attribute__((ext_vector_type(4))) float  f32x4;

__device__ __forceinline__ bf16_t f2bf(float f) {
    union { float f; unsigned u; } c; c.f = f;
    unsigned u = c.u;
    return (bf16_t)((u + 0x7fffu + ((u >> 16) & 1u)) >> 16);  // RNE (inputs finite)
}

// ---------------------------------------------------------------------------
// CSR build. edge_index is int32: src = ei[e], dst = ei[E+e].
// ---------------------------------------------------------------------------
__global__ void zero_int(int* __restrict__ p, int n) {
    int i = blockIdx.x * blockDim.x + threadIdx.x;
    if (i < n) p[i] = 0;
}

__global__ void cnt_count(const int* __restrict__ ei, int* __restrict__ cnt, int E) {
    int i = blockIdx.x * blockDim.x + threadIdx.x;
    if (i < E) atomicAdd(&cnt[ei[E + i]], 1);
}

__global__ void dinv_from_cnt(const int* __restrict__ cnt, float* __restrict__ dinv, int n) {
    int i = blockIdx.x * blockDim.x + threadIdx.x;
    if (i < n) dinv[i] = rsqrtf((float)(cnt[i] + 1));
}

// single-block exclusive scan (n = 20000, chunked Hillis-Steele)
__global__ __launch_bounds__(1024) void scan_rowptr(const int* __restrict__ cnt,
                                                    int* __restrict__ rowptr, int n)
{
    __shared__ int sdata[1024];
    __shared__ int scarry;
    const int tid = threadIdx.x;
    if (tid == 0) scarry = 0;
    __syncthreads();
    for (int base = 0; base < n; base += 1024) {
        int i = base + tid;
        int v = (i < n) ? cnt[i] : 0;
        int x = v;
        sdata[tid] = x;
        __syncthreads();
#pragma unroll
        for (int off = 1; off < 1024; off <<= 1) {
            int y = (tid >= off) ? sdata[tid - off] : 0;
            __syncthreads();
            x += y;
            sdata[tid] = x;
            __syncthreads();
        }
        if (i < n) rowptr[i] = scarry + x - v;  // exclusive
        int total = sdata[1023];
        __syncthreads();
        if (tid == 0) scarry += total;
        __syncthreads();
    }
    if (tid == 0) rowptr[n] = scarry;
}

__global__ void csr_fill(const int* __restrict__ ei, const int* __restrict__ rowptr,
                         int* __restrict__ cursor, int* __restrict__ csr_src, int E)
{
    int e = blockIdx.x * blockDim.x + threadIdx.x;
    if (e < E) {
        int d = ei[E + e];
        int pos = rowptr[d] + atomicAdd(&cursor[d], 1);
        csr_src[pos] = ei[e];
    }
}

// ---------------------------------------------------------------------------
// fp32 -> bf16 cast (vectorized), and fp32 [R][C] -> bf16 [C][R] transpose
// ---------------------------------------------------------------------------
__global__ void cvt_bf16(const float4* __restrict__ in, ushort4* __restrict__ out, long long n4) {
    for (long long i = (long long)blockIdx.x * blockDim.x + threadIdx.x;
         i < n4; i += (long long)gridDim.x * blockDim.x) {
        float4 v = in[i];
        ushort4 o;
        o.x = f2bf(v.x); o.y = f2bf(v.y); o.z = f2bf(v.z); o.w = f2bf(v.w);
        out[i] = o;
    }
}

__global__ __launch_bounds__(256) void cvt_transpose_bf16(
    const float* __restrict__ in, bf16_t* __restrict__ out, int R, int C)
{
    __shared__ float tile[32][33];
    const int bx = blockIdx.x, by = blockIdx.y;   // bx over C/32, by over R/32
    const int tx = threadIdx.x & 31;
    const int ty = (threadIdx.x >> 5) * 4;
#pragma unroll
    for (int j = 0; j < 4; ++j)
        tile[ty + j][tx] = in[(long long)(by * 32 + ty + j) * C + bx * 32 + tx];
    __syncthreads();
#pragma unroll
    for (int j = 0; j < 4; ++j)
        out[(long long)(bx * 32 + ty + j) * R + by * 32 + tx] = f2bf(tile[tx][ty + j]);
}

#define GLOAD_LDS16(g, l)                                                     \
    __builtin_amdgcn_global_load_lds(                                         \
        (const __attribute__((address_space(1))) unsigned int*)(g),          \
        (__attribute__((address_space(3))) unsigned int*)(l), 16, 0, 0)

// ---------------------------------------------------------------------------
// 8-phase-derived 256x256 BF16 MFMA GEMM, 4 phases/tile, snake order with
// A0 PARKED across the tile: reads/tile/wave = 12,8,4,0 = 24 (minimum).
// One barrier per phase; NO forced lgkmcnt(0) drain -- plain LDS loads let
// the compiler emit fine-grained lgkmcnt(N) so MFMA overlaps ds_read.
// Stage targets >= 2 barriers after their region's last LDS read:
//   P1(0,0): rd A0,B0; stage (o).A1<-t+1   [last read t-1.P2]
//   P2(1,0): rd A1;    stage (o).B1<-t+1   [last read t-1.P3]
//   P3(1,1): rd B1;    stage (c).A0<-t+2   [last read t.P1]
//   P4(0,1): rd none;  stage (c).B0<-t+2   [last read t.P1]; vmcnt(4)
// FIFO vmcnt(4)/tile => tile t+1 fully landed by end of tile t (induction
// anchored by the prologue: tile0 complete + tile1 A0,B0 in flight).
// ---------------------------------------------------------------------------
#define MFMA16(a, b, c) __builtin_amdgcn_mfma_f32_16x16x32_bf16((a), (b), (c), 0, 0, 0)

#define LDA_F(CUR, MH, MF, KS)                                                \
    (*(const bf16x8*)((const char*)(&lds[(CUR)][0][(MH)][0]) +                \
        (arow + (MF) * 16) * 128 + ((KS) ? offk1 : offk0)))
#define LDB_F(CUR, NH, NF, KS)                                                \
    (*(const bf16x8*)((const char*)(&lds[(CUR)][1][(NH)][0]) +                \
        (brw + (NF) * 16) * 128 + ((KS) ? offk1 : offk0)))

#define READ_AQ(DST, CUR, MH)                                                  \
    _Pragma("unroll")                                                          \
    for (int mf = 0; mf < 4; ++mf) {                                           \
        DST[mf][0] = LDA_F(CUR, MH, mf, 0);                                    \
        DST[mf][1] = LDA_F(CUR, MH, mf, 1);                                    \
    }

#define READ_BQ(DST, CUR, NH)                                                  \
    _Pragma("unroll")                                                          \
    for (int nf = 0; nf < 2; ++nf) {                                           \
        DST[nf][0] = LDB_F(CUR, NH, nf, 0);                                    \
        DST[nf][1] = LDB_F(CUR, NH, nf, 1);                                    \
    }

#define MFMA_Q(MH, NH, PA, PB)                                                 \
    do {                                                                       \
        __builtin_amdgcn_s_setprio(1);                                         \
        _Pragma("unroll")                                                      \
        for (int mf = 0; mf < 4; ++mf) {                                       \
            _Pragma("unroll")                                                  \
            for (int nf = 0; nf < 2; ++nf) {                                   \
                acc[MH][NH][mf][nf] = MFMA16(PA[mf][0], PB[nf][0], acc[MH][NH][mf][nf]); \
                acc[MH][NH][mf][nf] = MFMA16(PA[mf][1], PB[nf][1], acc[MH][NH][mf][nf]); \
            }                                                                  \
        }                                                                      \
        __builtin_amdgcn_s_setprio(0);                                         \
    } while (0)

template <int HAS_BIAS, int RELU, int OUT_BF16>
__global__ __launch_bounds__(512, 2) void gemm_bf16_8ph(
    const bf16_t* __restrict__ A, const bf16_t* __restrict__ Bt,
    const float* __restrict__ bias, void* __restrict__ Cout,
    int M, int N, int K, int gx)
{
    __shared__ bf16_t lds[2][2][2][8192];   // [buf][A/B][half][128 rows x 64 k] = 128 KiB

    // bijective XCD chunk swizzle
    const int nwg = gridDim.x;
    const int q = nwg >> 3, r = nwg & 7;
    const int xcd = blockIdx.x & 7, lo = blockIdx.x >> 3;
    const int wgid = (xcd < r ? xcd * (q + 1) : r * (q + 1) + (xcd - r) * q) + lo;
    const int brow = (wgid / gx) * 256;
    const int bcol = (wgid % gx) * 256;

    const int tid = threadIdx.x;
    const int w = tid >> 6, l = tid & 63;
    const int wr = w >> 2, wc = w & 3;     // 2 x 4 wave grid
    const int nt = K >> 6;                 // BK=64 tiles

    f32x4 acc[2][2][4][2] = {};

    // staging lane constants: chunk c = w*2+i covers rows c*8..c*8+7 (1 KiB)
    const int srow8 = l >> 3;                         // row within chunk
    const int swz8  = (((l & 7) ^ (l >> 3)) << 3);    // swizzled k-slot (bf16 units)

    auto stage_a = [&](int buf, int h, int s) {
#pragma unroll
        for (int i = 0; i < 2; ++i) {
            const int c = (w << 1) + i;
            int grow = brow + h * 128 + c * 8 + srow8;
            if (grow > M - 1) grow = M - 1;           // clamp (in-bounds dup read)
            const bf16_t* g = A + (long long)grow * K + (s << 6) + swz8;
            GLOAD_LDS16(g, &lds[buf][0][h][c * 512]);
        }
    };
    auto stage_b = [&](int buf, int h, int s) {
#pragma unroll
        for (int i = 0; i < 2; ++i) {
            const int c = (w << 1) + i;
            const int grow = bcol + h * 128 + c * 8 + srow8;   // N%256==0, no clamp
            const bf16_t* g = Bt + (long long)grow * K + (s << 6) + swz8;
            GLOAD_LDS16(g, &lds[buf][1][h][c * 512]);
        }
    };

    // ds_read address constants (read-side swizzle: same involution)
    const int arow  = wr * 64 + (l & 15);
    const int brw   = wc * 32 + (l & 15);
    const int xm    = (l & 7) << 4;
    const int offk0 = ((l >> 4) << 4) ^ xm;
    const int offk1 = (((l >> 4) << 4) + 64) ^ xm;

    // prologue: tile0 complete (8 loads) + tile1 A0,B0 (4 loads);
    // vmcnt(4) -> tile0 landed, tile1 A0,B0 in flight (steady-state invariant)
    stage_a(0, 0, 0); stage_b(0, 0, 0);
    stage_a(0, 1, 0); stage_b(0, 1, 0);
    stage_a(1, 0, 1); stage_b(1, 0, 1);
    __builtin_amdgcn_sched_barrier(0);
    asm volatile("s_waitcnt vmcnt(4)" ::: "memory");
    __builtin_amdgcn_sched_barrier(0);
    __builtin_amdgcn_s_barrier();

    int cur = 0;
    for (int t = 0; t < nt; ++t) {
        const int t1 = (t + 1 < nt) ? t + 1 : nt - 1;
        const int t2 = (t + 2 < nt) ? t + 2 : nt - 1;
        bf16x8 pa0[4][2], pa1[4][2], pb[2][2];

        // P1 (0,0): read A0 (parked through P4) + B0; stage (o).A1 <- t+1
        __builtin_amdgcn_sched_barrier(0);
        READ_AQ(pa0, cur, 0);
        READ_BQ(pb,  cur, 0);
        stage_a(cur ^ 1, 1, t1);
        MFMA_Q(0, 0, pa0, pb);
        __builtin_amdgcn_s_barrier();

        // P2 (1,0): read A1 (B0 held); stage (o).B1 <- t+1
        __builtin_amdgcn_sched_barrier(0);
        READ_AQ(pa1, cur, 1);
        stage_b(cur ^ 1, 1, t1);
        MFMA_Q(1, 0, pa1, pb);
        __builtin_amdgcn_s_barrier();

        // P3 (1,1): read B1 (A1 held); stage (cur).A0 <- t+2 (last read t.P1)
        __builtin_amdgcn_sched_barrier(0);
        READ_BQ(pb, cur, 1);
        stage_a(cur, 0, t2);
        MFMA_Q(1, 1, pa1, pb);
        __builtin_amdgcn_s_barrier();

        // P4 (0,1): no reads (A0 parked, B1 held); stage (cur).B0 <- t+2
        __builtin_amdgcn_sched_barrier(0);
        stage_b(cur, 0, t2);
        MFMA_Q(0, 1, pa0, pb);
        asm volatile("s_waitcnt vmcnt(4)" ::: "memory");
        __builtin_amdgcn_sched_barrier(0);
        __builtin_amdgcn_s_barrier();

        cur ^= 1;
    }

    // epilogue: C/D layout col=lane&15, row=(lane>>4)*4+j per 16x16 frag
#pragma unroll
    for (int mh = 0; mh < 2; ++mh) {
#pragma unroll
        for (int nh = 0; nh < 2; ++nh) {
#pragma unroll
            for (int nf = 0; nf < 2; ++nf) {
                const int col = bcol + nh * 128 + wc * 32 + nf * 16 + (l & 15);
                const float bv = HAS_BIAS ? bias[col] : 0.0f;
#pragma unroll
                for (int mf = 0; mf < 4; ++mf) {
#pragma unroll
                    for (int j = 0; j < 4; ++j) {
                        const int row = brow + mh * 128 + wr * 64 + mf * 16 + (l >> 4) * 4 + j;
                        if (row < M) {
                            float v = acc[mh][nh][mf][nf][j] + bv;
                            if (RELU) v = fmaxf(v, 0.0f);
                            if (OUT_BF16) ((bf16_t*)Cout)[(long long)row * N + col] = f2bf(v);
                            else          ((float*)Cout)[(long long)row * N + col] = v;
                        }
                    }
                }
            }
        }
    }
}

// ---------------------------------------------------------------------------
// m97-structure BF16 MFMA GEMM (kept for the two small GEMMs):
// C[M,N] = A[M,K] @ Bt[N,K]^T (+bias)(+relu), fp32 or bf16 out.
// ---------------------------------------------------------------------------
template <int HAS_BIAS, int RELU, int OUT_BF16, int BNT>
__global__ __launch_bounds__(256) void gemm_bf16_mfma(
    const bf16_t* __restrict__ A, const bf16_t* __restrict__ Bt,
    const float* __restrict__ bias, void* __restrict__ Cout,
    int M, int N, int K, int gx)
{
    constexpr int NFRAG = BNT / 32;
    constexpr int BHALF = BNT / 64;
    constexpr int WCOFF = BNT / 2;

    __shared__ bf16_t As[128 * 32];
    __shared__ bf16_t Bs[BNT * 32];

    const int nwg = gridDim.x;
    const int q = nwg >> 3, r = nwg & 7;
    const int xcd = blockIdx.x & 7, lo = blockIdx.x >> 3;
    const int wgid = (xcd < r ? xcd * (q + 1) : r * (q + 1) + (xcd - r) * q) + lo;
    const int brow = (wgid / gx) * 128;
    const int bcol = (wgid % gx) * BNT;

    const int tid = threadIdx.x;
    const int w   = tid >> 6;
    const int l   = tid & 63;
    const int wr  = w >> 1, wc = w & 1;

    f32x4 acc[4][NFRAG] = {};

    const int srow   = tid >> 2;
    const int schunk = (tid & 3) * 8;

    for (int k0 = 0; k0 < K; k0 += 32) {
#pragma unroll
        for (int half = 0; half < 2; ++half) {
            int gr = brow + half * 64 + srow;
            if (gr > M - 1) gr = M - 1;
            const bf16_t* gsrc = A + (long long)gr * K + k0 + schunk;
            GLOAD_LDS16(gsrc, &As[(half * 64 + w * 16) * 32]);
        }
#pragma unroll
        for (int half = 0; half < BHALF; ++half) {
            int rr = half * 64 + srow;
            const bf16_t* gsrc = Bt + (long long)(bcol + rr) * K + k0 + schunk;
            GLOAD_LDS16(gsrc, &Bs[(half * 64 + w * 16) * 32]);
        }
        __syncthreads();

        bf16x8 af[4], bfr[NFRAG];
#pragma unroll
        for (int m = 0; m < 4; ++m) {
            int row = wr * 64 + m * 16 + (l & 15);
            af[m] = *(const bf16x8*)&As[row * 32 + (l >> 4) * 8];
        }
#pragma unroll
        for (int n = 0; n < NFRAG; ++n) {
            int row = wc * WCOFF + n * 16 + (l & 15);
            bfr[n] = *(const bf16x8*)&Bs[row * 32 + (l >> 4) * 8];
        }
#pragma unroll
        for (int m = 0; m < 4; ++m)
#pragma unroll
            for (int n = 0; n < NFRAG; ++n)
                acc[m][n] = MFMA16(af[m], bfr[n], acc[m][n]);
        __syncthreads();
    }

#pragma unroll
    for (int m = 0; m < 4; ++m) {
#pragma unroll
        for (int n = 0; n < NFRAG; ++n) {
            int col = bcol + wc * WCOFF + n * 16 + (l & 15);
            float b = HAS_BIAS ? bias[col] : 0.0f;
#pragma unroll
            for (int j = 0; j < 4; ++j) {
                int row = brow + wr * 64 + m * 16 + (l >> 4) * 4 + j;
                if (row < M) {
                    float v = acc[m][n][j] + b;
                    if (RELU) v = fmaxf(v, 0.0f);
                    if (OUT_BF16) ((bf16_t*)Cout)[(long long)row * N + col] = f2bf(v);
                    else          ((float*)Cout)[(long long)row * N + col] = v;
                }
            }
        }
    }
}

// ---------------------------------------------------------------------------
// Fused GCN aggregation (CSR gather, bf16 h) + bias + ReLU + LN, F = 1536.
// One WAVE per dst row (4 rows/block); lane owns 3 bf16x8 chunks (24 feats).
// ---------------------------------------------------------------------------
__global__ __launch_bounds__(256) void gcn_agg_ln_h(
    const bf16_t* __restrict__ h, const float* __restrict__ dinv,
    const int* __restrict__ rowptr, const int* __restrict__ csr_src,
    const float* __restrict__ bias, const float* __restrict__ g,
    const float* __restrict__ be, bf16_t* __restrict__ out, int n)
{
    const int row  = blockIdx.x * 4 + (threadIdx.x >> 6);
    const int lane = threadIdx.x & 63;
    if (row >= n) return;
    const float dd = dinv[row];

    float acc[24];
    {
        const bf16x8* hr = (const bf16x8*)(h + (long long)row * HH);
#pragma unroll
        for (int c = 0; c < 3; ++c) {
            bf16x8 v = hr[c * 64 + lane];
#pragma unroll
            for (int j = 0; j < 8; ++j) acc[c * 8 + j] = dd * (float)v[j];
        }
    }
    const int s0 = rowptr[row], s1 = rowptr[row + 1];
    for (int k = s0; k < s1; ++k) {
        const int s = csr_src[k];
        const float w = dinv[s];
        const bf16x8* hs = (const bf16x8*)(h + (long long)s * HH);
#pragma unroll
        for (int c = 0; c < 3; ++c) {
            bf16x8 v = hs[c * 64 + lane];
#pragma unroll
            for (int j = 0; j < 8; ++j) acc[c * 8 + j] += w * (float)v[j];
        }
    }

    float lsum = 0.0f, lsq = 0.0f;
#pragma unroll
    for (int c = 0; c < 3; ++c)
#pragma unroll
        for (int j = 0; j < 8; ++j) {
            int idx = c * 512 + lane * 8 + j;
            float v = fmaxf(acc[c * 8 + j] * dd + bias[idx], 0.0f);
            acc[c * 8 + j] = v;
            lsum += v;
            lsq  += v * v;
        }
#pragma unroll
    for (int off = 32; off > 0; off >>= 1) {
        lsum += __shfl_xor(lsum, off);
        lsq  += __shfl_xor(lsq,  off);
    }
    const float mean = lsum / HH;
    const float var  = lsq / HH - mean * mean;
    const float rstd = rsqrtf(var + 1e-5f);

    bf16_t* y = out + (long long)row * HH;
#pragma unroll
    for (int c = 0; c < 3; ++c)
#pragma unroll
        for (int j = 0; j < 8; ++j) {
            int idx = c * 512 + lane * 8 + j;
            y[idx] = f2bf((acc[c * 8 + j] - mean) * rstd * g[idx] + be[idx]);
        }
}

// Same, F = 64 (fp32 h): writes fp32 latent (output 0) AND bf16 copy.
__global__ __launch_bounds__(256) void gcn_agg_ln_l(
    const float* __restrict__ h, const float* __restrict__ dinv,
    const int* __restrict__ rowptr, const int* __restrict__ csr_src,
    const float* __restrict__ bias, const float* __restrict__ g,
    const float* __restrict__ be, float* __restrict__ out,
    bf16_t* __restrict__ outb, int n)
{
    const int row  = blockIdx.x * 4 + (threadIdx.x >> 6);
    const int lane = threadIdx.x & 63;
    if (row >= n) return;
    const float dd = dinv[row];

    float acc = dd * h[(long long)row * LL + lane];
    const int s0 = rowptr[row], s1 = rowptr[row + 1];
    for (int k = s0; k < s1; ++k) {
        const int s = csr_src[k];
        acc += dinv[s] * h[(long long)s * LL + lane];
    }
    float v = fmaxf(acc * dd + bias[lane], 0.0f);
    float lsum = v, lsq = v * v;
#pragma unroll
    for (int off = 32; off > 0; off >>= 1) {
        lsum += __shfl_xor(lsum, off);
        lsq  += __shfl_xor(lsq,  off);
    }
    const float mean = lsum / LL;
    const float var  = lsq / LL - mean * mean;
    const float rstd = rsqrtf(var + 1e-5f);
    float o = (v - mean) * rstd * g[lane] + be[lane];
    out[(long long)row * LL + lane]  = o;
    outb[(long long)row * LL + lane] = f2bf(o);
}

// ---------------------------------------------------------------------------
// Launch.
// ---------------------------------------------------------------------------
extern "C" void kernel_launch(void* const* d_in, const int* in_sizes, int n_in,
                              void* d_out, int out_size, void* d_ws, size_t ws_size,
                              hipStream_t stream)
{
    const float* x     = (const float*)d_in[0];
    const int*   ei    = (const int*)d_in[1];
    const float* W_gc1 = (const float*)d_in[2];
    const float* b_gc1 = (const float*)d_in[3];
    const float* W_gc2 = (const float*)d_in[4];
    const float* b_gc2 = (const float*)d_in[5];
    const float* g1    = (const float*)d_in[6];
    const float* be1   = (const float*)d_in[7];
    const float* g2    = (const float*)d_in[8];
    const float* be2   = (const float*)d_in[9];
    const float* W_fc1 = (const float*)d_in[10];
    const float* b_fc1 = (const float*)d_in[11];
    const float* W_fc2 = (const float*)d_in[12];
    const float* b_fc2 = (const float*)d_in[13];

    float* out_latent = (float*)d_out;                       // [N, L]
    float* out_recon  = (float*)d_out + (long long)NN * LL;  // [N, D]

    bf16_t* h1b     = (bf16_t*)out_recon;                         // N*H bf16
    bf16_t* hiddenb = (bf16_t*)(out_recon + (long long)NN * HH);  // N*H bf16 (2nd half)

    float*  dinv    = (float*)d_ws;                          // N
    int*    cnt     = (int*)(dinv + NN);                     // N
    int*    cursor  = cnt + NN;                              // N
    int*    rowptr  = cursor + NN;                           // N+1
    int*    csr_src = rowptr + NN + 1;                       // E
    char*   pbase   = (char*)(csr_src + EE);
    pbase = (char*)(((size_t)pbase + 255) & ~(size_t)255);
    bf16_t* xb      = (bf16_t*)pbase;                        // N*D bf16 (later decodeb)
    bf16_t* W1t     = xb + (long long)NN * DD;               // H*D bf16 (W_gc1^T)
    bf16_t* W2t     = W1t + (long long)DD * HH;              // D*H bf16 (W_fc2^T)
    bf16_t* Wg2t    = W2t + (long long)DD * HH;              // L*H bf16 (W_gc2^T)
    bf16_t* Wf1t    = Wg2t + (long long)HH * LL;             // H*L bf16 (W_fc1^T)
    bf16_t* latentb = Wf1t + (long long)LL * HH;             // N*L bf16
    float*  wsC     = (float*)(latentb + (long long)NN * LL); // N*L f32 (h2)
    bf16_t* decodeb = xb;                                    // N*H bf16, reuses xb

    // 1) CSR build + dinv
    zero_int<<<(2 * NN + 255) / 256, 256, 0, stream>>>(cnt, 2 * NN);
    cnt_count<<<(EE + 255) / 256, 256, 0, stream>>>(ei, cnt, EE);
    dinv_from_cnt<<<(NN + 255) / 256, 256, 0, stream>>>(cnt, dinv, NN);
    scan_rowptr<<<1, 1024, 0, stream>>>(cnt, rowptr, NN);
    csr_fill<<<(EE + 255) / 256, 256, 0, stream>>>(ei, rowptr, cursor, csr_src, EE);

    // 2) bf16 conversions
    cvt_bf16<<<2048, 256, 0, stream>>>((const float4*)x, (ushort4*)xb, (long long)NN * DD / 4);
    {
        dim3 ga(HH / 32, DD / 32);
        cvt_transpose_bf16<<<ga, 256, 0, stream>>>(W_gc1, W1t, DD, HH);
        dim3 gb(DD / 32, HH / 32);
        cvt_transpose_bf16<<<gb, 256, 0, stream>>>(W_fc2, W2t, HH, DD);
        dim3 gc(LL / 32, HH / 32);
        cvt_transpose_bf16<<<gc, 256, 0, stream>>>(W_gc2, Wg2t, HH, LL);
        dim3 gd(HH / 32, LL / 32);
        cvt_transpose_bf16<<<gd, 256, 0, stream>>>(W_fc1, Wf1t, LL, HH);
    }

    const int MB128 = (NN + 127) / 128;   // 157
    const int MB256 = (NN + 255) / 256;   // 79

    // 3) h1b = bf16(xb @ W1t^T)   [N, H]   (256x256 pipelined)
    {
        int gx = HH / 256;   // 6
        gemm_bf16_8ph<0, 0, 1><<<gx * MB256, 512, 0, stream>>>(xb, W1t, nullptr, h1b, NN, HH, DD, gx);
    }

    // 4) hiddenb = bf16(LN(relu(agg(h1b) + b_gc1)))
    gcn_agg_ln_h<<<(NN + 3) / 4, 256, 0, stream>>>(h1b, dinv, rowptr, csr_src, b_gc1, g1, be1, hiddenb, NN);

    // 5) h2 = hiddenb @ Wg2t^T    [N, L] f32 -> wsC   (MFMA 128x64)
    gemm_bf16_mfma<0, 0, 0, 64><<<MB128, 256, 0, stream>>>(hiddenb, Wg2t, nullptr, wsC, NN, LL, HH, 1);

    // 6) latent = LN(relu(agg(h2) + b_gc2)) -> output 0 (+ bf16 copy)
    gcn_agg_ln_l<<<(NN + 3) / 4, 256, 0, stream>>>(wsC, dinv, rowptr, csr_src, b_gc2, g2, be2, out_latent, latentb, NN);

    // 7) decodeb = bf16(relu(latentb @ Wf1t^T + b_fc1))  [N, H] (MFMA 128x128, K=64)
    {
        int gx = HH / 128;
        gemm_bf16_mfma<1, 1, 1, 128><<<gx * MB128, 256, 0, stream>>>(latentb, Wf1t, b_fc1, decodeb, NN, HH, LL, gx);
    }

    // 8) reconstructed = decodeb @ W2t^T + b_fc2  [N, D] -> output 1 (256x256)
    {
        int gx = DD / 256;   // 12
        gemm_bf16_8ph<1, 0, 0><<<gx * MB256, 512, 0, stream>>>(decodeb, W2t, b_fc2, out_recon, NN, DD, HH, gx);
    }
}

// Round 11
// 776.539 us; speedup vs baseline: 12.5775x; 1.0065x over previous
//
#include <hip/hip_runtime.h>
#include <hip/hip_bf16.h>

// Problem constants (match reference)
#define NN 20000
#define EE 320000
#define DD 3072
#define HH 1536
#define LL 64

typedef unsigned short bf16_t;
typedef __attribute__((ext_vector_type(8))) __bf16 bf16x8;
typedef __attribute__((ext_vector_type(4))) float  f32x4;

__device__ __forceinline__ bf16_t f2bf(float f) {
    union { float f; unsigned u; } c; c.f = f;
    unsigned u = c.u;
    return (bf16_t)((u + 0x7fffu + ((u >> 16) & 1u)) >> 16);  // RNE (inputs finite)
}

// ---------------------------------------------------------------------------
// CSR build. edge_index is int32: src = ei[e], dst = ei[E+e].
// ---------------------------------------------------------------------------
__global__ void zero_int(int* __restrict__ p, int n) {
    int i = blockIdx.x * blockDim.x + threadIdx.x;
    if (i < n) p[i] = 0;
}

__global__ void cnt_count(const int* __restrict__ ei, int* __restrict__ cnt, int E) {
    int i = blockIdx.x * blockDim.x + threadIdx.x;
    if (i < E) atomicAdd(&cnt[ei[E + i]], 1);
}

__global__ void dinv_from_cnt(const int* __restrict__ cnt, float* __restrict__ dinv, int n) {
    int i = blockIdx.x * blockDim.x + threadIdx.x;
    if (i < n) dinv[i] = rsqrtf((float)(cnt[i] + 1));
}

// single-block exclusive scan (n = 20000, chunked Hillis-Steele)
__global__ __launch_bounds__(1024) void scan_rowptr(const int* __restrict__ cnt,
                                                    int* __restrict__ rowptr, int n)
{
    __shared__ int sdata[1024];
    __shared__ int scarry;
    const int tid = threadIdx.x;
    if (tid == 0) scarry = 0;
    __syncthreads();
    for (int base = 0; base < n; base += 1024) {
        int i = base + tid;
        int v = (i < n) ? cnt[i] : 0;
        int x = v;
        sdata[tid] = x;
        __syncthreads();
#pragma unroll
        for (int off = 1; off < 1024; off <<= 1) {
            int y = (tid >= off) ? sdata[tid - off] : 0;
            __syncthreads();
            x += y;
            sdata[tid] = x;
            __syncthreads();
        }
        if (i < n) rowptr[i] = scarry + x - v;  // exclusive
        int total = sdata[1023];
        __syncthreads();
        if (tid == 0) scarry += total;
        __syncthreads();
    }
    if (tid == 0) rowptr[n] = scarry;
}

__global__ void csr_fill(const int* __restrict__ ei, const int* __restrict__ rowptr,
                         int* __restrict__ cursor, int* __restrict__ csr_src, int E)
{
    int e = blockIdx.x * blockDim.x + threadIdx.x;
    if (e < E) {
        int d = ei[E + e];
        int pos = rowptr[d] + atomicAdd(&cursor[d], 1);
        csr_src[pos] = ei[e];
    }
}

// ---------------------------------------------------------------------------
// fp32 -> bf16 cast (vectorized), and fp32 [R][C] -> bf16 [C][R] transpose
// ---------------------------------------------------------------------------
__global__ void cvt_bf16(const float4* __restrict__ in, ushort4* __restrict__ out, long long n4) {
    for (long long i = (long long)blockIdx.x * blockDim.x + threadIdx.x;
         i < n4; i += (long long)gridDim.x * blockDim.x) {
        float4 v = in[i];
        ushort4 o;
        o.x = f2bf(v.x); o.y = f2bf(v.y); o.z = f2bf(v.z); o.w = f2bf(v.w);
        out[i] = o;
    }
}

__global__ __launch_bounds__(256) void cvt_transpose_bf16(
    const float* __restrict__ in, bf16_t* __restrict__ out, int R, int C)
{
    __shared__ float tile[32][33];
    const int bx = blockIdx.x, by = blockIdx.y;   // bx over C/32, by over R/32
    const int tx = threadIdx.x & 31;
    const int ty = (threadIdx.x >> 5) * 4;
#pragma unroll
    for (int j = 0; j < 4; ++j)
        tile[ty + j][tx] = in[(long long)(by * 32 + ty + j) * C + bx * 32 + tx];
    __syncthreads();
#pragma unroll
    for (int j = 0; j < 4; ++j)
        out[(long long)(bx * 32 + ty + j) * R + by * 32 + tx] = f2bf(tile[tx][ty + j]);
}

#define GLOAD_LDS16(g, l)                                                     \
    __builtin_amdgcn_global_load_lds(                                         \
        (const __attribute__((address_space(1))) unsigned int*)(g),          \
        (__attribute__((address_space(3))) unsigned int*)(l), 16, 0, 0)

// ---------------------------------------------------------------------------
// 256x256 BF16 MFMA GEMM, 4 phases/tile, snake order, ONE-PHASE-AHEAD
// REGISTER PREFETCH: each phase's MFMA operands were ds_read a full phase
// earlier, so the compiler emits partial lgkmcnt (waits only on own operands,
// prefetch stays outstanding under the MFMA burst) -- m201's lgkmcnt(8)
// mechanism. Reads/tile/wave = 20,4,0,0 = 24 (minimum).
//   P1(0,0): rd A0,B0 + prefetch A1; stage (o).A1<-t+1
//   P2(1,0): prefetch B1;            stage (o).B1<-t+1
//   P3(1,1): no reads;               stage (c).A0<-t+2
//   P4(0,1): no reads;               stage (c).B0<-t+2; vmcnt(4)
// Validity: (c).A1/(c).B1 staged at t-1.P1/P2 are within the first-4 loads
// drained by t-1's vmcnt(4) -> landed before tile t begins (induction
// anchored by the prologue). Stage targets >= 2 barriers after last read.
// ---------------------------------------------------------------------------
#define MFMA16(a, b, c) __builtin_amdgcn_mfma_f32_16x16x32_bf16((a), (b), (c), 0, 0, 0)

#define LDA_F(CUR, MH, MF, KS)                                                \
    (*(const bf16x8*)((const char*)(&lds[(CUR)][0][(MH)][0]) +                \
        (arow + (MF) * 16) * 128 + ((KS) ? offk1 : offk0)))
#define LDB_F(CUR, NH, NF, KS)                                                \
    (*(const bf16x8*)((const char*)(&lds[(CUR)][1][(NH)][0]) +                \
        (brw + (NF) * 16) * 128 + ((KS) ? offk1 : offk0)))

#define READ_AQ(DST, CUR, MH)                                                  \
    _Pragma("unroll")                                                          \
    for (int mf = 0; mf < 4; ++mf) {                                           \
        DST[mf][0] = LDA_F(CUR, MH, mf, 0);                                    \
        DST[mf][1] = LDA_F(CUR, MH, mf, 1);                                    \
    }

#define READ_BQ(DST, CUR, NH)                                                  \
    _Pragma("unroll")                                                          \
    for (int nf = 0; nf < 2; ++nf) {                                           \
        DST[nf][0] = LDB_F(CUR, NH, nf, 0);                                    \
        DST[nf][1] = LDB_F(CUR, NH, nf, 1);                                    \
    }

#define MFMA_Q(MH, NH, PA, PB)                                                 \
    do {                                                                       \
        __builtin_amdgcn_s_setprio(1);                                         \
        _Pragma("unroll")                                                      \
        for (int mf = 0; mf < 4; ++mf) {                                       \
            _Pragma("unroll")                                                  \
            for (int nf = 0; nf < 2; ++nf) {                                   \
                acc[MH][NH][mf][nf] = MFMA16(PA[mf][0], PB[nf][0], acc[MH][NH][mf][nf]); \
                acc[MH][NH][mf][nf] = MFMA16(PA[mf][1], PB[nf][1], acc[MH][NH][mf][nf]); \
            }                                                                  \
        }                                                                      \
        __builtin_amdgcn_s_setprio(0);                                         \
    } while (0)

template <int HAS_BIAS, int RELU, int OUT_BF16>
__global__ __launch_bounds__(512, 2) void gemm_bf16_8ph(
    const bf16_t* __restrict__ A, const bf16_t* __restrict__ Bt,
    const float* __restrict__ bias, void* __restrict__ Cout,
    int M, int N, int K, int gx)
{
    __shared__ bf16_t lds[2][2][2][8192];   // [buf][A/B][half][128 rows x 64 k] = 128 KiB

    // bijective XCD chunk swizzle
    const int nwg = gridDim.x;
    const int q = nwg >> 3, r = nwg & 7;
    const int xcd = blockIdx.x & 7, lo = blockIdx.x >> 3;
    const int wgid = (xcd < r ? xcd * (q + 1) : r * (q + 1) + (xcd - r) * q) + lo;
    const int brow = (wgid / gx) * 256;
    const int bcol = (wgid % gx) * 256;

    const int tid = threadIdx.x;
    const int w = tid >> 6, l = tid & 63;
    const int wr = w >> 2, wc = w & 3;     // 2 x 4 wave grid
    const int nt = K >> 6;                 // BK=64 tiles

    f32x4 acc[2][2][4][2] = {};

    // staging lane constants: chunk c = w*2+i covers rows c*8..c*8+7 (1 KiB)
    const int srow8 = l >> 3;                         // row within chunk
    const int swz8  = (((l & 7) ^ (l >> 3)) << 3);    // swizzled k-slot (bf16 units)

    auto stage_a = [&](int buf, int h, int s) {
#pragma unroll
        for (int i = 0; i < 2; ++i) {
            const int c = (w << 1) + i;
            int grow = brow + h * 128 + c * 8 + srow8;
            if (grow > M - 1) grow = M - 1;           // clamp (in-bounds dup read)
            const bf16_t* g = A + (long long)grow * K + (s << 6) + swz8;
            GLOAD_LDS16(g, &lds[buf][0][h][c * 512]);
        }
    };
    auto stage_b = [&](int buf, int h, int s) {
#pragma unroll
        for (int i = 0; i < 2; ++i) {
            const int c = (w << 1) + i;
            const int grow = bcol + h * 128 + c * 8 + srow8;   // N%256==0, no clamp
            const bf16_t* g = Bt + (long long)grow * K + (s << 6) + swz8;
            GLOAD_LDS16(g, &lds[buf][1][h][c * 512]);
        }
    };

    // ds_read address constants (read-side swizzle: same involution)
    const int arow  = wr * 64 + (l & 15);
    const int brw   = wc * 32 + (l & 15);
    const int xm    = (l & 7) << 4;
    const int offk0 = ((l >> 4) << 4) ^ xm;
    const int offk1 = (((l >> 4) << 4) + 64) ^ xm;

    // prologue: tile0 complete (8 loads) + tile1 A0,B0 (4 loads);
    // vmcnt(4) -> tile0 landed, tile1 A0,B0 in flight (steady-state invariant)
    stage_a(0, 0, 0); stage_b(0, 0, 0);
    stage_a(0, 1, 0); stage_b(0, 1, 0);
    stage_a(1, 0, 1); stage_b(1, 0, 1);
    __builtin_amdgcn_sched_barrier(0);
    asm volatile("s_waitcnt vmcnt(4)" ::: "memory");
    __builtin_amdgcn_sched_barrier(0);
    __builtin_amdgcn_s_barrier();

    int cur = 0;
    for (int t = 0; t < nt; ++t) {
        const int t1 = (t + 1 < nt) ? t + 1 : nt - 1;
        const int t2 = (t + 2 < nt) ? t + 2 : nt - 1;
        bf16x8 pa0[4][2], pa1[4][2], pb0[2][2], pb1[2][2];

        // P1 (0,0): read A0+B0 (own) + prefetch A1; stage (o).A1 <- t+1
        __builtin_amdgcn_sched_barrier(0);
        READ_AQ(pa0, cur, 0);
        READ_BQ(pb0, cur, 0);
        READ_AQ(pa1, cur, 1);              // prefetch for P2 (valid since t-1)
        stage_a(cur ^ 1, 1, t1);
        MFMA_Q(0, 0, pa0, pb0);
        __builtin_amdgcn_s_barrier();

        // P2 (1,0): prefetch B1 for P3; stage (o).B1 <- t+1
        __builtin_amdgcn_sched_barrier(0);
        READ_BQ(pb1, cur, 1);              // prefetch for P3 (valid since t-1)
        stage_b(cur ^ 1, 1, t1);
        MFMA_Q(1, 0, pa1, pb0);
        __builtin_amdgcn_s_barrier();

        // P3 (1,1): no reads; stage (cur).A0 <- t+2 (last read of A0 was t.P1)
        __builtin_amdgcn_sched_barrier(0);
        stage_a(cur, 0, t2);
        MFMA_Q(1, 1, pa1, pb1);
        __builtin_amdgcn_s_barrier();

        // P4 (0,1): no reads; stage (cur).B0 <- t+2; counted vmcnt
        __builtin_amdgcn_sched_barrier(0);
        stage_b(cur, 0, t2);
        MFMA_Q(0, 1, pa0, pb1);
        asm volatile("s_waitcnt vmcnt(4)" ::: "memory");
        __builtin_amdgcn_sched_barrier(0);
        __builtin_amdgcn_s_barrier();

        cur ^= 1;
    }

    // epilogue: C/D layout col=lane&15, row=(lane>>4)*4+j per 16x16 frag
#pragma unroll
    for (int mh = 0; mh < 2; ++mh) {
#pragma unroll
        for (int nh = 0; nh < 2; ++nh) {
#pragma unroll
            for (int nf = 0; nf < 2; ++nf) {
                const int col = bcol + nh * 128 + wc * 32 + nf * 16 + (l & 15);
                const float bv = HAS_BIAS ? bias[col] : 0.0f;
#pragma unroll
                for (int mf = 0; mf < 4; ++mf) {
#pragma unroll
                    for (int j = 0; j < 4; ++j) {
                        const int row = brow + mh * 128 + wr * 64 + mf * 16 + (l >> 4) * 4 + j;
                        if (row < M) {
                            float v = acc[mh][nh][mf][nf][j] + bv;
                            if (RELU) v = fmaxf(v, 0.0f);
                            if (OUT_BF16) ((bf16_t*)Cout)[(long long)row * N + col] = f2bf(v);
                            else          ((float*)Cout)[(long long)row * N + col] = v;
                        }
                    }
                }
            }
        }
    }
}

// ---------------------------------------------------------------------------
// m97-structure BF16 MFMA GEMM (kept for the two small GEMMs):
// C[M,N] = A[M,K] @ Bt[N,K]^T (+bias)(+relu), fp32 or bf16 out.
// ---------------------------------------------------------------------------
template <int HAS_BIAS, int RELU, int OUT_BF16, int BNT>
__global__ __launch_bounds__(256) void gemm_bf16_mfma(
    const bf16_t* __restrict__ A, const bf16_t* __restrict__ Bt,
    const float* __restrict__ bias, void* __restrict__ Cout,
    int M, int N, int K, int gx)
{
    constexpr int NFRAG = BNT / 32;
    constexpr int BHALF = BNT / 64;
    constexpr int WCOFF = BNT / 2;

    __shared__ bf16_t As[128 * 32];
    __shared__ bf16_t Bs[BNT * 32];

    const int nwg = gridDim.x;
    const int q = nwg >> 3, r = nwg & 7;
    const int xcd = blockIdx.x & 7, lo = blockIdx.x >> 3;
    const int wgid = (xcd < r ? xcd * (q + 1) : r * (q + 1) + (xcd - r) * q) + lo;
    const int brow = (wgid / gx) * 128;
    const int bcol = (wgid % gx) * BNT;

    const int tid = threadIdx.x;
    const int w   = tid >> 6;
    const int l   = tid & 63;
    const int wr  = w >> 1, wc = w & 1;

    f32x4 acc[4][NFRAG] = {};

    const int srow   = tid >> 2;
    const int schunk = (tid & 3) * 8;

    for (int k0 = 0; k0 < K; k0 += 32) {
#pragma unroll
        for (int half = 0; half < 2; ++half) {
            int gr = brow + half * 64 + srow;
            if (gr > M - 1) gr = M - 1;
            const bf16_t* gsrc = A + (long long)gr * K + k0 + schunk;
            GLOAD_LDS16(gsrc, &As[(half * 64 + w * 16) * 32]);
        }
#pragma unroll
        for (int half = 0; half < BHALF; ++half) {
            int rr = half * 64 + srow;
            const bf16_t* gsrc = Bt + (long long)(bcol + rr) * K + k0 + schunk;
            GLOAD_LDS16(gsrc, &Bs[(half * 64 + w * 16) * 32]);
        }
        __syncthreads();

        bf16x8 af[4], bfr[NFRAG];
#pragma unroll
        for (int m = 0; m < 4; ++m) {
            int row = wr * 64 + m * 16 + (l & 15);
            af[m] = *(const bf16x8*)&As[row * 32 + (l >> 4) * 8];
        }
#pragma unroll
        for (int n = 0; n < NFRAG; ++n) {
            int row = wc * WCOFF + n * 16 + (l & 15);
            bfr[n] = *(const bf16x8*)&Bs[row * 32 + (l >> 4) * 8];
        }
#pragma unroll
        for (int m = 0; m < 4; ++m)
#pragma unroll
            for (int n = 0; n < NFRAG; ++n)
                acc[m][n] = MFMA16(af[m], bfr[n], acc[m][n]);
        __syncthreads();
    }

#pragma unroll
    for (int m = 0; m < 4; ++m) {
#pragma unroll
        for (int n = 0; n < NFRAG; ++n) {
            int col = bcol + wc * WCOFF + n * 16 + (l & 15);
            float b = HAS_BIAS ? bias[col] : 0.0f;
#pragma unroll
            for (int j = 0; j < 4; ++j) {
                int row = brow + wr * 64 + m * 16 + (l >> 4) * 4 + j;
                if (row < M) {
                    float v = acc[m][n][j] + b;
                    if (RELU) v = fmaxf(v, 0.0f);
                    if (OUT_BF16) ((bf16_t*)Cout)[(long long)row * N + col] = f2bf(v);
                    else          ((float*)Cout)[(long long)row * N + col] = v;
                }
            }
        }
    }
}

// ---------------------------------------------------------------------------
// Fused GCN aggregation (CSR gather, bf16 h) + bias + ReLU + LN, F = 1536.
// One WAVE per dst row (4 rows/block); lane owns 3 bf16x8 chunks (24 feats).
// ---------------------------------------------------------------------------
__global__ __launch_bounds__(256) void gcn_agg_ln_h(
    const bf16_t* __restrict__ h, const float* __restrict__ dinv,
    const int* __restrict__ rowptr, const int* __restrict__ csr_src,
    const float* __restrict__ bias, const float* __restrict__ g,
    const float* __restrict__ be, bf16_t* __restrict__ out, int n)
{
    const int row  = blockIdx.x * 4 + (threadIdx.x >> 6);
    const int lane = threadIdx.x & 63;
    if (row >= n) return;
    const float dd = dinv[row];

    float acc[24];
    {
        const bf16x8* hr = (const bf16x8*)(h + (long long)row * HH);
#pragma unroll
        for (int c = 0; c < 3; ++c) {
            bf16x8 v = hr[c * 64 + lane];
#pragma unroll
            for (int j = 0; j < 8; ++j) acc[c * 8 + j] = dd * (float)v[j];
        }
    }
    const int s0 = rowptr[row], s1 = rowptr[row + 1];
    for (int k = s0; k < s1; ++k) {
        const int s = csr_src[k];
        const float w = dinv[s];
        const bf16x8* hs = (const bf16x8*)(h + (long long)s * HH);
#pragma unroll
        for (int c = 0; c < 3; ++c) {
            bf16x8 v = hs[c * 64 + lane];
#pragma unroll
            for (int j = 0; j < 8; ++j) acc[c * 8 + j] += w * (float)v[j];
        }
    }

    float lsum = 0.0f, lsq = 0.0f;
#pragma unroll
    for (int c = 0; c < 3; ++c)
#pragma unroll
        for (int j = 0; j < 8; ++j) {
            int idx = c * 512 + lane * 8 + j;
            float v = fmaxf(acc[c * 8 + j] * dd + bias[idx], 0.0f);
            acc[c * 8 + j] = v;
            lsum += v;
            lsq  += v * v;
        }
#pragma unroll
    for (int off = 32; off > 0; off >>= 1) {
        lsum += __shfl_xor(lsum, off);
        lsq  += __shfl_xor(lsq,  off);
    }
    const float mean = lsum / HH;
    const float var  = lsq / HH - mean * mean;
    const float rstd = rsqrtf(var + 1e-5f);

    bf16_t* y = out + (long long)row * HH;
#pragma unroll
    for (int c = 0; c < 3; ++c)
#pragma unroll
        for (int j = 0; j < 8; ++j) {
            int idx = c * 512 + lane * 8 + j;
            y[idx] = f2bf((acc[c * 8 + j] - mean) * rstd * g[idx] + be[idx]);
        }
}

// Same, F = 64 (fp32 h): writes fp32 latent (output 0) AND bf16 copy.
__global__ __launch_bounds__(256) void gcn_agg_ln_l(
    const float* __restrict__ h, const float* __restrict__ dinv,
    const int* __restrict__ rowptr, const int* __restrict__ csr_src,
    const float* __restrict__ bias, const float* __restrict__ g,
    const float* __restrict__ be, float* __restrict__ out,
    bf16_t* __restrict__ outb, int n)
{
    const int row  = blockIdx.x * 4 + (threadIdx.x >> 6);
    const int lane = threadIdx.x & 63;
    if (row >= n) return;
    const float dd = dinv[row];

    float acc = dd * h[(long long)row * LL + lane];
    const int s0 = rowptr[row], s1 = rowptr[row + 1];
    for (int k = s0; k < s1; ++k) {
        const int s = csr_src[k];
        acc += dinv[s] * h[(long long)s * LL + lane];
    }
    float v = fmaxf(acc * dd + bias[lane], 0.0f);
    float lsum = v, lsq = v * v;
#pragma unroll
    for (int off = 32; off > 0; off >>= 1) {
        lsum += __shfl_xor(lsum, off);
        lsq  += __shfl_xor(lsq,  off);
    }
    const float mean = lsum / LL;
    const float var  = lsq / LL - mean * mean;
    const float rstd = rsqrtf(var + 1e-5f);
    float o = (v - mean) * rstd * g[lane] + be[lane];
    out[(long long)row * LL + lane]  = o;
    outb[(long long)row * LL + lane] = f2bf(o);
}

// ---------------------------------------------------------------------------
// Launch.
// ---------------------------------------------------------------------------
extern "C" void kernel_launch(void* const* d_in, const int* in_sizes, int n_in,
                              void* d_out, int out_size, void* d_ws, size_t ws_size,
                              hipStream_t stream)
{
    const float* x     = (const float*)d_in[0];
    const int*   ei    = (const int*)d_in[1];
    const float* W_gc1 = (const float*)d_in[2];
    const float* b_gc1 = (const float*)d_in[3];
    const float* W_gc2 = (const float*)d_in[4];
    const float* b_gc2 = (const float*)d_in[5];
    const float* g1    = (const float*)d_in[6];
    const float* be1   = (const float*)d_in[7];
    const float* g2    = (const float*)d_in[8];
    const float* be2   = (const float*)d_in[9];
    const float* W_fc1 = (const float*)d_in[10];
    const float* b_fc1 = (const float*)d_in[11];
    const float* W_fc2 = (const float*)d_in[12];
    const float* b_fc2 = (const float*)d_in[13];

    float* out_latent = (float*)d_out;                       // [N, L]
    float* out_recon  = (float*)d_out + (long long)NN * LL;  // [N, D]

    bf16_t* h1b     = (bf16_t*)out_recon;                         // N*H bf16
    bf16_t* hiddenb = (bf16_t*)(out_recon + (long long)NN * HH);  // N*H bf16 (2nd half)

    float*  dinv    = (float*)d_ws;                          // N
    int*    cnt     = (int*)(dinv + NN);                     // N
    int*    cursor  = cnt + NN;                              // N
    int*    rowptr  = cursor + NN;                           // N+1
    int*    csr_src = rowptr + NN + 1;                       // E
    char*   pbase   = (char*)(csr_src + EE);
    pbase = (char*)(((size_t)pbase + 255) & ~(size_t)255);
    bf16_t* xb      = (bf16_t*)pbase;                        // N*D bf16 (later decodeb)
    bf16_t* W1t     = xb + (long long)NN * DD;               // H*D bf16 (W_gc1^T)
    bf16_t* W2t     = W1t + (long long)DD * HH;              // D*H bf16 (W_fc2^T)
    bf16_t* Wg2t    = W2t + (long long)DD * HH;              // L*H bf16 (W_gc2^T)
    bf16_t* Wf1t    = Wg2t + (long long)HH * LL;             // H*L bf16 (W_fc1^T)
    bf16_t* latentb = Wf1t + (long long)LL * HH;             // N*L bf16
    float*  wsC     = (float*)(latentb + (long long)NN * LL); // N*L f32 (h2)
    bf16_t* decodeb = xb;                                    // N*H bf16, reuses xb

    // 1) CSR build + dinv
    zero_int<<<(2 * NN + 255) / 256, 256, 0, stream>>>(cnt, 2 * NN);
    cnt_count<<<(EE + 255) / 256, 256, 0, stream>>>(ei, cnt, EE);
    dinv_from_cnt<<<(NN + 255) / 256, 256, 0, stream>>>(cnt, dinv, NN);
    scan_rowptr<<<1, 1024, 0, stream>>>(cnt, rowptr, NN);
    csr_fill<<<(EE + 255) / 256, 256, 0, stream>>>(ei, rowptr, cursor, csr_src, EE);

    // 2) bf16 conversions
    cvt_bf16<<<2048, 256, 0, stream>>>((const float4*)x, (ushort4*)xb, (long long)NN * DD / 4);
    {
        dim3 ga(HH / 32, DD / 32);
        cvt_transpose_bf16<<<ga, 256, 0, stream>>>(W_gc1, W1t, DD, HH);
        dim3 gb(DD / 32, HH / 32);
        cvt_transpose_bf16<<<gb, 256, 0, stream>>>(W_fc2, W2t, HH, DD);
        dim3 gc(LL / 32, HH / 32);
        cvt_transpose_bf16<<<gc, 256, 0, stream>>>(W_gc2, Wg2t, HH, LL);
        dim3 gd(HH / 32, LL / 32);
        cvt_transpose_bf16<<<gd, 256, 0, stream>>>(W_fc1, Wf1t, LL, HH);
    }

    const int MB128 = (NN + 127) / 128;   // 157
    const int MB256 = (NN + 255) / 256;   // 79

    // 3) h1b = bf16(xb @ W1t^T)   [N, H]   (256x256 pipelined)
    {
        int gx = HH / 256;   // 6
        gemm_bf16_8ph<0, 0, 1><<<gx * MB256, 512, 0, stream>>>(xb, W1t, nullptr, h1b, NN, HH, DD, gx);
    }

    // 4) hiddenb = bf16(LN(relu(agg(h1b) + b_gc1)))
    gcn_agg_ln_h<<<(NN + 3) / 4, 256, 0, stream>>>(h1b, dinv, rowptr, csr_src, b_gc1, g1, be1, hiddenb, NN);

    // 5) h2 = hiddenb @ Wg2t^T    [N, L] f32 -> wsC   (MFMA 128x64)
    gemm_bf16_mfma<0, 0, 0, 64><<<MB128, 256, 0, stream>>>(hiddenb, Wg2t, nullptr, wsC, NN, LL, HH, 1);

    // 6) latent = LN(relu(agg(h2) + b_gc2)) -> output 0 (+ bf16 copy)
    gcn_agg_ln_l<<<(NN + 3) / 4, 256, 0, stream>>>(wsC, dinv, rowptr, csr_src, b_gc2, g2, be2, out_latent, latentb, NN);

    // 7) decodeb = bf16(relu(latentb @ Wf1t^T + b_fc1))  [N, H] (MFMA 128x128, K=64)
    {
        int gx = HH / 128;
        gemm_bf16_mfma<1, 1, 1, 128><<<gx * MB128, 256, 0, stream>>>(latentb, Wf1t, b_fc1, decodeb, NN, HH, LL, gx);
    }

    // 8) reconstructed = decodeb @ W2t^T + b_fc2  [N, D] -> output 1 (256x256)
    {
        int gx = DD / 256;   // 12
        gemm_bf16_8ph<1, 0, 0><<<gx * MB256, 512, 0, stream>>>(decodeb, W2t, b_fc2, out_recon, NN, DD, HH, gx);
    }
}